// Round 6
// baseline (1249.655 us; speedup 1.0000x reference)
//
#include <hip/hip_runtime.h>
#include <stdint.h>

#define L_TOK 16384
#define DM 256
#define DI 512
#define DS 64
#define NH 8
#define HD 64
#define CD 640
#define DP 1160
#define CHUNK 64
#define NC 256
#define EPSF 1e-5f

typedef __attribute__((ext_vector_type(8))) short short8;
typedef __attribute__((ext_vector_type(4))) float f32x4;

#define GLL16(gp, lp) __builtin_amdgcn_global_load_lds((const __attribute__((address_space(1))) void*)(gp), (__attribute__((address_space(3))) void*)(lp), 16, 0, 0)

__device__ __forceinline__ float warp_sum(float v) {
  v += __shfl_xor(v, 1, 64);
  v += __shfl_xor(v, 2, 64);
  v += __shfl_xor(v, 4, 64);
  v += __shfl_xor(v, 8, 64);
  v += __shfl_xor(v, 16, 64);
  v += __shfl_xor(v, 32, 64);
  return v;
}

__device__ __forceinline__ float siluf(float x) { return x / (1.0f + expf(-x)); }

__device__ __forceinline__ unsigned short f2bf(float f) {
  unsigned int u = __float_as_uint(f);
  unsigned int r = (u + 0x7FFFu + ((u >> 16) & 1u)) >> 16;
  return (unsigned short)r;
}
__device__ __forceinline__ float bf2f(unsigned short u) {
  return __uint_as_float(((unsigned int)u) << 16);
}

// fused 4-tap causal conv + bias + SiLU over 8 consecutive channels at token `tok`
__device__ __forceinline__ void conv8(const unsigned short* __restrict__ xbc, const float* __restrict__ cw,
                                      const float* __restrict__ cbias, int tok, int ch, float out[8]) {
  #pragma unroll
  for (int e = 0; e < 8; ++e) out[e] = cbias[ch + e];
  #pragma unroll
  for (int k = 0; k < 4; ++k) {
    int row = tok - 3 + k;
    if (row >= 0) {
      short8 xv = *(const short8*)(xbc + (size_t)row*CD + ch);
      #pragma unroll
      for (int e = 0; e < 8; ++e)
        out[e] = fmaf(cw[(ch + e)*4 + k], bf2f((unsigned short)xv[e]), out[e]);
    }
  }
  #pragma unroll
  for (int e = 0; e < 8; ++e) out[e] = siluf(out[e]);
}

// ---------------- serialization ----------------

__global__ __launch_bounds__(256) void minmax_kernel(const float* __restrict__ pos, float* __restrict__ pmm) {
  __shared__ float sm[6][256];
  int tid = threadIdx.x;
  float mn0=1e30f, mn1=1e30f, mn2=1e30f, mx0=-1e30f, mx1=-1e30f, mx2=-1e30f;
  for (int t = tid; t < L_TOK; t += 256) {
    float a = pos[t*3+0], b = pos[t*3+1], c = pos[t*3+2];
    mn0=fminf(mn0,a); mx0=fmaxf(mx0,a);
    mn1=fminf(mn1,b); mx1=fmaxf(mx1,b);
    mn2=fminf(mn2,c); mx2=fmaxf(mx2,c);
  }
  sm[0][tid]=mn0; sm[1][tid]=mn1; sm[2][tid]=mn2;
  sm[3][tid]=mx0; sm[4][tid]=mx1; sm[5][tid]=mx2;
  __syncthreads();
  for (int s = 128; s > 0; s >>= 1) {
    if (tid < s) {
      #pragma unroll
      for (int d = 0; d < 3; ++d) {
        sm[d][tid]   = fminf(sm[d][tid],   sm[d][tid+s]);
        sm[3+d][tid] = fmaxf(sm[3+d][tid], sm[3+d][tid+s]);
      }
    }
    __syncthreads();
  }
  if (tid < 6) pmm[tid] = sm[tid][0];
}

__device__ unsigned int hilbert3(unsigned int a, unsigned int b, unsigned int c) {
  unsigned int x0 = a, x1 = b, x2 = c;
  for (unsigned int Q = 512u; Q > 1u; Q >>= 1) {
    unsigned int P = Q - 1u;
    { if (x0 & Q) x0 ^= P; }
    {
      unsigned int t = (x0 ^ x1) & P;
      if (x1 & Q) { x0 ^= P; }
      else { x0 ^= t; x1 ^= t; }
    }
    {
      unsigned int t = (x0 ^ x2) & P;
      if (x2 & Q) { x0 ^= P; }
      else { x0 ^= t; x2 ^= t; }
    }
  }
  x1 ^= x0; x2 ^= x1;
  unsigned int tt = 0;
  for (unsigned int Q = 512u; Q > 1u; Q >>= 1)
    if (x2 & Q) tt ^= (Q - 1u);
  x0 ^= tt; x1 ^= tt; x2 ^= tt;
  unsigned int code = 0;
  #pragma unroll
  for (int bb = 9; bb >= 0; --bb) {
    code = (code << 1) | ((x0 >> bb) & 1u);
    code = (code << 1) | ((x1 >> bb) & 1u);
    code = (code << 1) | ((x2 >> bb) & 1u);
  }
  return code;
}

__global__ __launch_bounds__(256) void hilbert_kernel(const float* __restrict__ pos, const float* __restrict__ pmm,
                                                      unsigned long long* __restrict__ keys) {
  int t = blockIdx.x*256 + threadIdx.x;
  if (t >= L_TOK) return;
  unsigned int g[3];
  #pragma unroll
  for (int d = 0; d < 3; ++d) {
    float v = (pos[t*3+d] - pmm[d]) / (pmm[3+d] - pmm[d] + 1e-6f) * 1023.0f;
    v = fminf(fmaxf(v, 0.0f), 1023.0f);
    g[d] = (unsigned int)(int)v;
  }
  unsigned int ca = hilbert3(g[0], g[1], g[2]);
  unsigned int cb = hilbert3(g[1], g[0], g[2]);
  keys[t]         = ((unsigned long long)ca << 14) | (unsigned long long)t;
  keys[L_TOK + t] = ((unsigned long long)cb << 14) | (unsigned long long)t;
}

__global__ __launch_bounds__(256) void rank_partial(const unsigned long long* __restrict__ keys,
                                                    unsigned int* __restrict__ partial) {
  __shared__ unsigned long long tile[1024];
  int arr = blockIdx.y, ks = blockIdx.z;
  const unsigned long long* k = keys + (size_t)arr * L_TOK;
  int qbase = blockIdx.x*2048 + threadIdx.x;
  unsigned long long q[8];
  #pragma unroll
  for (int i = 0; i < 8; ++i) q[i] = k[qbase + 256*i];
  const unsigned long long* src = k + ks*1024;
  #pragma unroll
  for (int t = 0; t < 4; ++t) tile[threadIdx.x + 256*t] = src[threadIdx.x + 256*t];
  __syncthreads();
  unsigned int r[8] = {};
  const ulonglong2* t2 = (const ulonglong2*)tile;
  #pragma unroll 4
  for (int j = 0; j < 512; ++j) {
    ulonglong2 v = t2[j];
    #pragma unroll
    for (int i = 0; i < 8; ++i) {
      r[i] += (v.x < q[i]) ? 1u : 0u;
      r[i] += (v.y < q[i]) ? 1u : 0u;
    }
  }
  #pragma unroll
  for (int i = 0; i < 8; ++i)
    partial[(size_t)(ks*2 + arr)*L_TOK + qbase + 256*i] = r[i];
}

__global__ __launch_bounds__(256) void rank_scatter(const unsigned long long* __restrict__ keys,
                                                    const unsigned int* __restrict__ partial,
                                                    unsigned int* __restrict__ ord) {
  int i = blockIdx.x*256 + threadIdx.x;
  int arr = i >> 14;
  int qi = i & (L_TOK - 1);
  unsigned int r = 0;
  #pragma unroll
  for (int ks = 0; ks < 16; ++ks) r += partial[(size_t)(ks*2 + arr)*L_TOK + qi];
  ord[(size_t)arr*L_TOK + r] = (unsigned int)(keys[i] & 0x3FFFu);
}

// ---------------- layernorm / gating ----------------

__global__ __launch_bounds__(256) void ln_kernel(const float* __restrict__ in, float* __restrict__ out,
                                                 unsigned short* __restrict__ outbf,
                                                 const float* __restrict__ w, const float* __restrict__ b) {
  int row = blockIdx.x*4 + (threadIdx.x >> 6);
  int lane = threadIdx.x & 63;
  const float4 v = *(const float4*)(in + (size_t)row*DM + lane*4);
  float s = v.x + v.y + v.z + v.w;
  float mean = warp_sum(s) * (1.0f/DM);
  float4 xc = make_float4(v.x-mean, v.y-mean, v.z-mean, v.w-mean);
  float ss = xc.x*xc.x + xc.y*xc.y + xc.z*xc.z + xc.w*xc.w;
  ss = warp_sum(ss) * (1.0f/DM);
  float inv = rsqrtf(ss + EPSF);
  const float4 w4 = *(const float4*)(w + lane*4);
  const float4 b4 = *(const float4*)(b + lane*4);
  float4 o;
  o.x = xc.x*inv*w4.x + b4.x;
  o.y = xc.y*inv*w4.y + b4.y;
  o.z = xc.z*inv*w4.z + b4.z;
  o.w = xc.w*inv*w4.w + b4.w;
  *(float4*)(out + (size_t)row*DM + lane*4) = o;
  if (outbf) {
    ushort4 ob = make_ushort4(f2bf(o.x), f2bf(o.y), f2bf(o.z), f2bf(o.w));
    *(ushort4*)(outbf + (size_t)row*DM + lane*4) = ob;
  }
}

__global__ __launch_bounds__(256) void gating_kernel(unsigned short* __restrict__ ybf,
                                                     const unsigned short* __restrict__ gatebf,
                                                     const float* __restrict__ nw) {
  int row = blockIdx.x*4 + (threadIdx.x >> 6);
  int lane = threadIdx.x & 63;
  unsigned short* yr = ybf + (size_t)row*DI;
  const unsigned short* gr = gatebf + (size_t)row*DI;
  ushort4 yu0 = *(const ushort4*)(yr + lane*4);
  ushort4 yu1 = *(const ushort4*)(yr + 256 + lane*4);
  ushort4 gu0 = *(const ushort4*)(gr + lane*4);
  ushort4 gu1 = *(const ushort4*)(gr + 256 + lane*4);
  float4 y0 = make_float4(bf2f(yu0.x), bf2f(yu0.y), bf2f(yu0.z), bf2f(yu0.w));
  float4 y1 = make_float4(bf2f(yu1.x), bf2f(yu1.y), bf2f(yu1.z), bf2f(yu1.w));
  y0.x *= siluf(bf2f(gu0.x)); y0.y *= siluf(bf2f(gu0.y)); y0.z *= siluf(bf2f(gu0.z)); y0.w *= siluf(bf2f(gu0.w));
  y1.x *= siluf(bf2f(gu1.x)); y1.y *= siluf(bf2f(gu1.y)); y1.z *= siluf(bf2f(gu1.z)); y1.w *= siluf(bf2f(gu1.w));
  float ss = y0.x*y0.x + y0.y*y0.y + y0.z*y0.z + y0.w*y0.w
           + y1.x*y1.x + y1.y*y1.y + y1.z*y1.z + y1.w*y1.w;
  ss = warp_sum(ss) * (1.0f/DI);
  float inv = rsqrtf(ss + EPSF);
  const float4 w0 = *(const float4*)(nw + lane*4);
  const float4 w1 = *(const float4*)(nw + 256 + lane*4);
  y0.x *= inv*w0.x; y0.y *= inv*w0.y; y0.z *= inv*w0.z; y0.w *= inv*w0.w;
  y1.x *= inv*w1.x; y1.y *= inv*w1.y; y1.z *= inv*w1.z; y1.w *= inv*w1.w;
  *(ushort4*)(yr + lane*4)       = make_ushort4(f2bf(y0.x), f2bf(y0.y), f2bf(y0.z), f2bf(y0.w));
  *(ushort4*)(yr + 256 + lane*4) = make_ushort4(f2bf(y1.x), f2bf(y1.y), f2bf(y1.z), f2bf(y1.w));
}

// ---------------- weight transpose+convert ----------------

__global__ __launch_bounds__(256) void tcvt_both(const float* __restrict__ Wi, const float* __restrict__ Wo,
                                                 unsigned short* __restrict__ WtA, unsigned short* __restrict__ WtO) {
  int idx = blockIdx.x*256 + threadIdx.x;
  if (idx < 1152*DM) {
    int n = idx >> 8, k = idx & 255;
    WtA[idx] = f2bf(Wi[(size_t)k*DP + n]);
  } else {
    int j = idx - 1152*DM;
    int n = j >> 9, k = j & 511;
    WtO[j] = f2bf(Wo[(size_t)k*DM + n]);
  }
}

// ---------------- MFMA GEMMs ----------------

__global__ __launch_bounds__(256) void gemm_in_mfma(const unsigned short* __restrict__ Abf,
                                                    const unsigned short* __restrict__ Wt,
                                                    const unsigned int* __restrict__ ordp,
                                                    unsigned short* __restrict__ gatebf,
                                                    unsigned short* __restrict__ xbcbf) {
  __shared__ unsigned short Alds[128*64];
  __shared__ unsigned short Blds[128*64];
  int tid = threadIdx.x, lane = tid & 63, w = tid >> 6;
  int rb = blockIdx.y*128, cb = blockIdx.x*128;
  int wm = (w & 1)*64, wn = (w >> 1)*64;
  const unsigned short* pA[4]; const unsigned short* pB[4];
  unsigned short* dA[4]; unsigned short* dB[4];
  #pragma unroll
  for (int s = 0; s < 4; ++s) {
    int inst = w*4 + s;
    int r = inst*8 + (lane >> 3);
    int cA = (lane & 7) ^ (r & 7);
    pA[s] = Abf + (size_t)ordp[rb + r]*DM + cA*8;
    pB[s] = Wt + (size_t)(cb + r)*DM + cA*8;
    dA[s] = &Alds[inst*512];
    dB[s] = &Blds[inst*512];
  }
  f32x4 zero = {0.f, 0.f, 0.f, 0.f};
  f32x4 acc[4][4];
  #pragma unroll
  for (int i = 0; i < 4; ++i)
    #pragma unroll
    for (int j = 0; j < 4; ++j) acc[i][j] = zero;
  int t = lane & 15, q = lane >> 4;
  for (int k0 = 0; k0 < DM; k0 += 64) {
    #pragma unroll
    for (int s = 0; s < 4; ++s) GLL16(pA[s] + k0, dA[s]);
    #pragma unroll
    for (int s = 0; s < 4; ++s) GLL16(pB[s] + k0, dB[s]);
    __syncthreads();
    #pragma unroll
    for (int ks = 0; ks < 2; ++ks) {
      short8 af[4], bfr[4];
      int cc = ks*4 + q;
      #pragma unroll
      for (int i = 0; i < 4; ++i) {
        int rr = wm + 16*i + t;
        af[i] = *(const short8*)&Alds[rr*64 + ((cc ^ (rr & 7))*8)];
      }
      #pragma unroll
      for (int j = 0; j < 4; ++j) {
        int rr = wn + 16*j + t;
        bfr[j] = *(const short8*)&Blds[rr*64 + ((cc ^ (rr & 7))*8)];
      }
      #pragma unroll
      for (int i = 0; i < 4; ++i)
        #pragma unroll
        for (int j = 0; j < 4; ++j)
          acc[i][j] = __builtin_amdgcn_mfma_f32_16x16x32_bf16(af[i], bfr[j], acc[i][j], 0, 0, 0);
    }
    __syncthreads();
  }
  unsigned short* dst; int ld;
  if (cb < DI) { dst = gatebf + cb; ld = DI; }
  else         { dst = xbcbf + (cb - DI); ld = CD; }
  #pragma unroll
  for (int i = 0; i < 4; ++i) {
    int rowb = rb + wm + 16*i + q*4;
    #pragma unroll
    for (int j = 0; j < 4; ++j) {
      int col = wn + 16*j + t;
      #pragma unroll
      for (int r = 0; r < 4; ++r)
        dst[(size_t)(rowb + r)*ld + col] = f2bf(acc[i][j][r]);
    }
  }
}

__global__ __launch_bounds__(256) void gemm_out_mfma(const unsigned short* __restrict__ Abf,
                                                     const unsigned short* __restrict__ Wt,
                                                     const unsigned int* __restrict__ ordp,
                                                     float* __restrict__ out) {
  __shared__ unsigned short Alds[128*64];
  __shared__ unsigned short Blds[128*64];
  __shared__ unsigned int ordl[128];
  int tid = threadIdx.x, lane = tid & 63, w = tid >> 6;
  int rb = blockIdx.y*128, cb = blockIdx.x*128;
  int wm = (w & 1)*64, wn = (w >> 1)*64;
  if (tid < 128) ordl[tid] = ordp[rb + tid];
  const unsigned short* pA[4]; const unsigned short* pB[4];
  unsigned short* dA[4]; unsigned short* dB[4];
  #pragma unroll
  for (int s = 0; s < 4; ++s) {
    int inst = w*4 + s;
    int r = inst*8 + (lane >> 3);
    int cA = (lane & 7) ^ (r & 7);
    pA[s] = Abf + (size_t)(rb + r)*DI + cA*8;
    pB[s] = Wt + (size_t)(cb + r)*DI + cA*8;
    dA[s] = &Alds[inst*512];
    dB[s] = &Blds[inst*512];
  }
  f32x4 zero = {0.f, 0.f, 0.f, 0.f};
  f32x4 acc[4][4];
  #pragma unroll
  for (int i = 0; i < 4; ++i)
    #pragma unroll
    for (int j = 0; j < 4; ++j) acc[i][j] = zero;
  int t = lane & 15, q = lane >> 4;
  for (int k0 = 0; k0 < DI; k0 += 64) {
    #pragma unroll
    for (int s = 0; s < 4; ++s) GLL16(pA[s] + k0, dA[s]);
    #pragma unroll
    for (int s = 0; s < 4; ++s) GLL16(pB[s] + k0, dB[s]);
    __syncthreads();
    #pragma unroll
    for (int ks = 0; ks < 2; ++ks) {
      short8 af[4], bfr[4];
      int cc = ks*4 + q;
      #pragma unroll
      for (int i = 0; i < 4; ++i) {
        int rr = wm + 16*i + t;
        af[i] = *(const short8*)&Alds[rr*64 + ((cc ^ (rr & 7))*8)];
      }
      #pragma unroll
      for (int j = 0; j < 4; ++j) {
        int rr = wn + 16*j + t;
        bfr[j] = *(const short8*)&Blds[rr*64 + ((cc ^ (rr & 7))*8)];
      }
      #pragma unroll
      for (int i = 0; i < 4; ++i)
        #pragma unroll
        for (int j = 0; j < 4; ++j)
          acc[i][j] = __builtin_amdgcn_mfma_f32_16x16x32_bf16(af[i], bfr[j], acc[i][j], 0, 0, 0);
    }
    __syncthreads();
  }
  #pragma unroll
  for (int i = 0; i < 4; ++i) {
    #pragma unroll
    for (int r = 0; r < 4; ++r) {
      unsigned int tok = ordl[wm + 16*i + q*4 + r];
      float* op = out + (size_t)tok*DM + cb;
      #pragma unroll
      for (int j = 0; j < 4; ++j) {
        int col = wn + 16*j + t;
        op[col] += 0.5f*acc[i][j][r];
      }
    }
  }
}

// ---------------- dt path (fp32, fused softplus) ----------------
__global__ __launch_bounds__(256) void dt_gemv(const float* __restrict__ qn, const float* __restrict__ W,
                                               const unsigned int* __restrict__ ordp,
                                               const float* __restrict__ dt_bias, float* __restrict__ dtb) {
  int row = blockIdx.x*4 + (threadIdx.x >> 6);
  int lane = threadIdx.x & 63;
  unsigned int src = ordp[row];
  const float4 q4 = *(const float4*)(qn + (size_t)src*DM + lane*4);
  float a[8] = {0,0,0,0,0,0,0,0};
  const float* wp = W + (size_t)(lane*4)*DP + (DI + CD);
  float qe[4] = {q4.x, q4.y, q4.z, q4.w};
  #pragma unroll
  for (int e = 0; e < 4; ++e) {
    float4 wa = *(const float4*)(wp + (size_t)e*DP);
    float4 wb = *(const float4*)(wp + (size_t)e*DP + 4);
    a[0] += qe[e]*wa.x; a[1] += qe[e]*wa.y; a[2] += qe[e]*wa.z; a[3] += qe[e]*wa.w;
    a[4] += qe[e]*wb.x; a[5] += qe[e]*wb.y; a[6] += qe[e]*wb.z; a[7] += qe[e]*wb.w;
  }
  #pragma unroll
  for (int h = 0; h < 8; ++h) a[h] = warp_sum(a[h]);
  float v = 0.0f;
  #pragma unroll
  for (int h = 0; h < 8; ++h) if (lane == h) v = a[h];
  if (lane < 8) {
    v += dt_bias[lane];
    float sp = (v > 0.0f) ? (v + log1pf(expf(-v))) : log1pf(expf(v));
    dtb[(size_t)row*NH + lane] = sp;
  }
}

// ---------------- chunked scan (MFMA, fused conv, bf16 S) ----------------

__global__ __launch_bounds__(256) void phaseA_mfma(const unsigned short* __restrict__ xbc,
                                                   const float* __restrict__ cw, const float* __restrict__ cbias,
                                                   const float* __restrict__ dtb, const float* __restrict__ A_log,
                                                   unsigned short* __restrict__ S, float* __restrict__ P) {
  int c = blockIdx.x, h = blockIdx.y, tid = threadIdx.x;
  int lane = tid & 63, w = tid >> 6;
  __shared__ unsigned short xT[64*64];
  __shared__ unsigned short Bt[64*64];
  __shared__ float dts[64], lg[64], sfx[64], wgt[64];
  __shared__ float totals;
  int c0 = c*CHUNK;
  float Ah = -expf(A_log[h]);
  if (tid < 64) {
    float dtv = dtb[(size_t)(c0+tid)*NH + h];
    dts[tid] = dtv; lg[tid] = dtv*Ah;
  }
  // stage B transposed with fused conv: rows s, col t
  #pragma unroll
  for (int i = 0; i < 2; ++i) {
    int q = tid + 256*i;
    int t = q >> 3, s0 = (q & 7)*8;
    float cv[8];
    conv8(xbc, cw, cbias, c0 + t, DI + s0, cv);
    int tc = t >> 3, ti = t & 7;
    #pragma unroll
    for (int e = 0; e < 8; ++e) {
      int s = s0 + e;
      Bt[s*64 + ((tc ^ (s & 7))*8 + ti)] = f2bf(cv[e]);
    }
  }
  __syncthreads();
  if (tid == 0) {
    float run = 0.f;
    for (int t = 63; t >= 0; --t) { sfx[t] = run; run += lg[t]; }
    totals = run;
  }
  __syncthreads();
  if (tid < 64) wgt[tid] = dts[tid]*expf(sfx[tid]);
  if (tid == 0) P[h*NC + c] = expf(totals);
  __syncthreads();
  // stage x transposed with fused conv and weight
  #pragma unroll
  for (int i = 0; i < 2; ++i) {
    int q = tid + 256*i;
    int t = q >> 3, p0 = (q & 7)*8;
    float cv[8];
    conv8(xbc, cw, cbias, c0 + t, h*HD + p0, cv);
    float wv = wgt[t];
    int tc = t >> 3, ti = t & 7;
    #pragma unroll
    for (int e = 0; e < 8; ++e) {
      int p = p0 + e;
      xT[p*64 + ((tc ^ (p & 7))*8 + ti)] = f2bf(cv[e] * wv);
    }
  }
  __syncthreads();
  int t16 = lane & 15, q4 = lane >> 4;
  f32x4 zero = {0.f,0.f,0.f,0.f};
  f32x4 acc[4];
  #pragma unroll
  for (int j = 0; j < 4; ++j) acc[j] = zero;
  #pragma unroll
  for (int ks = 0; ks < 2; ++ks) {
    int rowA = 16*w + t16;
    short8 a = *(const short8*)&xT[rowA*64 + (((ks*4 + q4) ^ (rowA & 7))*8)];
    #pragma unroll
    for (int j = 0; j < 4; ++j) {
      int rowB = 16*j + t16;
      short8 b = *(const short8*)&Bt[rowB*64 + (((ks*4 + q4) ^ (rowB & 7))*8)];
      acc[j] = __builtin_amdgcn_mfma_f32_16x16x32_bf16(a, b, acc[j], 0, 0, 0);
    }
  }
  unsigned short* Sp = S + ((size_t)(h*NC + c))*4096;
  #pragma unroll
  for (int j = 0; j < 4; ++j)
    #pragma unroll
    for (int r = 0; r < 4; ++r)
      Sp[(size_t)(16*w + q4*4 + r)*64 + 16*j + t16] = f2bf(acc[j][r]);
}

// ---- phaseB split: 16 superchunks x 16 chunks, fp32 carry, bf16 storage ----

__global__ __launch_bounds__(256) void phaseB1(const unsigned short* __restrict__ S, const float* __restrict__ P,
                                               float* __restrict__ Ssum, float* __restrict__ Psum) {
  int gid = blockIdx.x*256 + threadIdx.x;
  int e2 = gid & 2047;
  int sc = (gid >> 11) & 15;
  int h  = gid >> 15;
  const unsigned short* base = S + ((size_t)(h*NC + sc*16))*4096 + e2*2;
  const float* Ph = P + h*NC + sc*16;
  float hx = 0.f, hy = 0.f, pprod = 1.f;
  #pragma unroll
  for (int k = 0; k < 16; ++k) {
    unsigned int v = *(const unsigned int*)(base + (size_t)k*4096);
    float p = Ph[k];
    hx = p*hx + bf2f((unsigned short)(v & 0xffffu));
    hy = p*hy + bf2f((unsigned short)(v >> 16));
    pprod *= p;
  }
  float* sp = Ssum + ((size_t)(h*16 + sc))*4096 + e2*2;
  sp[0] = hx; sp[1] = hy;
  if (e2 == 0) Psum[h*16 + sc] = pprod;
}

__global__ __launch_bounds__(256) void phaseB3(unsigned short* __restrict__ S, const float* __restrict__ P,
                                               const float* __restrict__ Ssum, const float* __restrict__ Psum) {
  int gid = blockIdx.x*256 + threadIdx.x;
  int e2 = gid & 2047;
  int sc = (gid >> 11) & 15;
  int h  = gid >> 15;
  float hx = 0.f, hy = 0.f;
  for (int s2 = 0; s2 < sc; ++s2) {
    float pp = Psum[h*16 + s2];
    const float* sp = Ssum + ((size_t)(h*16 + s2))*4096 + e2*2;
    hx = pp*hx + sp[0];
    hy = pp*hy + sp[1];
  }
  unsigned short* base = S + ((size_t)(h*NC + sc*16))*4096 + e2*2;
  const float* Ph = P + h*NC + sc*16;
  #pragma unroll
  for (int k = 0; k < 16; ++k) {
    unsigned int* ptr = (unsigned int*)(base + (size_t)k*4096);
    unsigned int v = *ptr;
    float p = Ph[k];
    *ptr = (unsigned int)f2bf(hx) | ((unsigned int)f2bf(hy) << 16);
    hx = p*hx + bf2f((unsigned short)(v & 0xffffu));
    hy = p*hy + bf2f((unsigned short)(v >> 16));
  }
}

// phaseC: fused conv on C/B/x staging; Y bf16 out
__global__ __launch_bounds__(256) void phaseC_mfma(const unsigned short* __restrict__ xbc,
                                                   const float* __restrict__ cw, const float* __restrict__ cbias,
                                                   const float* __restrict__ dtb, const float* __restrict__ A_log,
                                                   const float* __restrict__ Dp,
                                                   const unsigned short* __restrict__ S,
                                                   unsigned short* __restrict__ y) {
  int c = blockIdx.x, h = blockIdx.y, tid = threadIdx.x;
  int lane = tid & 63, w = tid >> 6;
  __shared__ unsigned short Cl[64*64];
  __shared__ unsigned short Bl[64*64];
  __shared__ unsigned short h0l[64*64];
  __shared__ unsigned short xT[64*64];
  __shared__ unsigned short Gl[64*64];
  __shared__ float dts[64], lg[64], pl[64], pe[64];
  int c0 = c*CHUNK;
  float Ah = -expf(A_log[h]);
  float Dh = Dp[h];
  if (tid < 64) {
    float dtv = dtb[(size_t)(c0+tid)*NH + h];
    dts[tid] = dtv; lg[tid] = dtv*Ah;
  }
  const unsigned short* Sp = S + ((size_t)(h*NC + c))*4096;
  #pragma unroll
  for (int i = 0; i < 2; ++i) {
    int q = tid + 256*i;
    int t = q >> 3, d0 = (q & 7)*8;
    int swoff = t*64 + (((q & 7) ^ (t & 7))*8);
    float cv[8];
    // C slice
    conv8(xbc, cw, cbias, c0 + t, DI + DS + d0, cv);
    {
      short8 r;
      #pragma unroll
      for (int e = 0; e < 8; ++e) r[e] = (short)f2bf(cv[e]);
      *(short8*)&Cl[swoff] = r;
    }
    // B slice
    conv8(xbc, cw, cbias, c0 + t, DI + d0, cv);
    {
      short8 r;
      #pragma unroll
      for (int e = 0; e < 8; ++e) r[e] = (short)f2bf(cv[e]);
      *(short8*)&Bl[swoff] = r;
    }
    // h0 (already bf16)
    *(short8*)&h0l[swoff] = *(const short8*)(Sp + (size_t)t*64 + d0);
    // x slice, transposed scatter
    conv8(xbc, cw, cbias, c0 + t, h*HD + d0, cv);
    int tc = t >> 3, ti = t & 7;
    #pragma unroll
    for (int e = 0; e < 8; ++e) {
      int p = d0 + e;
      xT[p*64 + ((tc ^ (p & 7))*8 + ti)] = f2bf(cv[e]);
    }
  }
  __syncthreads();
  if (tid == 0) {
    float run = 0.f;
    for (int t = 0; t < 64; ++t) { run += lg[t]; pl[t] = run; }
  }
  __syncthreads();
  if (tid < 64) pe[tid] = expf(pl[tid]);
  __syncthreads();
  int t16 = lane & 15, q4 = lane >> 4;
  int t0 = 16*w;
  f32x4 zero = {0.f,0.f,0.f,0.f};
  f32x4 accG[4], accY[4];
  #pragma unroll
  for (int j = 0; j < 4; ++j) { accG[j] = zero; accY[j] = zero; }
  #pragma unroll
  for (int ks = 0; ks < 2; ++ks) {
    int rowA = t0 + t16;
    short8 a = *(const short8*)&Cl[rowA*64 + (((ks*4 + q4) ^ (rowA & 7))*8)];
    #pragma unroll
    for (int j = 0; j < 4; ++j) {
      int rowB = 16*j + t16;
      int off = rowB*64 + (((ks*4 + q4) ^ (rowB & 7))*8);
      accG[j] = __builtin_amdgcn_mfma_f32_16x16x32_bf16(a, *(const short8*)&Bl[off], accG[j], 0, 0, 0);
      accY[j] = __builtin_amdgcn_mfma_f32_16x16x32_bf16(a, *(const short8*)&h0l[off], accY[j], 0, 0, 0);
    }
  }
  #pragma unroll
  for (int j = 0; j < 4; ++j) {
    #pragma unroll
    for (int r = 0; r < 4; ++r) {
      int t = t0 + q4*4 + r;
      int s = 16*j + t16;
      float v = 0.f;
      if (s <= t) {
        v = accG[j][r] * dts[s] * expf(pl[t] - pl[s]);
        if (s == t) v += Dh;
      }
      Gl[t*64 + (((s >> 3) ^ (t & 7))*8 + (s & 7))] = f2bf(v);
    }
  }
  #pragma unroll
  for (int j = 0; j < 4; ++j)
    #pragma unroll
    for (int r = 0; r < 4; ++r)
      accY[j][r] *= pe[t0 + q4*4 + r];
  #pragma unroll
  for (int ks = 0; ks < 2; ++ks) {
    int rowA = t0 + t16;
    short8 a = *(const short8*)&Gl[rowA*64 + (((ks*4 + q4) ^ (rowA & 7))*8)];
    #pragma unroll
    for (int j = 0; j < 4; ++j) {
      int rowB = 16*j + t16;
      short8 b = *(const short8*)&xT[rowB*64 + (((ks*4 + q4) ^ (rowB & 7))*8)];
      accY[j] = __builtin_amdgcn_mfma_f32_16x16x32_bf16(a, b, accY[j], 0, 0, 0);
    }
  }
  #pragma unroll
  for (int j = 0; j < 4; ++j)
    #pragma unroll
    for (int r = 0; r < 4; ++r) {
      int t = t0 + q4*4 + r;
      int p = 16*j + t16;
      y[(size_t)(c0+t)*DI + h*HD + p] = f2bf(accY[j][r]);
    }
}

__global__ void fill_debug(float* out, float v) {
  int i = blockIdx.x*256 + threadIdx.x;
  if (i < L_TOK*DM) out[i] = v;
}

// ---------------- host ----------------

extern "C" void kernel_launch(void* const* d_in, const int* in_sizes, int n_in,
                              void* d_out, int out_size, void* d_ws, size_t ws_size,
                              hipStream_t stream) {
  const float* query = (const float*)d_in[0];
  const float* qpos  = (const float*)d_in[1];
  const float* pre_w = (const float*)d_in[2];
  const float* pre_b = (const float*)d_in[3];
  const float* fin_w = (const float*)d_in[4];
  const float* fin_b = (const float*)d_in[5];
  float* out = (float*)d_out;

  char* ws = (char*)d_ws;
  size_t off = 0;
  auto alloc = [&](size_t bytes) -> void* {
    void* p = ws + off;
    off += (bytes + 255) & ~(size_t)255;
    return p;
  };
  unsigned long long* keys = (unsigned long long*)alloc((size_t)2*L_TOK*8);
  unsigned int* ord = (unsigned int*)alloc((size_t)2*L_TOK*4);
  unsigned int* rpart = (unsigned int*)alloc((size_t)16*2*L_TOK*4);
  float* pmm  = (float*)alloc(256);
  float* qn   = (float*)alloc((size_t)L_TOK*DM*4);
  unsigned short* qnbf = (unsigned short*)alloc((size_t)L_TOK*DM*2);
  unsigned short* gatebf = (unsigned short*)alloc((size_t)L_TOK*DI*2);
  unsigned short* xbcbf  = (unsigned short*)alloc((size_t)L_TOK*CD*2);
  float* dtb  = (float*)alloc((size_t)L_TOK*NH*4);
  unsigned short* Sbuf = (unsigned short*)alloc((size_t)NH*NC*4096*2);
  float* Pbuf = (float*)alloc((size_t)NH*NC*4);
  float* Ssum = (float*)alloc((size_t)NH*16*4096*4);
  float* Psum = (float*)alloc((size_t)NH*16*4);
  unsigned short* ybf = (unsigned short*)alloc((size_t)L_TOK*DI*2);
  unsigned short* WtA = (unsigned short*)alloc((size_t)1152*DM*2);
  unsigned short* WtO = (unsigned short*)alloc((size_t)DM*DI*2);
  if (off > ws_size) {
    fill_debug<<<(L_TOK*DM + 255)/256, 256, 0, stream>>>(out, (float)(ws_size >> 20));
    return;
  }

  minmax_kernel<<<1, 256, 0, stream>>>(qpos, pmm);
  hilbert_kernel<<<L_TOK/256, 256, 0, stream>>>(qpos, pmm, keys);
  rank_partial<<<dim3(8, 2, 16), 256, 0, stream>>>(keys, rpart);
  rank_scatter<<<(2*L_TOK)/256, 256, 0, stream>>>(keys, rpart, ord);
  hipMemcpyAsync(out, query, (size_t)L_TOK*DM*4, hipMemcpyDeviceToDevice, stream);

  for (int l = 0; l < 2; ++l) {
    int base = 6 + 8*l;
    const float* in_proj  = (const float*)d_in[base+0];
    const float* conv_w   = (const float*)d_in[base+1];
    const float* conv_b   = (const float*)d_in[base+2];
    const float* dt_bias  = (const float*)d_in[base+3];
    const float* A_log    = (const float*)d_in[base+4];
    const float* Dp       = (const float*)d_in[base+5];
    const float* norm_w   = (const float*)d_in[base+6];
    const float* out_proj = (const float*)d_in[base+7];

    ln_kernel<<<L_TOK/4, 256, 0, stream>>>(out, qn, qnbf, pre_w, pre_b);
    tcvt_both<<<(1152*DM + DM*DI)/256, 256, 0, stream>>>(in_proj, out_proj, WtA, WtO);
    for (int dir = 0; dir < 2; ++dir) {
      const unsigned int* o = ord + (size_t)dir*L_TOK;
      gemm_in_mfma<<<dim3(9, L_TOK/128), 256, 0, stream>>>(qnbf, WtA, o, gatebf, xbcbf);
      dt_gemv<<<L_TOK/4, 256, 0, stream>>>(qn, in_proj, o, dt_bias, dtb);
      phaseA_mfma<<<dim3(NC, NH), 256, 0, stream>>>(xbcbf, conv_w, conv_b, dtb, A_log, Sbuf, Pbuf);
      phaseB1<<<(NH*16*2048)/256, 256, 0, stream>>>(Sbuf, Pbuf, Ssum, Psum);
      phaseB3<<<(NH*16*2048)/256, 256, 0, stream>>>(Sbuf, Pbuf, Ssum, Psum);
      phaseC_mfma<<<dim3(NC, NH), 256, 0, stream>>>(xbcbf, conv_w, conv_b, dtb, A_log, Dp, Sbuf, ybf);
      gating_kernel<<<L_TOK/4, 256, 0, stream>>>(ybf, gatebf, norm_w);
      gemm_out_mfma<<<dim3(2, L_TOK/128), 256, 0, stream>>>(ybf, WtO, o, out);
    }
    ln_kernel<<<L_TOK/4, 256, 0, stream>>>(out, out, (unsigned short*)nullptr, fin_w, fin_b);
  }
}

// Round 7
// 768.070 us; speedup vs baseline: 1.6270x; 1.6270x over previous
//
#include <hip/hip_runtime.h>
#include <stdint.h>

#define L_TOK 16384
#define DM 256
#define DI 512
#define DS 64
#define NH 8
#define HD 64
#define CD 640
#define DP 1160
#define CHUNK 64
#define NC 256
#define EPSF 1e-5f

typedef __attribute__((ext_vector_type(8))) short short8;
typedef __attribute__((ext_vector_type(4))) float f32x4;

#define GLL16(gp, lp) __builtin_amdgcn_global_load_lds((const __attribute__((address_space(1))) void*)(gp), (__attribute__((address_space(3))) void*)(lp), 16, 0, 0)

__device__ __forceinline__ float warp_sum(float v) {
  v += __shfl_xor(v, 1, 64);
  v += __shfl_xor(v, 2, 64);
  v += __shfl_xor(v, 4, 64);
  v += __shfl_xor(v, 8, 64);
  v += __shfl_xor(v, 16, 64);
  v += __shfl_xor(v, 32, 64);
  return v;
}

__device__ __forceinline__ float siluf(float x) { return x / (1.0f + expf(-x)); }

__device__ __forceinline__ unsigned short f2bf(float f) {
  unsigned int u = __float_as_uint(f);
  unsigned int r = (u + 0x7FFFu + ((u >> 16) & 1u)) >> 16;
  return (unsigned short)r;
}
__device__ __forceinline__ float bf2f(unsigned short u) {
  return __uint_as_float(((unsigned int)u) << 16);
}

// ---------------- serialization ----------------

__global__ __launch_bounds__(256) void minmax_kernel(const float* __restrict__ pos, float* __restrict__ pmm) {
  __shared__ float sm[6][256];
  int tid = threadIdx.x;
  float mn0=1e30f, mn1=1e30f, mn2=1e30f, mx0=-1e30f, mx1=-1e30f, mx2=-1e30f;
  for (int t = tid; t < L_TOK; t += 256) {
    float a = pos[t*3+0], b = pos[t*3+1], c = pos[t*3+2];
    mn0=fminf(mn0,a); mx0=fmaxf(mx0,a);
    mn1=fminf(mn1,b); mx1=fmaxf(mx1,b);
    mn2=fminf(mn2,c); mx2=fmaxf(mx2,c);
  }
  sm[0][tid]=mn0; sm[1][tid]=mn1; sm[2][tid]=mn2;
  sm[3][tid]=mx0; sm[4][tid]=mx1; sm[5][tid]=mx2;
  __syncthreads();
  for (int s = 128; s > 0; s >>= 1) {
    if (tid < s) {
      #pragma unroll
      for (int d = 0; d < 3; ++d) {
        sm[d][tid]   = fminf(sm[d][tid],   sm[d][tid+s]);
        sm[3+d][tid] = fmaxf(sm[3+d][tid], sm[3+d][tid+s]);
      }
    }
    __syncthreads();
  }
  if (tid < 6) pmm[tid] = sm[tid][0];
}

__device__ unsigned int hilbert3(unsigned int a, unsigned int b, unsigned int c) {
  unsigned int x0 = a, x1 = b, x2 = c;
  for (unsigned int Q = 512u; Q > 1u; Q >>= 1) {
    unsigned int P = Q - 1u;
    { if (x0 & Q) x0 ^= P; }
    {
      unsigned int t = (x0 ^ x1) & P;
      if (x1 & Q) { x0 ^= P; }
      else { x0 ^= t; x1 ^= t; }
    }
    {
      unsigned int t = (x0 ^ x2) & P;
      if (x2 & Q) { x0 ^= P; }
      else { x0 ^= t; x2 ^= t; }
    }
  }
  x1 ^= x0; x2 ^= x1;
  unsigned int tt = 0;
  for (unsigned int Q = 512u; Q > 1u; Q >>= 1)
    if (x2 & Q) tt ^= (Q - 1u);
  x0 ^= tt; x1 ^= tt; x2 ^= tt;
  unsigned int code = 0;
  #pragma unroll
  for (int bb = 9; bb >= 0; --bb) {
    code = (code << 1) | ((x0 >> bb) & 1u);
    code = (code << 1) | ((x1 >> bb) & 1u);
    code = (code << 1) | ((x2 >> bb) & 1u);
  }
  return code;
}

__global__ __launch_bounds__(256) void hilbert_kernel(const float* __restrict__ pos, const float* __restrict__ pmm,
                                                      unsigned long long* __restrict__ keys) {
  int t = blockIdx.x*256 + threadIdx.x;
  if (t >= L_TOK) return;
  unsigned int g[3];
  #pragma unroll
  for (int d = 0; d < 3; ++d) {
    float v = (pos[t*3+d] - pmm[d]) / (pmm[3+d] - pmm[d] + 1e-6f) * 1023.0f;
    v = fminf(fmaxf(v, 0.0f), 1023.0f);
    g[d] = (unsigned int)(int)v;
  }
  unsigned int ca = hilbert3(g[0], g[1], g[2]);
  unsigned int cb = hilbert3(g[1], g[0], g[2]);
  keys[t]         = ((unsigned long long)ca << 14) | (unsigned long long)t;
  keys[L_TOK + t] = ((unsigned long long)cb << 14) | (unsigned long long)t;
}

__global__ __launch_bounds__(256) void rank_partial(const unsigned long long* __restrict__ keys,
                                                    unsigned int* __restrict__ partial) {
  __shared__ unsigned long long tile[1024];
  int arr = blockIdx.y, ks = blockIdx.z;
  const unsigned long long* k = keys + (size_t)arr * L_TOK;
  int qbase = blockIdx.x*2048 + threadIdx.x;
  unsigned long long q[8];
  #pragma unroll
  for (int i = 0; i < 8; ++i) q[i] = k[qbase + 256*i];
  const unsigned long long* src = k + ks*1024;
  #pragma unroll
  for (int t = 0; t < 4; ++t) tile[threadIdx.x + 256*t] = src[threadIdx.x + 256*t];
  __syncthreads();
  unsigned int r[8] = {};
  const ulonglong2* t2 = (const ulonglong2*)tile;
  #pragma unroll 4
  for (int j = 0; j < 512; ++j) {
    ulonglong2 v = t2[j];
    #pragma unroll
    for (int i = 0; i < 8; ++i) {
      r[i] += (v.x < q[i]) ? 1u : 0u;
      r[i] += (v.y < q[i]) ? 1u : 0u;
    }
  }
  #pragma unroll
  for (int i = 0; i < 8; ++i)
    partial[(size_t)(ks*2 + arr)*L_TOK + qbase + 256*i] = r[i];
}

__global__ __launch_bounds__(256) void rank_scatter(const unsigned long long* __restrict__ keys,
                                                    const unsigned int* __restrict__ partial,
                                                    unsigned int* __restrict__ ord) {
  int i = blockIdx.x*256 + threadIdx.x;
  int arr = i >> 14;
  int qi = i & (L_TOK - 1);
  unsigned int r = 0;
  #pragma unroll
  for (int ks = 0; ks < 16; ++ks) r += partial[(size_t)(ks*2 + arr)*L_TOK + qi];
  ord[(size_t)arr*L_TOK + r] = (unsigned int)(keys[i] & 0x3FFFu);
}

// ---------------- layernorm / gating ----------------

__global__ __launch_bounds__(256) void ln_kernel(const float* __restrict__ in, float* __restrict__ out,
                                                 unsigned short* __restrict__ outbf,
                                                 const float* __restrict__ w, const float* __restrict__ b) {
  int row = blockIdx.x*4 + (threadIdx.x >> 6);
  int lane = threadIdx.x & 63;
  const float4 v = *(const float4*)(in + (size_t)row*DM + lane*4);
  float s = v.x + v.y + v.z + v.w;
  float mean = warp_sum(s) * (1.0f/DM);
  float4 xc = make_float4(v.x-mean, v.y-mean, v.z-mean, v.w-mean);
  float ss = xc.x*xc.x + xc.y*xc.y + xc.z*xc.z + xc.w*xc.w;
  ss = warp_sum(ss) * (1.0f/DM);
  float inv = rsqrtf(ss + EPSF);
  const float4 w4 = *(const float4*)(w + lane*4);
  const float4 b4 = *(const float4*)(b + lane*4);
  float4 o;
  o.x = xc.x*inv*w4.x + b4.x;
  o.y = xc.y*inv*w4.y + b4.y;
  o.z = xc.z*inv*w4.z + b4.z;
  o.w = xc.w*inv*w4.w + b4.w;
  *(float4*)(out + (size_t)row*DM + lane*4) = o;
  if (outbf) {
    ushort4 ob = make_ushort4(f2bf(o.x), f2bf(o.y), f2bf(o.z), f2bf(o.w));
    *(ushort4*)(outbf + (size_t)row*DM + lane*4) = ob;
  }
}

__global__ __launch_bounds__(256) void gating_kernel(unsigned short* __restrict__ ybf,
                                                     const unsigned short* __restrict__ gatebf,
                                                     const float* __restrict__ nw) {
  int row = blockIdx.x*4 + (threadIdx.x >> 6);
  int lane = threadIdx.x & 63;
  unsigned short* yr = ybf + (size_t)row*DI;
  const unsigned short* gr = gatebf + (size_t)row*DI;
  ushort4 yu0 = *(const ushort4*)(yr + lane*4);
  ushort4 yu1 = *(const ushort4*)(yr + 256 + lane*4);
  ushort4 gu0 = *(const ushort4*)(gr + lane*4);
  ushort4 gu1 = *(const ushort4*)(gr + 256 + lane*4);
  float4 y0 = make_float4(bf2f(yu0.x), bf2f(yu0.y), bf2f(yu0.z), bf2f(yu0.w));
  float4 y1 = make_float4(bf2f(yu1.x), bf2f(yu1.y), bf2f(yu1.z), bf2f(yu1.w));
  y0.x *= siluf(bf2f(gu0.x)); y0.y *= siluf(bf2f(gu0.y)); y0.z *= siluf(bf2f(gu0.z)); y0.w *= siluf(bf2f(gu0.w));
  y1.x *= siluf(bf2f(gu1.x)); y1.y *= siluf(bf2f(gu1.y)); y1.z *= siluf(bf2f(gu1.z)); y1.w *= siluf(bf2f(gu1.w));
  float ss = y0.x*y0.x + y0.y*y0.y + y0.z*y0.z + y0.w*y0.w
           + y1.x*y1.x + y1.y*y1.y + y1.z*y1.z + y1.w*y1.w;
  ss = warp_sum(ss) * (1.0f/DI);
  float inv = rsqrtf(ss + EPSF);
  const float4 w0 = *(const float4*)(nw + lane*4);
  const float4 w1 = *(const float4*)(nw + 256 + lane*4);
  y0.x *= inv*w0.x; y0.y *= inv*w0.y; y0.z *= inv*w0.z; y0.w *= inv*w0.w;
  y1.x *= inv*w1.x; y1.y *= inv*w1.y; y1.z *= inv*w1.z; y1.w *= inv*w1.w;
  *(ushort4*)(yr + lane*4)       = make_ushort4(f2bf(y0.x), f2bf(y0.y), f2bf(y0.z), f2bf(y0.w));
  *(ushort4*)(yr + 256 + lane*4) = make_ushort4(f2bf(y1.x), f2bf(y1.y), f2bf(y1.z), f2bf(y1.w));
}

// ---------------- weight transpose+convert ----------------

__global__ __launch_bounds__(256) void tcvt_both(const float* __restrict__ Wi, const float* __restrict__ Wo,
                                                 unsigned short* __restrict__ WtA, unsigned short* __restrict__ WtO) {
  int idx = blockIdx.x*256 + threadIdx.x;
  if (idx < 1152*DM) {
    int n = idx >> 8, k = idx & 255;
    WtA[idx] = f2bf(Wi[(size_t)k*DP + n]);
  } else {
    int j = idx - 1152*DM;
    int n = j >> 9, k = j & 511;
    WtO[j] = f2bf(Wo[(size_t)k*DM + n]);
  }
}

// ---------------- MFMA GEMMs ----------------

__global__ __launch_bounds__(256) void gemm_in_mfma(const unsigned short* __restrict__ Abf,
                                                    const unsigned short* __restrict__ Wt,
                                                    const unsigned int* __restrict__ ordp,
                                                    unsigned short* __restrict__ gatebf,
                                                    unsigned short* __restrict__ xbcbf) {
  __shared__ unsigned short Alds[128*64];
  __shared__ unsigned short Blds[128*64];
  int tid = threadIdx.x, lane = tid & 63, w = tid >> 6;
  int rb = blockIdx.y*128, cb = blockIdx.x*128;
  int wm = (w & 1)*64, wn = (w >> 1)*64;
  const unsigned short* pA[4]; const unsigned short* pB[4];
  unsigned short* dA[4]; unsigned short* dB[4];
  #pragma unroll
  for (int s = 0; s < 4; ++s) {
    int inst = w*4 + s;
    int r = inst*8 + (lane >> 3);
    int cA = (lane & 7) ^ (r & 7);
    pA[s] = Abf + (size_t)ordp[rb + r]*DM + cA*8;
    pB[s] = Wt + (size_t)(cb + r)*DM + cA*8;
    dA[s] = &Alds[inst*512];
    dB[s] = &Blds[inst*512];
  }
  f32x4 zero = {0.f, 0.f, 0.f, 0.f};
  f32x4 acc[4][4];
  #pragma unroll
  for (int i = 0; i < 4; ++i)
    #pragma unroll
    for (int j = 0; j < 4; ++j) acc[i][j] = zero;
  int t = lane & 15, q = lane >> 4;
  for (int k0 = 0; k0 < DM; k0 += 64) {
    #pragma unroll
    for (int s = 0; s < 4; ++s) GLL16(pA[s] + k0, dA[s]);
    #pragma unroll
    for (int s = 0; s < 4; ++s) GLL16(pB[s] + k0, dB[s]);
    __syncthreads();
    #pragma unroll
    for (int ks = 0; ks < 2; ++ks) {
      short8 af[4], bfr[4];
      int cc = ks*4 + q;
      #pragma unroll
      for (int i = 0; i < 4; ++i) {
        int rr = wm + 16*i + t;
        af[i] = *(const short8*)&Alds[rr*64 + ((cc ^ (rr & 7))*8)];
      }
      #pragma unroll
      for (int j = 0; j < 4; ++j) {
        int rr = wn + 16*j + t;
        bfr[j] = *(const short8*)&Blds[rr*64 + ((cc ^ (rr & 7))*8)];
      }
      #pragma unroll
      for (int i = 0; i < 4; ++i)
        #pragma unroll
        for (int j = 0; j < 4; ++j)
          acc[i][j] = __builtin_amdgcn_mfma_f32_16x16x32_bf16(af[i], bfr[j], acc[i][j], 0, 0, 0);
    }
    __syncthreads();
  }
  unsigned short* dst; int ld;
  if (cb < DI) { dst = gatebf + cb; ld = DI; }
  else         { dst = xbcbf + (cb - DI); ld = CD; }
  #pragma unroll
  for (int i = 0; i < 4; ++i) {
    int rowb = rb + wm + 16*i + q*4;
    #pragma unroll
    for (int j = 0; j < 4; ++j) {
      int col = wn + 16*j + t;
      #pragma unroll
      for (int r = 0; r < 4; ++r)
        dst[(size_t)(rowb + r)*ld + col] = f2bf(acc[i][j][r]);
    }
  }
}

__global__ __launch_bounds__(256) void gemm_out_mfma(const unsigned short* __restrict__ Abf,
                                                     const unsigned short* __restrict__ Wt,
                                                     const unsigned int* __restrict__ ordp,
                                                     float* __restrict__ out) {
  __shared__ unsigned short Alds[128*64];
  __shared__ unsigned short Blds[128*64];
  __shared__ unsigned int ordl[128];
  int tid = threadIdx.x, lane = tid & 63, w = tid >> 6;
  int rb = blockIdx.y*128, cb = blockIdx.x*128;
  int wm = (w & 1)*64, wn = (w >> 1)*64;
  if (tid < 128) ordl[tid] = ordp[rb + tid];
  const unsigned short* pA[4]; const unsigned short* pB[4];
  unsigned short* dA[4]; unsigned short* dB[4];
  #pragma unroll
  for (int s = 0; s < 4; ++s) {
    int inst = w*4 + s;
    int r = inst*8 + (lane >> 3);
    int cA = (lane & 7) ^ (r & 7);
    pA[s] = Abf + (size_t)(rb + r)*DI + cA*8;
    pB[s] = Wt + (size_t)(cb + r)*DI + cA*8;
    dA[s] = &Alds[inst*512];
    dB[s] = &Blds[inst*512];
  }
  f32x4 zero = {0.f, 0.f, 0.f, 0.f};
  f32x4 acc[4][4];
  #pragma unroll
  for (int i = 0; i < 4; ++i)
    #pragma unroll
    for (int j = 0; j < 4; ++j) acc[i][j] = zero;
  int t = lane & 15, q = lane >> 4;
  for (int k0 = 0; k0 < DI; k0 += 64) {
    #pragma unroll
    for (int s = 0; s < 4; ++s) GLL16(pA[s] + k0, dA[s]);
    #pragma unroll
    for (int s = 0; s < 4; ++s) GLL16(pB[s] + k0, dB[s]);
    __syncthreads();
    #pragma unroll
    for (int ks = 0; ks < 2; ++ks) {
      short8 af[4], bfr[4];
      int cc = ks*4 + q;
      #pragma unroll
      for (int i = 0; i < 4; ++i) {
        int rr = wm + 16*i + t;
        af[i] = *(const short8*)&Alds[rr*64 + ((cc ^ (rr & 7))*8)];
      }
      #pragma unroll
      for (int j = 0; j < 4; ++j) {
        int rr = wn + 16*j + t;
        bfr[j] = *(const short8*)&Blds[rr*64 + ((cc ^ (rr & 7))*8)];
      }
      #pragma unroll
      for (int i = 0; i < 4; ++i)
        #pragma unroll
        for (int j = 0; j < 4; ++j)
          acc[i][j] = __builtin_amdgcn_mfma_f32_16x16x32_bf16(af[i], bfr[j], acc[i][j], 0, 0, 0);
    }
    __syncthreads();
  }
  #pragma unroll
  for (int i = 0; i < 4; ++i) {
    #pragma unroll
    for (int r = 0; r < 4; ++r) {
      unsigned int tok = ordl[wm + 16*i + q*4 + r];
      float* op = out + (size_t)tok*DM + cb;
      #pragma unroll
      for (int j = 0; j < 4; ++j) {
        int col = wn + 16*j + t;
        op[col] += 0.5f*acc[i][j][r];
      }
    }
  }
}

// ---------------- dt path (fp32, fused softplus) ----------------
__global__ __launch_bounds__(256) void dt_gemv(const float* __restrict__ qn, const float* __restrict__ W,
                                               const unsigned int* __restrict__ ordp,
                                               const float* __restrict__ dt_bias, float* __restrict__ dtb) {
  int row = blockIdx.x*4 + (threadIdx.x >> 6);
  int lane = threadIdx.x & 63;
  unsigned int src = ordp[row];
  const float4 q4 = *(const float4*)(qn + (size_t)src*DM + lane*4);
  float a[8] = {0,0,0,0,0,0,0,0};
  const float* wp = W + (size_t)(lane*4)*DP + (DI + CD);
  float qe[4] = {q4.x, q4.y, q4.z, q4.w};
  #pragma unroll
  for (int e = 0; e < 4; ++e) {
    float4 wa = *(const float4*)(wp + (size_t)e*DP);
    float4 wb = *(const float4*)(wp + (size_t)e*DP + 4);
    a[0] += qe[e]*wa.x; a[1] += qe[e]*wa.y; a[2] += qe[e]*wa.z; a[3] += qe[e]*wa.w;
    a[4] += qe[e]*wb.x; a[5] += qe[e]*wb.y; a[6] += qe[e]*wb.z; a[7] += qe[e]*wb.w;
  }
  #pragma unroll
  for (int h = 0; h < 8; ++h) a[h] = warp_sum(a[h]);
  float v = 0.0f;
  #pragma unroll
  for (int h = 0; h < 8; ++h) if (lane == h) v = a[h];
  if (lane < 8) {
    v += dt_bias[lane];
    float sp = (v > 0.0f) ? (v + log1pf(expf(-v))) : log1pf(expf(v));
    dtb[(size_t)row*NH + lane] = sp;
  }
}

// ---------------- conv: register-blocked, 8 channels x 8 tokens per thread ----------------
// 640 blocks x 256 threads = 163840 threads = 80 ch-groups x 2048 token-strips.

__global__ __launch_bounds__(256) void conv_kernel(const unsigned short* __restrict__ xbc, const float* __restrict__ cw,
                                                   const float* __restrict__ cbias, unsigned short* __restrict__ outc) {
  int gid = blockIdx.x*256 + threadIdx.x;
  int g = gid % 80;
  int ts = gid / 80;           // 0..2047
  int t0 = ts*8;
  int ch = g*8;
  float wv[8][4];
  float bias[8];
  #pragma unroll
  for (int e = 0; e < 8; ++e) {
    float4 c4 = *(const float4*)(cw + (ch + e)*4);
    wv[e][0] = c4.x; wv[e][1] = c4.y; wv[e][2] = c4.z; wv[e][3] = c4.w;
  }
  {
    float4 b0 = *(const float4*)(cbias + ch);
    float4 b1 = *(const float4*)(cbias + ch + 4);
    bias[0]=b0.x; bias[1]=b0.y; bias[2]=b0.z; bias[3]=b0.w;
    bias[4]=b1.x; bias[5]=b1.y; bias[6]=b1.z; bias[7]=b1.w;
  }
  float rows[11][8];
  #pragma unroll
  for (int r = 0; r < 11; ++r) {
    int t = t0 - 3 + r;
    if (t >= 0) {
      short8 v = *(const short8*)(xbc + (size_t)t*CD + ch);
      #pragma unroll
      for (int e = 0; e < 8; ++e) rows[r][e] = bf2f((unsigned short)v[e]);
    } else {
      #pragma unroll
      for (int e = 0; e < 8; ++e) rows[r][e] = 0.f;
    }
  }
  #pragma unroll
  for (int tt = 0; tt < 8; ++tt) {
    short8 o;
    #pragma unroll
    for (int e = 0; e < 8; ++e) {
      float s = bias[e];
      #pragma unroll
      for (int k = 0; k < 4; ++k)
        s = fmaf(wv[e][k], rows[tt + k][e], s);
      o[e] = (short)f2bf(siluf(s));
    }
    *(short8*)(outc + (size_t)(t0 + tt)*CD + ch) = o;
  }
}

// ---------------- chunked scan (MFMA, bf16 S) ----------------

__global__ __launch_bounds__(256) void phaseA_mfma(const unsigned short* __restrict__ xc,
                                                   const float* __restrict__ dtb, const float* __restrict__ A_log,
                                                   unsigned short* __restrict__ S, float* __restrict__ P) {
  int c = blockIdx.x, h = blockIdx.y, tid = threadIdx.x;
  int lane = tid & 63, w = tid >> 6;
  __shared__ unsigned short xT[64*64];
  __shared__ unsigned short Bt[64*64];
  __shared__ float dts[64], lg[64], sfx[64], wgt[64];
  __shared__ float totals;
  int c0 = c*CHUNK;
  float Ah = -expf(A_log[h]);
  if (tid < 64) {
    float dtv = dtb[(size_t)(c0+tid)*NH + h];
    dts[tid] = dtv; lg[tid] = dtv*Ah;
  }
  #pragma unroll
  for (int i = 0; i < 2; ++i) {
    int q = tid + 256*i;
    int t = q >> 3, s0 = (q & 7)*8;
    short8 v = *(const short8*)(xc + (size_t)(c0+t)*CD + DI + s0);
    int tc = t >> 3, ti = t & 7;
    #pragma unroll
    for (int e = 0; e < 8; ++e) {
      int s = s0 + e;
      Bt[s*64 + ((tc ^ (s & 7))*8 + ti)] = (unsigned short)v[e];
    }
  }
  __syncthreads();
  if (tid == 0) {
    float run = 0.f;
    for (int t = 63; t >= 0; --t) { sfx[t] = run; run += lg[t]; }
    totals = run;
  }
  __syncthreads();
  if (tid < 64) wgt[tid] = dts[tid]*expf(sfx[tid]);
  if (tid == 0) P[h*NC + c] = expf(totals);
  __syncthreads();
  #pragma unroll
  for (int i = 0; i < 2; ++i) {
    int q = tid + 256*i;
    int t = q >> 3, p0 = (q & 7)*8;
    short8 v = *(const short8*)(xc + (size_t)(c0+t)*CD + h*HD + p0);
    float wvv = wgt[t];
    int tc = t >> 3, ti = t & 7;
    #pragma unroll
    for (int e = 0; e < 8; ++e) {
      int p = p0 + e;
      xT[p*64 + ((tc ^ (p & 7))*8 + ti)] = f2bf(bf2f((unsigned short)v[e]) * wvv);
    }
  }
  __syncthreads();
  int t16 = lane & 15, q4 = lane >> 4;
  f32x4 zero = {0.f,0.f,0.f,0.f};
  f32x4 acc[4];
  #pragma unroll
  for (int j = 0; j < 4; ++j) acc[j] = zero;
  #pragma unroll
  for (int ks = 0; ks < 2; ++ks) {
    int rowA = 16*w + t16;
    short8 a = *(const short8*)&xT[rowA*64 + (((ks*4 + q4) ^ (rowA & 7))*8)];
    #pragma unroll
    for (int j = 0; j < 4; ++j) {
      int rowB = 16*j + t16;
      short8 b = *(const short8*)&Bt[rowB*64 + (((ks*4 + q4) ^ (rowB & 7))*8)];
      acc[j] = __builtin_amdgcn_mfma_f32_16x16x32_bf16(a, b, acc[j], 0, 0, 0);
    }
  }
  unsigned short* Sp = S + ((size_t)(h*NC + c))*4096;
  #pragma unroll
  for (int j = 0; j < 4; ++j)
    #pragma unroll
    for (int r = 0; r < 4; ++r)
      Sp[(size_t)(16*w + q4*4 + r)*64 + 16*j + t16] = f2bf(acc[j][r]);
}

// ---- phaseB split: 16 superchunks x 16 chunks, fp32 carry, bf16 storage ----

__global__ __launch_bounds__(256) void phaseB1(const unsigned short* __restrict__ S, const float* __restrict__ P,
                                               float* __restrict__ Ssum, float* __restrict__ Psum) {
  int gid = blockIdx.x*256 + threadIdx.x;
  int e2 = gid & 2047;
  int sc = (gid >> 11) & 15;
  int h  = gid >> 15;
  const unsigned short* base = S + ((size_t)(h*NC + sc*16))*4096 + e2*2;
  const float* Ph = P + h*NC + sc*16;
  float hx = 0.f, hy = 0.f, pprod = 1.f;
  #pragma unroll
  for (int k = 0; k < 16; ++k) {
    unsigned int v = *(const unsigned int*)(base + (size_t)k*4096);
    float p = Ph[k];
    hx = p*hx + bf2f((unsigned short)(v & 0xffffu));
    hy = p*hy + bf2f((unsigned short)(v >> 16));
    pprod *= p;
  }
  float* sp = Ssum + ((size_t)(h*16 + sc))*4096 + e2*2;
  sp[0] = hx; sp[1] = hy;
  if (e2 == 0) Psum[h*16 + sc] = pprod;
}

__global__ __launch_bounds__(256) void phaseB3(unsigned short* __restrict__ S, const float* __restrict__ P,
                                               const float* __restrict__ Ssum, const float* __restrict__ Psum) {
  int gid = blockIdx.x*256 + threadIdx.x;
  int e2 = gid & 2047;
  int sc = (gid >> 11) & 15;
  int h  = gid >> 15;
  float hx = 0.f, hy = 0.f;
  for (int s2 = 0; s2 < sc; ++s2) {
    float pp = Psum[h*16 + s2];
    const float* sp = Ssum + ((size_t)(h*16 + s2))*4096 + e2*2;
    hx = pp*hx + sp[0];
    hy = pp*hy + sp[1];
  }
  unsigned short* base = S + ((size_t)(h*NC + sc*16))*4096 + e2*2;
  const float* Ph = P + h*NC + sc*16;
  #pragma unroll
  for (int k = 0; k < 16; ++k) {
    unsigned int* ptr = (unsigned int*)(base + (size_t)k*4096);
    unsigned int v = *ptr;
    float p = Ph[k];
    *ptr = (unsigned int)f2bf(hx) | ((unsigned int)f2bf(hy) << 16);
    hx = p*hx + bf2f((unsigned short)(v & 0xffffu));
    hy = p*hy + bf2f((unsigned short)(v >> 16));
  }
}

// phaseC: Y bf16 out
__global__ __launch_bounds__(256) void phaseC_mfma(const unsigned short* __restrict__ xc,
                                                   const float* __restrict__ dtb, const float* __restrict__ A_log,
                                                   const float* __restrict__ Dp,
                                                   const unsigned short* __restrict__ S,
                                                   unsigned short* __restrict__ y) {
  int c = blockIdx.x, h = blockIdx.y, tid = threadIdx.x;
  int lane = tid & 63, w = tid >> 6;
  __shared__ unsigned short Cl[64*64];
  __shared__ unsigned short Bl[64*64];
  __shared__ unsigned short h0l[64*64];
  __shared__ unsigned short xT[64*64];
  __shared__ unsigned short Gl[64*64];
  __shared__ float dts[64], lg[64], pl[64], pe[64];
  int c0 = c*CHUNK;
  float Ah = -expf(A_log[h]);
  float Dh = Dp[h];
  if (tid < 64) {
    float dtv = dtb[(size_t)(c0+tid)*NH + h];
    dts[tid] = dtv; lg[tid] = dtv*Ah;
  }
  const unsigned short* Sp = S + ((size_t)(h*NC + c))*4096;
  #pragma unroll
  for (int i = 0; i < 2; ++i) {
    int q = tid + 256*i;
    int t = q >> 3, d0 = (q & 7)*8;
    int swoff = t*64 + (((q & 7) ^ (t & 7))*8);
    *(short8*)&Cl[swoff] = *(const short8*)(xc + (size_t)(c0+t)*CD + DI + DS + d0);
    *(short8*)&Bl[swoff] = *(const short8*)(xc + (size_t)(c0+t)*CD + DI + d0);
    *(short8*)&h0l[swoff] = *(const short8*)(Sp + (size_t)t*64 + d0);
    short8 xv = *(const short8*)(xc + (size_t)(c0+t)*CD + h*HD + d0);
    int tc = t >> 3, ti = t & 7;
    #pragma unroll
    for (int e = 0; e < 8; ++e) {
      int p = d0 + e;
      xT[p*64 + ((tc ^ (p & 7))*8 + ti)] = (unsigned short)xv[e];
    }
  }
  __syncthreads();
  if (tid == 0) {
    float run = 0.f;
    for (int t = 0; t < 64; ++t) { run += lg[t]; pl[t] = run; }
  }
  __syncthreads();
  if (tid < 64) pe[tid] = expf(pl[tid]);
  __syncthreads();
  int t16 = lane & 15, q4 = lane >> 4;
  int t0 = 16*w;
  f32x4 zero = {0.f,0.f,0.f,0.f};
  f32x4 accG[4], accY[4];
  #pragma unroll
  for (int j = 0; j < 4; ++j) { accG[j] = zero; accY[j] = zero; }
  #pragma unroll
  for (int ks = 0; ks < 2; ++ks) {
    int rowA = t0 + t16;
    short8 a = *(const short8*)&Cl[rowA*64 + (((ks*4 + q4) ^ (rowA & 7))*8)];
    #pragma unroll
    for (int j = 0; j < 4; ++j) {
      int rowB = 16*j + t16;
      int off = rowB*64 + (((ks*4 + q4) ^ (rowB & 7))*8);
      accG[j] = __builtin_amdgcn_mfma_f32_16x16x32_bf16(a, *(const short8*)&Bl[off], accG[j], 0, 0, 0);
      accY[j] = __builtin_amdgcn_mfma_f32_16x16x32_bf16(a, *(const short8*)&h0l[off], accY[j], 0, 0, 0);
    }
  }
  #pragma unroll
  for (int j = 0; j < 4; ++j) {
    #pragma unroll
    for (int r = 0; r < 4; ++r) {
      int t = t0 + q4*4 + r;
      int s = 16*j + t16;
      float v = 0.f;
      if (s <= t) {
        v = accG[j][r] * dts[s] * expf(pl[t] - pl[s]);
        if (s == t) v += Dh;
      }
      Gl[t*64 + (((s >> 3) ^ (t & 7))*8 + (s & 7))] = f2bf(v);
    }
  }
  #pragma unroll
  for (int j = 0; j < 4; ++j)
    #pragma unroll
    for (int r = 0; r < 4; ++r)
      accY[j][r] *= pe[t0 + q4*4 + r];
  #pragma unroll
  for (int ks = 0; ks < 2; ++ks) {
    int rowA = t0 + t16;
    short8 a = *(const short8*)&Gl[rowA*64 + (((ks*4 + q4) ^ (rowA & 7))*8)];
    #pragma unroll
    for (int j = 0; j < 4; ++j) {
      int rowB = 16*j + t16;
      short8 b = *(const short8*)&xT[rowB*64 + (((ks*4 + q4) ^ (rowB & 7))*8)];
      accY[j] = __builtin_amdgcn_mfma_f32_16x16x32_bf16(a, b, accY[j], 0, 0, 0);
    }
  }
  #pragma unroll
  for (int j = 0; j < 4; ++j)
    #pragma unroll
    for (int r = 0; r < 4; ++r) {
      int t = t0 + q4*4 + r;
      int p = 16*j + t16;
      y[(size_t)(c0+t)*DI + h*HD + p] = f2bf(accY[j][r]);
    }
}

__global__ void fill_debug(float* out, float v) {
  int i = blockIdx.x*256 + threadIdx.x;
  if (i < L_TOK*DM) out[i] = v;
}

// ---------------- host ----------------

extern "C" void kernel_launch(void* const* d_in, const int* in_sizes, int n_in,
                              void* d_out, int out_size, void* d_ws, size_t ws_size,
                              hipStream_t stream) {
  const float* query = (const float*)d_in[0];
  const float* qpos  = (const float*)d_in[1];
  const float* pre_w = (const float*)d_in[2];
  const float* pre_b = (const float*)d_in[3];
  const float* fin_w = (const float*)d_in[4];
  const float* fin_b = (const float*)d_in[5];
  float* out = (float*)d_out;

  char* ws = (char*)d_ws;
  size_t off = 0;
  auto alloc = [&](size_t bytes) -> void* {
    void* p = ws + off;
    off += (bytes + 255) & ~(size_t)255;
    return p;
  };
  unsigned long long* keys = (unsigned long long*)alloc((size_t)2*L_TOK*8);
  unsigned int* ord = (unsigned int*)alloc((size_t)2*L_TOK*4);
  unsigned int* rpart = (unsigned int*)alloc((size_t)16*2*L_TOK*4);
  float* pmm  = (float*)alloc(256);
  float* qn   = (float*)alloc((size_t)L_TOK*DM*4);
  unsigned short* qnbf = (unsigned short*)alloc((size_t)L_TOK*DM*2);
  unsigned short* gatebf = (unsigned short*)alloc((size_t)L_TOK*DI*2);
  unsigned short* xbcbf  = (unsigned short*)alloc((size_t)L_TOK*CD*2);
  unsigned short* convo = (unsigned short*)alloc((size_t)L_TOK*CD*2);
  float* dtb  = (float*)alloc((size_t)L_TOK*NH*4);
  unsigned short* Sbuf = (unsigned short*)alloc((size_t)NH*NC*4096*2);
  float* Pbuf = (float*)alloc((size_t)NH*NC*4);
  float* Ssum = (float*)alloc((size_t)NH*16*4096*4);
  float* Psum = (float*)alloc((size_t)NH*16*4);
  unsigned short* ybf = (unsigned short*)alloc((size_t)L_TOK*DI*2);
  unsigned short* WtA = (unsigned short*)alloc((size_t)1152*DM*2);
  unsigned short* WtO = (unsigned short*)alloc((size_t)DM*DI*2);
  if (off > ws_size) {
    fill_debug<<<(L_TOK*DM + 255)/256, 256, 0, stream>>>(out, (float)(ws_size >> 20));
    return;
  }

  minmax_kernel<<<1, 256, 0, stream>>>(qpos, pmm);
  hilbert_kernel<<<L_TOK/256, 256, 0, stream>>>(qpos, pmm, keys);
  rank_partial<<<dim3(8, 2, 16), 256, 0, stream>>>(keys, rpart);
  rank_scatter<<<(2*L_TOK)/256, 256, 0, stream>>>(keys, rpart, ord);
  hipMemcpyAsync(out, query, (size_t)L_TOK*DM*4, hipMemcpyDeviceToDevice, stream);

  for (int l = 0; l < 2; ++l) {
    int base = 6 + 8*l;
    const float* in_proj  = (const float*)d_in[base+0];
    const float* conv_w   = (const float*)d_in[base+1];
    const float* conv_b   = (const float*)d_in[base+2];
    const float* dt_bias  = (const float*)d_in[base+3];
    const float* A_log    = (const float*)d_in[base+4];
    const float* Dp       = (const float*)d_in[base+5];
    const float* norm_w   = (const float*)d_in[base+6];
    const float* out_proj = (const float*)d_in[base+7];

    ln_kernel<<<L_TOK/4, 256, 0, stream>>>(out, qn, qnbf, pre_w, pre_b);
    tcvt_both<<<(1152*DM + DM*DI)/256, 256, 0, stream>>>(in_proj, out_proj, WtA, WtO);
    for (int dir = 0; dir < 2; ++dir) {
      const unsigned int* o = ord + (size_t)dir*L_TOK;
      gemm_in_mfma<<<dim3(9, L_TOK/128), 256, 0, stream>>>(qnbf, WtA, o, gatebf, xbcbf);
      dt_gemv<<<L_TOK/4, 256, 0, stream>>>(qn, in_proj, o, dt_bias, dtb);
      conv_kernel<<<640, 256, 0, stream>>>(xbcbf, conv_w, conv_b, convo);
      phaseA_mfma<<<dim3(NC, NH), 256, 0, stream>>>(convo, dtb, A_log, Sbuf, Pbuf);
      phaseB1<<<(NH*16*2048)/256, 256, 0, stream>>>(Sbuf, Pbuf, Ssum, Psum);
      phaseB3<<<(NH*16*2048)/256, 256, 0, stream>>>(Sbuf, Pbuf, Ssum, Psum);
      phaseC_mfma<<<dim3(NC, NH), 256, 0, stream>>>(convo, dtb, A_log, Dp, Sbuf, ybf);
      gating_kernel<<<L_TOK/4, 256, 0, stream>>>(ybf, gatebf, norm_w);
      gemm_out_mfma<<<dim3(2, L_TOK/128), 256, 0, stream>>>(ybf, WtO, o, out);
    }
    ln_kernel<<<L_TOK/4, 256, 0, stream>>>(out, out, (unsigned short*)nullptr, fin_w, fin_b);
  }
}

// Round 8
// 693.671 us; speedup vs baseline: 1.8015x; 1.1073x over previous
//
#include <hip/hip_runtime.h>
#include <stdint.h>

#define L_TOK 16384
#define DM 256
#define DI 512
#define DS 64
#define NH 8
#define HD 64
#define CD 640
#define DP 1160
#define CHUNK 64
#define NC 256
#define EPSF 1e-5f

typedef __attribute__((ext_vector_type(8))) short short8;
typedef __attribute__((ext_vector_type(4))) float f32x4;

#define GLL16(gp, lp) __builtin_amdgcn_global_load_lds((const __attribute__((address_space(1))) void*)(gp), (__attribute__((address_space(3))) void*)(lp), 16, 0, 0)

__device__ __forceinline__ float warp_sum(float v) {
  v += __shfl_xor(v, 1, 64);
  v += __shfl_xor(v, 2, 64);
  v += __shfl_xor(v, 4, 64);
  v += __shfl_xor(v, 8, 64);
  v += __shfl_xor(v, 16, 64);
  v += __shfl_xor(v, 32, 64);
  return v;
}

__device__ __forceinline__ float siluf(float x) { return x / (1.0f + expf(-x)); }

__device__ __forceinline__ unsigned short f2bf(float f) {
  unsigned int u = __float_as_uint(f);
  unsigned int r = (u + 0x7FFFu + ((u >> 16) & 1u)) >> 16;
  return (unsigned short)r;
}
__device__ __forceinline__ float bf2f(unsigned short u) {
  return __uint_as_float(((unsigned int)u) << 16);
}

// ---------------- serialization ----------------

__global__ __launch_bounds__(256) void minmax_kernel(const float* __restrict__ pos, float* __restrict__ pmm) {
  __shared__ float sm[6][256];
  int tid = threadIdx.x;
  float mn0=1e30f, mn1=1e30f, mn2=1e30f, mx0=-1e30f, mx1=-1e30f, mx2=-1e30f;
  for (int t = tid; t < L_TOK; t += 256) {
    float a = pos[t*3+0], b = pos[t*3+1], c = pos[t*3+2];
    mn0=fminf(mn0,a); mx0=fmaxf(mx0,a);
    mn1=fminf(mn1,b); mx1=fmaxf(mx1,b);
    mn2=fminf(mn2,c); mx2=fmaxf(mx2,c);
  }
  sm[0][tid]=mn0; sm[1][tid]=mn1; sm[2][tid]=mn2;
  sm[3][tid]=mx0; sm[4][tid]=mx1; sm[5][tid]=mx2;
  __syncthreads();
  for (int s = 128; s > 0; s >>= 1) {
    if (tid < s) {
      #pragma unroll
      for (int d = 0; d < 3; ++d) {
        sm[d][tid]   = fminf(sm[d][tid],   sm[d][tid+s]);
        sm[3+d][tid] = fmaxf(sm[3+d][tid], sm[3+d][tid+s]);
      }
    }
    __syncthreads();
  }
  if (tid < 6) pmm[tid] = sm[tid][0];
}

__device__ unsigned int hilbert3(unsigned int a, unsigned int b, unsigned int c) {
  unsigned int x0 = a, x1 = b, x2 = c;
  for (unsigned int Q = 512u; Q > 1u; Q >>= 1) {
    unsigned int P = Q - 1u;
    { if (x0 & Q) x0 ^= P; }
    {
      unsigned int t = (x0 ^ x1) & P;
      if (x1 & Q) { x0 ^= P; }
      else { x0 ^= t; x1 ^= t; }
    }
    {
      unsigned int t = (x0 ^ x2) & P;
      if (x2 & Q) { x0 ^= P; }
      else { x0 ^= t; x2 ^= t; }
    }
  }
  x1 ^= x0; x2 ^= x1;
  unsigned int tt = 0;
  for (unsigned int Q = 512u; Q > 1u; Q >>= 1)
    if (x2 & Q) tt ^= (Q - 1u);
  x0 ^= tt; x1 ^= tt; x2 ^= tt;
  unsigned int code = 0;
  #pragma unroll
  for (int bb = 9; bb >= 0; --bb) {
    code = (code << 1) | ((x0 >> bb) & 1u);
    code = (code << 1) | ((x1 >> bb) & 1u);
    code = (code << 1) | ((x2 >> bb) & 1u);
  }
  return code;
}

__global__ __launch_bounds__(256) void hilbert_kernel(const float* __restrict__ pos, const float* __restrict__ pmm,
                                                      unsigned long long* __restrict__ keys) {
  int t = blockIdx.x*256 + threadIdx.x;
  if (t >= L_TOK) return;
  unsigned int g[3];
  #pragma unroll
  for (int d = 0; d < 3; ++d) {
    float v = (pos[t*3+d] - pmm[d]) / (pmm[3+d] - pmm[d] + 1e-6f) * 1023.0f;
    v = fminf(fmaxf(v, 0.0f), 1023.0f);
    g[d] = (unsigned int)(int)v;
  }
  unsigned int ca = hilbert3(g[0], g[1], g[2]);
  unsigned int cb = hilbert3(g[1], g[0], g[2]);
  keys[t]         = ((unsigned long long)ca << 14) | (unsigned long long)t;
  keys[L_TOK + t] = ((unsigned long long)cb << 14) | (unsigned long long)t;
}

// all-pairs rank, 4 q/thread, 512-key tiles, 32 splits -> 1024 blocks (4/CU, 16 waves/CU)
__global__ __launch_bounds__(256) void rank_partial(const unsigned long long* __restrict__ keys,
                                                    unsigned int* __restrict__ partial) {
  __shared__ unsigned long long tile[512];
  int arr = blockIdx.y, ks = blockIdx.z;
  const unsigned long long* k = keys + (size_t)arr * L_TOK;
  int qbase = blockIdx.x*1024 + threadIdx.x;
  unsigned long long q[4];
  #pragma unroll
  for (int i = 0; i < 4; ++i) q[i] = k[qbase + 256*i];
  const unsigned long long* src = k + ks*512;
  #pragma unroll
  for (int t = 0; t < 2; ++t) tile[threadIdx.x + 256*t] = src[threadIdx.x + 256*t];
  __syncthreads();
  unsigned int r[4] = {};
  const ulonglong2* t2 = (const ulonglong2*)tile;
  #pragma unroll 4
  for (int j = 0; j < 256; ++j) {
    ulonglong2 v = t2[j];
    #pragma unroll
    for (int i = 0; i < 4; ++i) {
      r[i] += (v.x < q[i]) ? 1u : 0u;
      r[i] += (v.y < q[i]) ? 1u : 0u;
    }
  }
  #pragma unroll
  for (int i = 0; i < 4; ++i)
    partial[(size_t)(ks*2 + arr)*L_TOK + qbase + 256*i] = r[i];
}

__global__ __launch_bounds__(256) void rank_scatter(const unsigned long long* __restrict__ keys,
                                                    const unsigned int* __restrict__ partial,
                                                    unsigned int* __restrict__ ord) {
  int i = blockIdx.x*256 + threadIdx.x;
  int arr = i >> 14;
  int qi = i & (L_TOK - 1);
  unsigned int r = 0;
  #pragma unroll
  for (int ks = 0; ks < 32; ++ks) r += partial[(size_t)(ks*2 + arr)*L_TOK + qi];
  ord[(size_t)arr*L_TOK + r] = (unsigned int)(keys[i] & 0x3FFFu);
}

// ---------------- layernorm / gating ----------------

__global__ __launch_bounds__(256) void ln_kernel(const float* __restrict__ in, float* __restrict__ out,
                                                 unsigned short* __restrict__ outbf,
                                                 const float* __restrict__ w, const float* __restrict__ b) {
  int row = blockIdx.x*4 + (threadIdx.x >> 6);
  int lane = threadIdx.x & 63;
  const float4 v = *(const float4*)(in + (size_t)row*DM + lane*4);
  float s = v.x + v.y + v.z + v.w;
  float mean = warp_sum(s) * (1.0f/DM);
  float4 xc = make_float4(v.x-mean, v.y-mean, v.z-mean, v.w-mean);
  float ss = xc.x*xc.x + xc.y*xc.y + xc.z*xc.z + xc.w*xc.w;
  ss = warp_sum(ss) * (1.0f/DM);
  float inv = rsqrtf(ss + EPSF);
  const float4 w4 = *(const float4*)(w + lane*4);
  const float4 b4 = *(const float4*)(b + lane*4);
  float4 o;
  o.x = xc.x*inv*w4.x + b4.x;
  o.y = xc.y*inv*w4.y + b4.y;
  o.z = xc.z*inv*w4.z + b4.z;
  o.w = xc.w*inv*w4.w + b4.w;
  *(float4*)(out + (size_t)row*DM + lane*4) = o;
  if (outbf) {
    ushort4 ob = make_ushort4(f2bf(o.x), f2bf(o.y), f2bf(o.z), f2bf(o.w));
    *(ushort4*)(outbf + (size_t)row*DM + lane*4) = ob;
  }
}

// merged dirs: row spans 2L; y lives in xbc buffer (stride DI within dir region of stride CD rows)
__global__ __launch_bounds__(256) void gating_kernel(unsigned short* __restrict__ ybase,
                                                     const unsigned short* __restrict__ gatebf,
                                                     const float* __restrict__ nw) {
  int row = blockIdx.x*4 + (threadIdx.x >> 6);
  int lane = threadIdx.x & 63;
  int dir = row >> 14, lrow = row & (L_TOK - 1);
  unsigned short* yr = ybase + (size_t)dir*L_TOK*CD + (size_t)lrow*DI;
  const unsigned short* gr = gatebf + (size_t)dir*L_TOK*DI + (size_t)lrow*DI;
  ushort4 yu0 = *(const ushort4*)(yr + lane*4);
  ushort4 yu1 = *(const ushort4*)(yr + 256 + lane*4);
  ushort4 gu0 = *(const ushort4*)(gr + lane*4);
  ushort4 gu1 = *(const ushort4*)(gr + 256 + lane*4);
  float4 y0 = make_float4(bf2f(yu0.x), bf2f(yu0.y), bf2f(yu0.z), bf2f(yu0.w));
  float4 y1 = make_float4(bf2f(yu1.x), bf2f(yu1.y), bf2f(yu1.z), bf2f(yu1.w));
  y0.x *= siluf(bf2f(gu0.x)); y0.y *= siluf(bf2f(gu0.y)); y0.z *= siluf(bf2f(gu0.z)); y0.w *= siluf(bf2f(gu0.w));
  y1.x *= siluf(bf2f(gu1.x)); y1.y *= siluf(bf2f(gu1.y)); y1.z *= siluf(bf2f(gu1.z)); y1.w *= siluf(bf2f(gu1.w));
  float ss = y0.x*y0.x + y0.y*y0.y + y0.z*y0.z + y0.w*y0.w
           + y1.x*y1.x + y1.y*y1.y + y1.z*y1.z + y1.w*y1.w;
  ss = warp_sum(ss) * (1.0f/DI);
  float inv = rsqrtf(ss + EPSF);
  const float4 w0 = *(const float4*)(nw + lane*4);
  const float4 w1 = *(const float4*)(nw + 256 + lane*4);
  y0.x *= inv*w0.x; y0.y *= inv*w0.y; y0.z *= inv*w0.z; y0.w *= inv*w0.w;
  y1.x *= inv*w1.x; y1.y *= inv*w1.y; y1.z *= inv*w1.z; y1.w *= inv*w1.w;
  *(ushort4*)(yr + lane*4)       = make_ushort4(f2bf(y0.x), f2bf(y0.y), f2bf(y0.z), f2bf(y0.w));
  *(ushort4*)(yr + 256 + lane*4) = make_ushort4(f2bf(y1.x), f2bf(y1.y), f2bf(y1.z), f2bf(y1.w));
}

// ---------------- weight transpose+convert ----------------

__global__ __launch_bounds__(256) void tcvt_both(const float* __restrict__ Wi, const float* __restrict__ Wo,
                                                 unsigned short* __restrict__ WtA, unsigned short* __restrict__ WtO) {
  int idx = blockIdx.x*256 + threadIdx.x;
  if (idx < 1152*DM) {
    int n = idx >> 8, k = idx & 255;
    WtA[idx] = f2bf(Wi[(size_t)k*DP + n]);
  } else {
    int j = idx - 1152*DM;
    int n = j >> 9, k = j & 511;
    WtO[j] = f2bf(Wo[(size_t)k*DM + n]);
  }
}

// ---------------- MFMA GEMMs ----------------

// merged dirs via blockIdx.z
__global__ __launch_bounds__(256) void gemm_in_mfma(const unsigned short* __restrict__ Abf,
                                                    const unsigned short* __restrict__ Wt,
                                                    const unsigned int* __restrict__ ord,
                                                    unsigned short* __restrict__ gatebf,
                                                    unsigned short* __restrict__ xbcbf) {
  __shared__ unsigned short Alds[128*64];
  __shared__ unsigned short Blds[128*64];
  int tid = threadIdx.x, lane = tid & 63, w = tid >> 6;
  int rb = blockIdx.y*128, cb = blockIdx.x*128;
  int dir = blockIdx.z;
  const unsigned int* ordp = ord + (size_t)dir*L_TOK;
  int wm = (w & 1)*64, wn = (w >> 1)*64;
  const unsigned short* pA[4]; const unsigned short* pB[4];
  unsigned short* dA[4]; unsigned short* dB[4];
  #pragma unroll
  for (int s = 0; s < 4; ++s) {
    int inst = w*4 + s;
    int r = inst*8 + (lane >> 3);
    int cA = (lane & 7) ^ (r & 7);
    pA[s] = Abf + (size_t)ordp[rb + r]*DM + cA*8;
    pB[s] = Wt + (size_t)(cb + r)*DM + cA*8;
    dA[s] = &Alds[inst*512];
    dB[s] = &Blds[inst*512];
  }
  f32x4 zero = {0.f, 0.f, 0.f, 0.f};
  f32x4 acc[4][4];
  #pragma unroll
  for (int i = 0; i < 4; ++i)
    #pragma unroll
    for (int j = 0; j < 4; ++j) acc[i][j] = zero;
  int t = lane & 15, q = lane >> 4;
  for (int k0 = 0; k0 < DM; k0 += 64) {
    #pragma unroll
    for (int s = 0; s < 4; ++s) GLL16(pA[s] + k0, dA[s]);
    #pragma unroll
    for (int s = 0; s < 4; ++s) GLL16(pB[s] + k0, dB[s]);
    __syncthreads();
    #pragma unroll
    for (int ks = 0; ks < 2; ++ks) {
      short8 af[4], bfr[4];
      int cc = ks*4 + q;
      #pragma unroll
      for (int i = 0; i < 4; ++i) {
        int rr = wm + 16*i + t;
        af[i] = *(const short8*)&Alds[rr*64 + ((cc ^ (rr & 7))*8)];
      }
      #pragma unroll
      for (int j = 0; j < 4; ++j) {
        int rr = wn + 16*j + t;
        bfr[j] = *(const short8*)&Blds[rr*64 + ((cc ^ (rr & 7))*8)];
      }
      #pragma unroll
      for (int i = 0; i < 4; ++i)
        #pragma unroll
        for (int j = 0; j < 4; ++j)
          acc[i][j] = __builtin_amdgcn_mfma_f32_16x16x32_bf16(af[i], bfr[j], acc[i][j], 0, 0, 0);
    }
    __syncthreads();
  }
  unsigned short* dst; int ld;
  if (cb < DI) { dst = gatebf + (size_t)dir*L_TOK*DI + cb; ld = DI; }
  else         { dst = xbcbf + (size_t)dir*L_TOK*CD + (cb - DI); ld = CD; }
  #pragma unroll
  for (int i = 0; i < 4; ++i) {
    int rowb = rb + wm + 16*i + q*4;
    #pragma unroll
    for (int j = 0; j < 4; ++j) {
      int col = wn + 16*j + t;
      #pragma unroll
      for (int r = 0; r < 4; ++r)
        dst[(size_t)(rowb + r)*ld + col] = f2bf(acc[i][j][r]);
    }
  }
}

// per-dir launch (sequential) to keep out-accumulate race-free
__global__ __launch_bounds__(256) void gemm_out_mfma(const unsigned short* __restrict__ Abf,
                                                     const unsigned short* __restrict__ Wt,
                                                     const unsigned int* __restrict__ ordp,
                                                     float* __restrict__ out) {
  __shared__ unsigned short Alds[128*64];
  __shared__ unsigned short Blds[128*64];
  __shared__ unsigned int ordl[128];
  int tid = threadIdx.x, lane = tid & 63, w = tid >> 6;
  int rb = blockIdx.y*128, cb = blockIdx.x*128;
  int wm = (w & 1)*64, wn = (w >> 1)*64;
  if (tid < 128) ordl[tid] = ordp[rb + tid];
  const unsigned short* pA[4]; const unsigned short* pB[4];
  unsigned short* dA[4]; unsigned short* dB[4];
  #pragma unroll
  for (int s = 0; s < 4; ++s) {
    int inst = w*4 + s;
    int r = inst*8 + (lane >> 3);
    int cA = (lane & 7) ^ (r & 7);
    pA[s] = Abf + (size_t)(rb + r)*DI + cA*8;
    pB[s] = Wt + (size_t)(cb + r)*DI + cA*8;
    dA[s] = &Alds[inst*512];
    dB[s] = &Blds[inst*512];
  }
  f32x4 zero = {0.f, 0.f, 0.f, 0.f};
  f32x4 acc[4][4];
  #pragma unroll
  for (int i = 0; i < 4; ++i)
    #pragma unroll
    for (int j = 0; j < 4; ++j) acc[i][j] = zero;
  int t = lane & 15, q = lane >> 4;
  for (int k0 = 0; k0 < DI; k0 += 64) {
    #pragma unroll
    for (int s = 0; s < 4; ++s) GLL16(pA[s] + k0, dA[s]);
    #pragma unroll
    for (int s = 0; s < 4; ++s) GLL16(pB[s] + k0, dB[s]);
    __syncthreads();
    #pragma unroll
    for (int ks = 0; ks < 2; ++ks) {
      short8 af[4], bfr[4];
      int cc = ks*4 + q;
      #pragma unroll
      for (int i = 0; i < 4; ++i) {
        int rr = wm + 16*i + t;
        af[i] = *(const short8*)&Alds[rr*64 + ((cc ^ (rr & 7))*8)];
      }
      #pragma unroll
      for (int j = 0; j < 4; ++j) {
        int rr = wn + 16*j + t;
        bfr[j] = *(const short8*)&Blds[rr*64 + ((cc ^ (rr & 7))*8)];
      }
      #pragma unroll
      for (int i = 0; i < 4; ++i)
        #pragma unroll
        for (int j = 0; j < 4; ++j)
          acc[i][j] = __builtin_amdgcn_mfma_f32_16x16x32_bf16(af[i], bfr[j], acc[i][j], 0, 0, 0);
    }
    __syncthreads();
  }
  #pragma unroll
  for (int i = 0; i < 4; ++i) {
    #pragma unroll
    for (int r = 0; r < 4; ++r) {
      unsigned int tok = ordl[wm + 16*i + q*4 + r];
      float* op = out + (size_t)tok*DM + cb;
      #pragma unroll
      for (int j = 0; j < 4; ++j) {
        int col = wn + 16*j + t;
        op[col] += 0.5f*acc[i][j][r];
      }
    }
  }
}

// ---------------- dt path (fp32, fused softplus); merged dirs ----------------
__global__ __launch_bounds__(256) void dt_gemv(const float* __restrict__ qn, const float* __restrict__ W,
                                               const unsigned int* __restrict__ ord,
                                               const float* __restrict__ dt_bias, float* __restrict__ dtb) {
  int row = blockIdx.x*4 + (threadIdx.x >> 6);   // 0..2L-1
  int lane = threadIdx.x & 63;
  int dir = row >> 14, lrow = row & (L_TOK - 1);
  unsigned int src = ord[(size_t)dir*L_TOK + lrow];
  const float4 q4 = *(const float4*)(qn + (size_t)src*DM + lane*4);
  float a[8] = {0,0,0,0,0,0,0,0};
  const float* wp = W + (size_t)(lane*4)*DP + (DI + CD);
  float qe[4] = {q4.x, q4.y, q4.z, q4.w};
  #pragma unroll
  for (int e = 0; e < 4; ++e) {
    float4 wa = *(const float4*)(wp + (size_t)e*DP);
    float4 wb = *(const float4*)(wp + (size_t)e*DP + 4);
    a[0] += qe[e]*wa.x; a[1] += qe[e]*wa.y; a[2] += qe[e]*wa.z; a[3] += qe[e]*wa.w;
    a[4] += qe[e]*wb.x; a[5] += qe[e]*wb.y; a[6] += qe[e]*wb.z; a[7] += qe[e]*wb.w;
  }
  #pragma unroll
  for (int h = 0; h < 8; ++h) a[h] = warp_sum(a[h]);
  float v = 0.0f;
  #pragma unroll
  for (int h = 0; h < 8; ++h) if (lane == h) v = a[h];
  if (lane < 8) {
    v += dt_bias[lane];
    float sp = (v > 0.0f) ? (v + log1pf(expf(-v))) : log1pf(expf(v));
    dtb[(size_t)row*NH + lane] = sp;
  }
}

// ---------------- conv: register-blocked, merged dirs ----------------
// 1280 blocks: gid covers 2 x (80 ch-groups x 2048 token-strips)

__global__ __launch_bounds__(256) void conv_kernel(const unsigned short* __restrict__ xbc, const float* __restrict__ cw,
                                                   const float* __restrict__ cbias, unsigned short* __restrict__ outc) {
  int gid = blockIdx.x*256 + threadIdx.x;
  int dir = gid / 163840;
  int lid = gid - dir*163840;
  int g = lid % 80;
  int ts = lid / 80;
  int t0 = ts*8;
  int ch = g*8;
  const unsigned short* src = xbc + (size_t)dir*L_TOK*CD;
  unsigned short* dst = outc + (size_t)dir*L_TOK*CD;
  float wv[8][4];
  float bias[8];
  #pragma unroll
  for (int e = 0; e < 8; ++e) {
    float4 c4 = *(const float4*)(cw + (ch + e)*4);
    wv[e][0] = c4.x; wv[e][1] = c4.y; wv[e][2] = c4.z; wv[e][3] = c4.w;
  }
  {
    float4 b0 = *(const float4*)(cbias + ch);
    float4 b1 = *(const float4*)(cbias + ch + 4);
    bias[0]=b0.x; bias[1]=b0.y; bias[2]=b0.z; bias[3]=b0.w;
    bias[4]=b1.x; bias[5]=b1.y; bias[6]=b1.z; bias[7]=b1.w;
  }
  float rows[11][8];
  #pragma unroll
  for (int r = 0; r < 11; ++r) {
    int t = t0 - 3 + r;
    if (t >= 0) {
      short8 v = *(const short8*)(src + (size_t)t*CD + ch);
      #pragma unroll
      for (int e = 0; e < 8; ++e) rows[r][e] = bf2f((unsigned short)v[e]);
    } else {
      #pragma unroll
      for (int e = 0; e < 8; ++e) rows[r][e] = 0.f;
    }
  }
  #pragma unroll
  for (int tt = 0; tt < 8; ++tt) {
    short8 o;
    #pragma unroll
    for (int e = 0; e < 8; ++e) {
      float s = bias[e];
      #pragma unroll
      for (int k = 0; k < 4; ++k)
        s = fmaf(wv[e][k], rows[tt + k][e], s);
      o[e] = (short)f2bf(siluf(s));
    }
    *(short8*)(dst + (size_t)(t0 + tt)*CD + ch) = o;
  }
}

// ---------------- chunked scan (MFMA, bf16 S); dirs merged via blockIdx.z ----------------

__global__ __launch_bounds__(256) void phaseA_mfma(const unsigned short* __restrict__ convo,
                                                   const float* __restrict__ dtb, const float* __restrict__ A_log,
                                                   unsigned short* __restrict__ S, float* __restrict__ P) {
  int c = blockIdx.x, h = blockIdx.y, dir = blockIdx.z, tid = threadIdx.x;
  int lane = tid & 63, w = tid >> 6;
  int hh = dir*NH + h;
  const unsigned short* xc = convo + (size_t)dir*L_TOK*CD;
  __shared__ unsigned short xT[64*64];
  __shared__ unsigned short Bt[64*64];
  __shared__ float dts[64], lg[64], sfx[64], wgt[64];
  __shared__ float totals;
  int c0 = c*CHUNK;
  float Ah = -expf(A_log[h]);
  if (tid < 64) {
    float dtv = dtb[(size_t)(dir*L_TOK + c0 + tid)*NH + h];
    dts[tid] = dtv; lg[tid] = dtv*Ah;
  }
  #pragma unroll
  for (int i = 0; i < 2; ++i) {
    int q = tid + 256*i;
    int t = q >> 3, s0 = (q & 7)*8;
    short8 v = *(const short8*)(xc + (size_t)(c0+t)*CD + DI + s0);
    int tc = t >> 3, ti = t & 7;
    #pragma unroll
    for (int e = 0; e < 8; ++e) {
      int s = s0 + e;
      Bt[s*64 + ((tc ^ (s & 7))*8 + ti)] = (unsigned short)v[e];
    }
  }
  __syncthreads();
  if (tid == 0) {
    float run = 0.f;
    for (int t = 63; t >= 0; --t) { sfx[t] = run; run += lg[t]; }
    totals = run;
  }
  __syncthreads();
  if (tid < 64) wgt[tid] = dts[tid]*expf(sfx[tid]);
  if (tid == 0) P[hh*NC + c] = expf(totals);
  __syncthreads();
  #pragma unroll
  for (int i = 0; i < 2; ++i) {
    int q = tid + 256*i;
    int t = q >> 3, p0 = (q & 7)*8;
    short8 v = *(const short8*)(xc + (size_t)(c0+t)*CD + h*HD + p0);
    float wvv = wgt[t];
    int tc = t >> 3, ti = t & 7;
    #pragma unroll
    for (int e = 0; e < 8; ++e) {
      int p = p0 + e;
      xT[p*64 + ((tc ^ (p & 7))*8 + ti)] = f2bf(bf2f((unsigned short)v[e]) * wvv);
    }
  }
  __syncthreads();
  int t16 = lane & 15, q4 = lane >> 4;
  f32x4 zero = {0.f,0.f,0.f,0.f};
  f32x4 acc[4];
  #pragma unroll
  for (int j = 0; j < 4; ++j) acc[j] = zero;
  #pragma unroll
  for (int ks = 0; ks < 2; ++ks) {
    int rowA = 16*w + t16;
    short8 a = *(const short8*)&xT[rowA*64 + (((ks*4 + q4) ^ (rowA & 7))*8)];
    #pragma unroll
    for (int j = 0; j < 4; ++j) {
      int rowB = 16*j + t16;
      short8 b = *(const short8*)&Bt[rowB*64 + (((ks*4 + q4) ^ (rowB & 7))*8)];
      acc[j] = __builtin_amdgcn_mfma_f32_16x16x32_bf16(a, b, acc[j], 0, 0, 0);
    }
  }
  unsigned short* Sp = S + ((size_t)(hh*NC + c))*4096;
  #pragma unroll
  for (int j = 0; j < 4; ++j)
    #pragma unroll
    for (int r = 0; r < 4; ++r)
      Sp[(size_t)(16*w + q4*4 + r)*64 + 16*j + t16] = f2bf(acc[j][r]);
}

// ---- phaseB: hh spans 16 (2 dirs x 8 heads) ----

__global__ __launch_bounds__(256) void phaseB1(const unsigned short* __restrict__ S, const float* __restrict__ P,
                                               float* __restrict__ Ssum, float* __restrict__ Psum) {
  int gid = blockIdx.x*256 + threadIdx.x;
  int e2 = gid & 2047;
  int sc = (gid >> 11) & 15;
  int hh = gid >> 15;   // 0..15
  const unsigned short* base = S + ((size_t)(hh*NC + sc*16))*4096 + e2*2;
  const float* Ph = P + hh*NC + sc*16;
  float hx = 0.f, hy = 0.f, pprod = 1.f;
  #pragma unroll
  for (int k = 0; k < 16; ++k) {
    unsigned int v = *(const unsigned int*)(base + (size_t)k*4096);
    float p = Ph[k];
    hx = p*hx + bf2f((unsigned short)(v & 0xffffu));
    hy = p*hy + bf2f((unsigned short)(v >> 16));
    pprod *= p;
  }
  float* sp = Ssum + ((size_t)(hh*16 + sc))*4096 + e2*2;
  sp[0] = hx; sp[1] = hy;
  if (e2 == 0) Psum[hh*16 + sc] = pprod;
}

__global__ __launch_bounds__(256) void phaseB3(unsigned short* __restrict__ S, const float* __restrict__ P,
                                               const float* __restrict__ Ssum, const float* __restrict__ Psum) {
  int gid = blockIdx.x*256 + threadIdx.x;
  int e2 = gid & 2047;
  int sc = (gid >> 11) & 15;
  int hh = gid >> 15;
  float hx = 0.f, hy = 0.f;
  for (int s2 = 0; s2 < sc; ++s2) {
    float pp = Psum[hh*16 + s2];
    const float* sp = Ssum + ((size_t)(hh*16 + s2))*4096 + e2*2;
    hx = pp*hx + sp[0];
    hy = pp*hy + sp[1];
  }
  unsigned short* base = S + ((size_t)(hh*NC + sc*16))*4096 + e2*2;
  const float* Ph = P + hh*NC + sc*16;
  #pragma unroll
  for (int k = 0; k < 16; ++k) {
    unsigned int* ptr = (unsigned int*)(base + (size_t)k*4096);
    unsigned int v = *ptr;
    float p = Ph[k];
    *ptr = (unsigned int)f2bf(hx) | ((unsigned int)f2bf(hy) << 16);
    hx = p*hx + bf2f((unsigned short)(v & 0xffffu));
    hy = p*hy + bf2f((unsigned short)(v >> 16));
  }
}

// phaseC: dirs merged; Y written into xbc buffer region (stride DI)
__global__ __launch_bounds__(256) void phaseC_mfma(const unsigned short* __restrict__ convo,
                                                   const float* __restrict__ dtb, const float* __restrict__ A_log,
                                                   const float* __restrict__ Dp,
                                                   const unsigned short* __restrict__ S,
                                                   unsigned short* __restrict__ ybase) {
  int c = blockIdx.x, h = blockIdx.y, dir = blockIdx.z, tid = threadIdx.x;
  int lane = tid & 63, w = tid >> 6;
  int hh = dir*NH + h;
  const unsigned short* xc = convo + (size_t)dir*L_TOK*CD;
  unsigned short* y = ybase + (size_t)dir*L_TOK*CD;
  __shared__ unsigned short Cl[64*64];
  __shared__ unsigned short Bl[64*64];
  __shared__ unsigned short h0l[64*64];
  __shared__ unsigned short xT[64*64];
  __shared__ unsigned short Gl[64*64];
  __shared__ float dts[64], lg[64], pl[64], pe[64];
  int c0 = c*CHUNK;
  float Ah = -expf(A_log[h]);
  float Dh = Dp[h];
  if (tid < 64) {
    float dtv = dtb[(size_t)(dir*L_TOK + c0 + tid)*NH + h];
    dts[tid] = dtv; lg[tid] = dtv*Ah;
  }
  const unsigned short* Sp = S + ((size_t)(hh*NC + c))*4096;
  #pragma unroll
  for (int i = 0; i < 2; ++i) {
    int q = tid + 256*i;
    int t = q >> 3, d0 = (q & 7)*8;
    int swoff = t*64 + (((q & 7) ^ (t & 7))*8);
    *(short8*)&Cl[swoff] = *(const short8*)(xc + (size_t)(c0+t)*CD + DI + DS + d0);
    *(short8*)&Bl[swoff] = *(const short8*)(xc + (size_t)(c0+t)*CD + DI + d0);
    *(short8*)&h0l[swoff] = *(const short8*)(Sp + (size_t)t*64 + d0);
    short8 xv = *(const short8*)(xc + (size_t)(c0+t)*CD + h*HD + d0);
    int tc = t >> 3, ti = t & 7;
    #pragma unroll
    for (int e = 0; e < 8; ++e) {
      int p = d0 + e;
      xT[p*64 + ((tc ^ (p & 7))*8 + ti)] = (unsigned short)xv[e];
    }
  }
  __syncthreads();
  if (tid == 0) {
    float run = 0.f;
    for (int t = 0; t < 64; ++t) { run += lg[t]; pl[t] = run; }
  }
  __syncthreads();
  if (tid < 64) pe[tid] = expf(pl[tid]);
  __syncthreads();
  int t16 = lane & 15, q4 = lane >> 4;
  int t0 = 16*w;
  f32x4 zero = {0.f,0.f,0.f,0.f};
  f32x4 accG[4], accY[4];
  #pragma unroll
  for (int j = 0; j < 4; ++j) { accG[j] = zero; accY[j] = zero; }
  #pragma unroll
  for (int ks = 0; ks < 2; ++ks) {
    int rowA = t0 + t16;
    short8 a = *(const short8*)&Cl[rowA*64 + (((ks*4 + q4) ^ (rowA & 7))*8)];
    #pragma unroll
    for (int j = 0; j < 4; ++j) {
      int rowB = 16*j + t16;
      int off = rowB*64 + (((ks*4 + q4) ^ (rowB & 7))*8);
      accG[j] = __builtin_amdgcn_mfma_f32_16x16x32_bf16(a, *(const short8*)&Bl[off], accG[j], 0, 0, 0);
      accY[j] = __builtin_amdgcn_mfma_f32_16x16x32_bf16(a, *(const short8*)&h0l[off], accY[j], 0, 0, 0);
    }
  }
  #pragma unroll
  for (int j = 0; j < 4; ++j) {
    #pragma unroll
    for (int r = 0; r < 4; ++r) {
      int t = t0 + q4*4 + r;
      int s = 16*j + t16;
      float v = 0.f;
      if (s <= t) {
        v = accG[j][r] * dts[s] * expf(pl[t] - pl[s]);
        if (s == t) v += Dh;
      }
      Gl[t*64 + (((s >> 3) ^ (t & 7))*8 + (s & 7))] = f2bf(v);
    }
  }
  #pragma unroll
  for (int j = 0; j < 4; ++j)
    #pragma unroll
    for (int r = 0; r < 4; ++r)
      accY[j][r] *= pe[t0 + q4*4 + r];
  #pragma unroll
  for (int ks = 0; ks < 2; ++ks) {
    int rowA = t0 + t16;
    short8 a = *(const short8*)&Gl[rowA*64 + (((ks*4 + q4) ^ (rowA & 7))*8)];
    #pragma unroll
    for (int j = 0; j < 4; ++j) {
      int rowB = 16*j + t16;
      short8 b = *(const short8*)&xT[rowB*64 + (((ks*4 + q4) ^ (rowB & 7))*8)];
      accY[j] = __builtin_amdgcn_mfma_f32_16x16x32_bf16(a, b, accY[j], 0, 0, 0);
    }
  }
  #pragma unroll
  for (int j = 0; j < 4; ++j)
    #pragma unroll
    for (int r = 0; r < 4; ++r) {
      int t = t0 + q4*4 + r;
      int p = 16*j + t16;
      y[(size_t)(c0+t)*DI + h*HD + p] = f2bf(accY[j][r]);
    }
}

__global__ void fill_debug(float* out, float v) {
  int i = blockIdx.x*256 + threadIdx.x;
  if (i < L_TOK*DM) out[i] = v;
}

// ---------------- host ----------------

extern "C" void kernel_launch(void* const* d_in, const int* in_sizes, int n_in,
                              void* d_out, int out_size, void* d_ws, size_t ws_size,
                              hipStream_t stream) {
  const float* query = (const float*)d_in[0];
  const float* qpos  = (const float*)d_in[1];
  const float* pre_w = (const float*)d_in[2];
  const float* pre_b = (const float*)d_in[3];
  const float* fin_w = (const float*)d_in[4];
  const float* fin_b = (const float*)d_in[5];
  float* out = (float*)d_out;

  char* ws = (char*)d_ws;
  size_t off = 0;
  auto alloc = [&](size_t bytes) -> void* {
    void* p = ws + off;
    off += (bytes + 255) & ~(size_t)255;
    return p;
  };
  unsigned long long* keys = (unsigned long long*)alloc((size_t)2*L_TOK*8);
  unsigned int* ord = (unsigned int*)alloc((size_t)2*L_TOK*4);
  unsigned int* rpart = (unsigned int*)alloc((size_t)32*2*L_TOK*4);
  float* pmm  = (float*)alloc(256);
  float* qn   = (float*)alloc((size_t)L_TOK*DM*4);
  unsigned short* qnbf = (unsigned short*)alloc((size_t)L_TOK*DM*2);
  unsigned short* gatebf = (unsigned short*)alloc((size_t)2*L_TOK*DI*2);
  unsigned short* xbcbf  = (unsigned short*)alloc((size_t)2*L_TOK*CD*2);  // also hosts y (stride DI) after conv
  unsigned short* convo  = (unsigned short*)alloc((size_t)2*L_TOK*CD*2);
  float* dtb  = (float*)alloc((size_t)2*L_TOK*NH*4);
  unsigned short* Sbuf = (unsigned short*)alloc((size_t)2*NH*NC*4096*2);
  float* Pbuf = (float*)alloc((size_t)2*NH*NC*4);
  float* Ssum = (float*)alloc((size_t)2*NH*16*4096*4);
  float* Psum = (float*)alloc((size_t)2*NH*16*4);
  unsigned short* WtA = (unsigned short*)alloc((size_t)1152*DM*2);
  unsigned short* WtO = (unsigned short*)alloc((size_t)DM*DI*2);
  if (off > ws_size) {
    fill_debug<<<(L_TOK*DM + 255)/256, 256, 0, stream>>>(out, (float)(ws_size >> 20));
    return;
  }

  minmax_kernel<<<1, 256, 0, stream>>>(qpos, pmm);
  hilbert_kernel<<<L_TOK/256, 256, 0, stream>>>(qpos, pmm, keys);
  rank_partial<<<dim3(16, 2, 32), 256, 0, stream>>>(keys, rpart);
  rank_scatter<<<(2*L_TOK)/256, 256, 0, stream>>>(keys, rpart, ord);
  hipMemcpyAsync(out, query, (size_t)L_TOK*DM*4, hipMemcpyDeviceToDevice, stream);

  for (int l = 0; l < 2; ++l) {
    int base = 6 + 8*l;
    const float* in_proj  = (const float*)d_in[base+0];
    const float* conv_w   = (const float*)d_in[base+1];
    const float* conv_b   = (const float*)d_in[base+2];
    const float* dt_bias  = (const float*)d_in[base+3];
    const float* A_log    = (const float*)d_in[base+4];
    const float* Dp       = (const float*)d_in[base+5];
    const float* norm_w   = (const float*)d_in[base+6];
    const float* out_proj = (const float*)d_in[base+7];

    ln_kernel<<<L_TOK/4, 256, 0, stream>>>(out, qn, qnbf, pre_w, pre_b);
    tcvt_both<<<(1152*DM + DM*DI)/256, 256, 0, stream>>>(in_proj, out_proj, WtA, WtO);
    gemm_in_mfma<<<dim3(9, L_TOK/128, 2), 256, 0, stream>>>(qnbf, WtA, ord, gatebf, xbcbf);
    dt_gemv<<<(2*L_TOK)/4, 256, 0, stream>>>(qn, in_proj, ord, dt_bias, dtb);
    conv_kernel<<<1280, 256, 0, stream>>>(xbcbf, conv_w, conv_b, convo);
    phaseA_mfma<<<dim3(NC, NH, 2), 256, 0, stream>>>(convo, dtb, A_log, Sbuf, Pbuf);
    phaseB1<<<(16*16*2048)/256, 256, 0, stream>>>(Sbuf, Pbuf, Ssum, Psum);
    phaseB3<<<(16*16*2048)/256, 256, 0, stream>>>(Sbuf, Pbuf, Ssum, Psum);
    phaseC_mfma<<<dim3(NC, NH, 2), 256, 0, stream>>>(convo, dtb, A_log, Dp, Sbuf, xbcbf);
    gating_kernel<<<(2*L_TOK)/4, 256, 0, stream>>>(xbcbf, gatebf, norm_w);
    for (int dir = 0; dir < 2; ++dir)
      gemm_out_mfma<<<dim3(2, L_TOK/128), 256, 0, stream>>>(xbcbf + (size_t)dir*L_TOK*CD, WtO,
                                                            ord + (size_t)dir*L_TOK, out);
    ln_kernel<<<L_TOK/4, 256, 0, stream>>>(out, out, (unsigned short*)nullptr, fin_w, fin_b);
  }
}

// Round 9
// 645.201 us; speedup vs baseline: 1.9368x; 1.0751x over previous
//
#include <hip/hip_runtime.h>
#include <stdint.h>

#define L_TOK 16384
#define DM 256
#define DI 512
#define DS 64
#define NH 8
#define HD 64
#define CD 640
#define DP 1160
#define CHUNK 64
#define NC 256
#define EPSF 1e-5f

typedef __attribute__((ext_vector_type(8))) short short8;
typedef __attribute__((ext_vector_type(4))) float f32x4;

#define GLL16(gp, lp) __builtin_amdgcn_global_load_lds((const __attribute__((address_space(1))) void*)(gp), (__attribute__((address_space(3))) void*)(lp), 16, 0, 0)

__device__ __forceinline__ float warp_sum(float v) {
  v += __shfl_xor(v, 1, 64);
  v += __shfl_xor(v, 2, 64);
  v += __shfl_xor(v, 4, 64);
  v += __shfl_xor(v, 8, 64);
  v += __shfl_xor(v, 16, 64);
  v += __shfl_xor(v, 32, 64);
  return v;
}

__device__ __forceinline__ float siluf(float x) { return x / (1.0f + expf(-x)); }

__device__ __forceinline__ unsigned short f2bf(float f) {
  unsigned int u = __float_as_uint(f);
  unsigned int r = (u + 0x7FFFu + ((u >> 16) & 1u)) >> 16;
  return (unsigned short)r;
}
__device__ __forceinline__ float bf2f(unsigned short u) {
  return __uint_as_float(((unsigned int)u) << 16);
}

// ---------------- serialization ----------------

__global__ __launch_bounds__(256) void minmax_kernel(const float* __restrict__ pos, float* __restrict__ pmm) {
  __shared__ float sm[6][256];
  int tid = threadIdx.x;
  float mn0=1e30f, mn1=1e30f, mn2=1e30f, mx0=-1e30f, mx1=-1e30f, mx2=-1e30f;
  for (int t = tid; t < L_TOK; t += 256) {
    float a = pos[t*3+0], b = pos[t*3+1], c = pos[t*3+2];
    mn0=fminf(mn0,a); mx0=fmaxf(mx0,a);
    mn1=fminf(mn1,b); mx1=fmaxf(mx1,b);
    mn2=fminf(mn2,c); mx2=fmaxf(mx2,c);
  }
  sm[0][tid]=mn0; sm[1][tid]=mn1; sm[2][tid]=mn2;
  sm[3][tid]=mx0; sm[4][tid]=mx1; sm[5][tid]=mx2;
  __syncthreads();
  for (int s = 128; s > 0; s >>= 1) {
    if (tid < s) {
      #pragma unroll
      for (int d = 0; d < 3; ++d) {
        sm[d][tid]   = fminf(sm[d][tid],   sm[d][tid+s]);
        sm[3+d][tid] = fmaxf(sm[3+d][tid], sm[3+d][tid+s]);
      }
    }
    __syncthreads();
  }
  if (tid < 6) pmm[tid] = sm[tid][0];
}

__device__ unsigned int hilbert3(unsigned int a, unsigned int b, unsigned int c) {
  unsigned int x0 = a, x1 = b, x2 = c;
  for (unsigned int Q = 512u; Q > 1u; Q >>= 1) {
    unsigned int P = Q - 1u;
    { if (x0 & Q) x0 ^= P; }
    {
      unsigned int t = (x0 ^ x1) & P;
      if (x1 & Q) { x0 ^= P; }
      else { x0 ^= t; x1 ^= t; }
    }
    {
      unsigned int t = (x0 ^ x2) & P;
      if (x2 & Q) { x0 ^= P; }
      else { x0 ^= t; x2 ^= t; }
    }
  }
  x1 ^= x0; x2 ^= x1;
  unsigned int tt = 0;
  for (unsigned int Q = 512u; Q > 1u; Q >>= 1)
    if (x2 & Q) tt ^= (Q - 1u);
  x0 ^= tt; x1 ^= tt; x2 ^= tt;
  unsigned int code = 0;
  #pragma unroll
  for (int bb = 9; bb >= 0; --bb) {
    code = (code << 1) | ((x0 >> bb) & 1u);
    code = (code << 1) | ((x1 >> bb) & 1u);
    code = (code << 1) | ((x2 >> bb) & 1u);
  }
  return code;
}

__global__ __launch_bounds__(256) void hilbert_kernel(const float* __restrict__ pos, const float* __restrict__ pmm,
                                                      unsigned long long* __restrict__ keys) {
  int t = blockIdx.x*256 + threadIdx.x;
  if (t >= L_TOK) return;
  unsigned int g[3];
  #pragma unroll
  for (int d = 0; d < 3; ++d) {
    float v = (pos[t*3+d] - pmm[d]) / (pmm[3+d] - pmm[d] + 1e-6f) * 1023.0f;
    v = fminf(fmaxf(v, 0.0f), 1023.0f);
    g[d] = (unsigned int)(int)v;
  }
  unsigned int ca = hilbert3(g[0], g[1], g[2]);
  unsigned int cb = hilbert3(g[1], g[0], g[2]);
  keys[t]         = ((unsigned long long)ca << 14) | (unsigned long long)t;
  keys[L_TOK + t] = ((unsigned long long)cb << 14) | (unsigned long long)t;
}

__global__ __launch_bounds__(256) void rank_partial(const unsigned long long* __restrict__ keys,
                                                    unsigned int* __restrict__ partial) {
  __shared__ unsigned long long tile[512];
  int arr = blockIdx.y, ks = blockIdx.z;
  const unsigned long long* k = keys + (size_t)arr * L_TOK;
  int qbase = blockIdx.x*1024 + threadIdx.x;
  unsigned long long q[4];
  #pragma unroll
  for (int i = 0; i < 4; ++i) q[i] = k[qbase + 256*i];
  const unsigned long long* src = k + ks*512;
  #pragma unroll
  for (int t = 0; t < 2; ++t) tile[threadIdx.x + 256*t] = src[threadIdx.x + 256*t];
  __syncthreads();
  unsigned int r[4] = {};
  const ulonglong2* t2 = (const ulonglong2*)tile;
  #pragma unroll 4
  for (int j = 0; j < 256; ++j) {
    ulonglong2 v = t2[j];
    #pragma unroll
    for (int i = 0; i < 4; ++i) {
      r[i] += (v.x < q[i]) ? 1u : 0u;
      r[i] += (v.y < q[i]) ? 1u : 0u;
    }
  }
  #pragma unroll
  for (int i = 0; i < 4; ++i)
    partial[(size_t)(ks*2 + arr)*L_TOK + qbase + 256*i] = r[i];
}

__global__ __launch_bounds__(256) void rank_scatter(const unsigned long long* __restrict__ keys,
                                                    const unsigned int* __restrict__ partial,
                                                    unsigned int* __restrict__ ord) {
  int i = blockIdx.x*256 + threadIdx.x;
  int arr = i >> 14;
  int qi = i & (L_TOK - 1);
  unsigned int r = 0;
  #pragma unroll
  for (int ks = 0; ks < 32; ++ks) r += partial[(size_t)(ks*2 + arr)*L_TOK + qi];
  ord[(size_t)arr*L_TOK + r] = (unsigned int)(keys[i] & 0x3FFFu);
}

// ---------------- layernorm / gating ----------------

__global__ __launch_bounds__(256) void ln_kernel(const float* __restrict__ in, float* __restrict__ out,
                                                 unsigned short* __restrict__ outbf,
                                                 const float* __restrict__ w, const float* __restrict__ b) {
  int row = blockIdx.x*4 + (threadIdx.x >> 6);
  int lane = threadIdx.x & 63;
  const float4 v = *(const float4*)(in + (size_t)row*DM + lane*4);
  float s = v.x + v.y + v.z + v.w;
  float mean = warp_sum(s) * (1.0f/DM);
  float4 xc = make_float4(v.x-mean, v.y-mean, v.z-mean, v.w-mean);
  float ss = xc.x*xc.x + xc.y*xc.y + xc.z*xc.z + xc.w*xc.w;
  ss = warp_sum(ss) * (1.0f/DM);
  float inv = rsqrtf(ss + EPSF);
  const float4 w4 = *(const float4*)(w + lane*4);
  const float4 b4 = *(const float4*)(b + lane*4);
  float4 o;
  o.x = xc.x*inv*w4.x + b4.x;
  o.y = xc.y*inv*w4.y + b4.y;
  o.z = xc.z*inv*w4.z + b4.z;
  o.w = xc.w*inv*w4.w + b4.w;
  *(float4*)(out + (size_t)row*DM + lane*4) = o;
  if (outbf) {
    ushort4 ob = make_ushort4(f2bf(o.x), f2bf(o.y), f2bf(o.z), f2bf(o.w));
    *(ushort4*)(outbf + (size_t)row*DM + lane*4) = ob;
  }
}

__global__ __launch_bounds__(256) void gating_kernel(unsigned short* __restrict__ ybase,
                                                     const unsigned short* __restrict__ gatebf,
                                                     const float* __restrict__ nw) {
  int row = blockIdx.x*4 + (threadIdx.x >> 6);
  int lane = threadIdx.x & 63;
  int dir = row >> 14, lrow = row & (L_TOK - 1);
  unsigned short* yr = ybase + (size_t)dir*L_TOK*CD + (size_t)lrow*DI;
  const unsigned short* gr = gatebf + (size_t)dir*L_TOK*DI + (size_t)lrow*DI;
  ushort4 yu0 = *(const ushort4*)(yr + lane*4);
  ushort4 yu1 = *(const ushort4*)(yr + 256 + lane*4);
  ushort4 gu0 = *(const ushort4*)(gr + lane*4);
  ushort4 gu1 = *(const ushort4*)(gr + 256 + lane*4);
  float4 y0 = make_float4(bf2f(yu0.x), bf2f(yu0.y), bf2f(yu0.z), bf2f(yu0.w));
  float4 y1 = make_float4(bf2f(yu1.x), bf2f(yu1.y), bf2f(yu1.z), bf2f(yu1.w));
  y0.x *= siluf(bf2f(gu0.x)); y0.y *= siluf(bf2f(gu0.y)); y0.z *= siluf(bf2f(gu0.z)); y0.w *= siluf(bf2f(gu0.w));
  y1.x *= siluf(bf2f(gu1.x)); y1.y *= siluf(bf2f(gu1.y)); y1.z *= siluf(bf2f(gu1.z)); y1.w *= siluf(bf2f(gu1.w));
  float ss = y0.x*y0.x + y0.y*y0.y + y0.z*y0.z + y0.w*y0.w
           + y1.x*y1.x + y1.y*y1.y + y1.z*y1.z + y1.w*y1.w;
  ss = warp_sum(ss) * (1.0f/DI);
  float inv = rsqrtf(ss + EPSF);
  const float4 w0 = *(const float4*)(nw + lane*4);
  const float4 w1 = *(const float4*)(nw + 256 + lane*4);
  y0.x *= inv*w0.x; y0.y *= inv*w0.y; y0.z *= inv*w0.z; y0.w *= inv*w0.w;
  y1.x *= inv*w1.x; y1.y *= inv*w1.y; y1.z *= inv*w1.z; y1.w *= inv*w1.w;
  *(ushort4*)(yr + lane*4)       = make_ushort4(f2bf(y0.x), f2bf(y0.y), f2bf(y0.z), f2bf(y0.w));
  *(ushort4*)(yr + 256 + lane*4) = make_ushort4(f2bf(y1.x), f2bf(y1.y), f2bf(y1.z), f2bf(y1.w));
}

// ---------------- weight transpose+convert ----------------

__global__ __launch_bounds__(256) void tcvt_both(const float* __restrict__ Wi, const float* __restrict__ Wo,
                                                 unsigned short* __restrict__ WtA, unsigned short* __restrict__ WtO) {
  int idx = blockIdx.x*256 + threadIdx.x;
  if (idx < 1152*DM) {
    int n = idx >> 8, k = idx & 255;
    WtA[idx] = f2bf(Wi[(size_t)k*DP + n]);
  } else {
    int j = idx - 1152*DM;
    int n = j >> 9, k = j & 511;
    WtO[j] = f2bf(Wo[(size_t)k*DM + n]);
  }
}

// ---------------- MFMA GEMMs ----------------

__global__ __launch_bounds__(256) void gemm_in_mfma(const unsigned short* __restrict__ Abf,
                                                    const unsigned short* __restrict__ Wt,
                                                    const unsigned int* __restrict__ ord,
                                                    unsigned short* __restrict__ gatebf,
                                                    unsigned short* __restrict__ xbcbf) {
  __shared__ unsigned short Alds[128*64];
  __shared__ unsigned short Blds[128*64];
  int tid = threadIdx.x, lane = tid & 63, w = tid >> 6;
  int rb = blockIdx.y*128, cb = blockIdx.x*128;
  int dir = blockIdx.z;
  const unsigned int* ordp = ord + (size_t)dir*L_TOK;
  int wm = (w & 1)*64, wn = (w >> 1)*64;
  const unsigned short* pA[4]; const unsigned short* pB[4];
  unsigned short* dA[4]; unsigned short* dB[4];
  #pragma unroll
  for (int s = 0; s < 4; ++s) {
    int inst = w*4 + s;
    int r = inst*8 + (lane >> 3);
    int cA = (lane & 7) ^ (r & 7);
    pA[s] = Abf + (size_t)ordp[rb + r]*DM + cA*8;
    pB[s] = Wt + (size_t)(cb + r)*DM + cA*8;
    dA[s] = &Alds[inst*512];
    dB[s] = &Blds[inst*512];
  }
  f32x4 zero = {0.f, 0.f, 0.f, 0.f};
  f32x4 acc[4][4];
  #pragma unroll
  for (int i = 0; i < 4; ++i)
    #pragma unroll
    for (int j = 0; j < 4; ++j) acc[i][j] = zero;
  int t = lane & 15, q = lane >> 4;
  for (int k0 = 0; k0 < DM; k0 += 64) {
    #pragma unroll
    for (int s = 0; s < 4; ++s) GLL16(pA[s] + k0, dA[s]);
    #pragma unroll
    for (int s = 0; s < 4; ++s) GLL16(pB[s] + k0, dB[s]);
    __syncthreads();
    #pragma unroll
    for (int ks = 0; ks < 2; ++ks) {
      short8 af[4], bfr[4];
      int cc = ks*4 + q;
      #pragma unroll
      for (int i = 0; i < 4; ++i) {
        int rr = wm + 16*i + t;
        af[i] = *(const short8*)&Alds[rr*64 + ((cc ^ (rr & 7))*8)];
      }
      #pragma unroll
      for (int j = 0; j < 4; ++j) {
        int rr = wn + 16*j + t;
        bfr[j] = *(const short8*)&Blds[rr*64 + ((cc ^ (rr & 7))*8)];
      }
      #pragma unroll
      for (int i = 0; i < 4; ++i)
        #pragma unroll
        for (int j = 0; j < 4; ++j)
          acc[i][j] = __builtin_amdgcn_mfma_f32_16x16x32_bf16(af[i], bfr[j], acc[i][j], 0, 0, 0);
    }
    __syncthreads();
  }
  unsigned short* dst; int ld;
  if (cb < DI) { dst = gatebf + (size_t)dir*L_TOK*DI + cb; ld = DI; }
  else         { dst = xbcbf + (size_t)dir*L_TOK*CD + (cb - DI); ld = CD; }
  #pragma unroll
  for (int i = 0; i < 4; ++i) {
    int rowb = rb + wm + 16*i + q*4;
    #pragma unroll
    for (int j = 0; j < 4; ++j) {
      int col = wn + 16*j + t;
      #pragma unroll
      for (int r = 0; r < 4; ++r)
        dst[(size_t)(rowb + r)*ld + col] = f2bf(acc[i][j][r]);
    }
  }
}

__global__ __launch_bounds__(256) void gemm_out_mfma(const unsigned short* __restrict__ Abf,
                                                     const unsigned short* __restrict__ Wt,
                                                     const unsigned int* __restrict__ ordp,
                                                     float* __restrict__ out) {
  __shared__ unsigned short Alds[128*64];
  __shared__ unsigned short Blds[128*64];
  __shared__ unsigned int ordl[128];
  int tid = threadIdx.x, lane = tid & 63, w = tid >> 6;
  int rb = blockIdx.y*128, cb = blockIdx.x*128;
  int wm = (w & 1)*64, wn = (w >> 1)*64;
  if (tid < 128) ordl[tid] = ordp[rb + tid];
  const unsigned short* pA[4]; const unsigned short* pB[4];
  unsigned short* dA[4]; unsigned short* dB[4];
  #pragma unroll
  for (int s = 0; s < 4; ++s) {
    int inst = w*4 + s;
    int r = inst*8 + (lane >> 3);
    int cA = (lane & 7) ^ (r & 7);
    pA[s] = Abf + (size_t)(rb + r)*DI + cA*8;
    pB[s] = Wt + (size_t)(cb + r)*DI + cA*8;
    dA[s] = &Alds[inst*512];
    dB[s] = &Blds[inst*512];
  }
  f32x4 zero = {0.f, 0.f, 0.f, 0.f};
  f32x4 acc[4][4];
  #pragma unroll
  for (int i = 0; i < 4; ++i)
    #pragma unroll
    for (int j = 0; j < 4; ++j) acc[i][j] = zero;
  int t = lane & 15, q = lane >> 4;
  for (int k0 = 0; k0 < DI; k0 += 64) {
    #pragma unroll
    for (int s = 0; s < 4; ++s) GLL16(pA[s] + k0, dA[s]);
    #pragma unroll
    for (int s = 0; s < 4; ++s) GLL16(pB[s] + k0, dB[s]);
    __syncthreads();
    #pragma unroll
    for (int ks = 0; ks < 2; ++ks) {
      short8 af[4], bfr[4];
      int cc = ks*4 + q;
      #pragma unroll
      for (int i = 0; i < 4; ++i) {
        int rr = wm + 16*i + t;
        af[i] = *(const short8*)&Alds[rr*64 + ((cc ^ (rr & 7))*8)];
      }
      #pragma unroll
      for (int j = 0; j < 4; ++j) {
        int rr = wn + 16*j + t;
        bfr[j] = *(const short8*)&Blds[rr*64 + ((cc ^ (rr & 7))*8)];
      }
      #pragma unroll
      for (int i = 0; i < 4; ++i)
        #pragma unroll
        for (int j = 0; j < 4; ++j)
          acc[i][j] = __builtin_amdgcn_mfma_f32_16x16x32_bf16(af[i], bfr[j], acc[i][j], 0, 0, 0);
    }
    __syncthreads();
  }
  #pragma unroll
  for (int i = 0; i < 4; ++i) {
    #pragma unroll
    for (int r = 0; r < 4; ++r) {
      unsigned int tok = ordl[wm + 16*i + q*4 + r];
      float* op = out + (size_t)tok*DM + cb;
      #pragma unroll
      for (int j = 0; j < 4; ++j) {
        int col = wn + 16*j + t;
        op[col] += 0.5f*acc[i][j][r];
      }
    }
  }
}

// ---------------- dt path: 8 rows/wave, LDS weights, fp32, fused softplus ----------------
// Grid: 2L/32 blocks of 256 (4 waves x 8 rows). Lane (r=l>>3, kg=l&7).
// LDS skew: off(k) = k*8 + (k>>5)*4 -> the 8 k-groups hit disjoint 4-bank spans.

__global__ __launch_bounds__(256) void dt_gemv(const float* __restrict__ qn, const float* __restrict__ W,
                                               const unsigned int* __restrict__ ord,
                                               const float* __restrict__ dt_bias, float* __restrict__ dtb) {
  __shared__ float Wl[2080];
  int tid = threadIdx.x;
  {
    const float* wp = W + (size_t)tid*DP + (DI + CD);
    float4 wa = *(const float4*)wp;
    float4 wb = *(const float4*)(wp + 4);
    int off = tid*8 + (tid >> 5)*4;
    *(float4*)&Wl[off]     = wa;
    *(float4*)&Wl[off + 4] = wb;
  }
  __syncthreads();
  int lane = tid & 63, w = tid >> 6;
  int r = blockIdx.x*32 + w*8 + (lane >> 3);
  int kg = lane & 7;
  int dir = r >> 14, lrow = r & (L_TOK - 1);
  unsigned int src = ord[(size_t)dir*L_TOK + lrow];
  const float* qp = qn + (size_t)src*DM + kg*32;
  float acc[8] = {};
  #pragma unroll
  for (int i = 0; i < 8; ++i) {
    float4 q4 = *(const float4*)(qp + i*4);
    float qv[4] = {q4.x, q4.y, q4.z, q4.w};
    #pragma unroll
    for (int e = 0; e < 4; ++e) {
      int k = kg*32 + i*4 + e;
      int off = k*8 + kg*4;
      float4 wa = *(const float4*)&Wl[off];
      float4 wb = *(const float4*)&Wl[off + 4];
      acc[0] = fmaf(qv[e], wa.x, acc[0]);
      acc[1] = fmaf(qv[e], wa.y, acc[1]);
      acc[2] = fmaf(qv[e], wa.z, acc[2]);
      acc[3] = fmaf(qv[e], wa.w, acc[3]);
      acc[4] = fmaf(qv[e], wb.x, acc[4]);
      acc[5] = fmaf(qv[e], wb.y, acc[5]);
      acc[6] = fmaf(qv[e], wb.z, acc[6]);
      acc[7] = fmaf(qv[e], wb.w, acc[7]);
    }
  }
  #pragma unroll
  for (int h = 0; h < 8; ++h) {
    acc[h] += __shfl_xor(acc[h], 8, 64);
    acc[h] += __shfl_xor(acc[h], 16, 64);
    acc[h] += __shfl_xor(acc[h], 32, 64);
  }
  float v = 0.f;
  #pragma unroll
  for (int h = 0; h < 8; ++h) if (kg == h) v = acc[h];
  v += dt_bias[kg];
  float sp = (v > 0.0f) ? (v + log1pf(expf(-v))) : log1pf(expf(v));
  dtb[(size_t)r*NH + kg] = sp;
}

// ---------------- conv: register-blocked, merged dirs ----------------

__global__ __launch_bounds__(256) void conv_kernel(const unsigned short* __restrict__ xbc, const float* __restrict__ cw,
                                                   const float* __restrict__ cbias, unsigned short* __restrict__ outc) {
  int gid = blockIdx.x*256 + threadIdx.x;
  int dir = gid / 163840;
  int lid = gid - dir*163840;
  int g = lid % 80;
  int ts = lid / 80;
  int t0 = ts*8;
  int ch = g*8;
  const unsigned short* src = xbc + (size_t)dir*L_TOK*CD;
  unsigned short* dst = outc + (size_t)dir*L_TOK*CD;
  float wv[8][4];
  float bias[8];
  #pragma unroll
  for (int e = 0; e < 8; ++e) {
    float4 c4 = *(const float4*)(cw + (ch + e)*4);
    wv[e][0] = c4.x; wv[e][1] = c4.y; wv[e][2] = c4.z; wv[e][3] = c4.w;
  }
  {
    float4 b0 = *(const float4*)(cbias + ch);
    float4 b1 = *(const float4*)(cbias + ch + 4);
    bias[0]=b0.x; bias[1]=b0.y; bias[2]=b0.z; bias[3]=b0.w;
    bias[4]=b1.x; bias[5]=b1.y; bias[6]=b1.z; bias[7]=b1.w;
  }
  float rows[11][8];
  #pragma unroll
  for (int r = 0; r < 11; ++r) {
    int t = t0 - 3 + r;
    if (t >= 0) {
      short8 v = *(const short8*)(src + (size_t)t*CD + ch);
      #pragma unroll
      for (int e = 0; e < 8; ++e) rows[r][e] = bf2f((unsigned short)v[e]);
    } else {
      #pragma unroll
      for (int e = 0; e < 8; ++e) rows[r][e] = 0.f;
    }
  }
  #pragma unroll
  for (int tt = 0; tt < 8; ++tt) {
    short8 o;
    #pragma unroll
    for (int e = 0; e < 8; ++e) {
      float s = bias[e];
      #pragma unroll
      for (int k = 0; k < 4; ++k)
        s = fmaf(wv[e][k], rows[tt + k][e], s);
      o[e] = (short)f2bf(siluf(s));
    }
    *(short8*)(dst + (size_t)(t0 + tt)*CD + ch) = o;
  }
}

// ---------------- chunked scan (MFMA, bf16 S); dirs merged via blockIdx.z ----------------

__global__ __launch_bounds__(256) void phaseA_mfma(const unsigned short* __restrict__ convo,
                                                   const float* __restrict__ dtb, const float* __restrict__ A_log,
                                                   unsigned short* __restrict__ S, float* __restrict__ P) {
  int c = blockIdx.x, h = blockIdx.y, dir = blockIdx.z, tid = threadIdx.x;
  int lane = tid & 63, w = tid >> 6;
  int hh = dir*NH + h;
  const unsigned short* xc = convo + (size_t)dir*L_TOK*CD;
  __shared__ unsigned short xT[64*64];
  __shared__ unsigned short Bt[64*64];
  __shared__ float dts[64], lg[64], sfx[64], wgt[64];
  __shared__ float totals;
  int c0 = c*CHUNK;
  float Ah = -expf(A_log[h]);
  if (tid < 64) {
    float dtv = dtb[(size_t)(dir*L_TOK + c0 + tid)*NH + h];
    dts[tid] = dtv; lg[tid] = dtv*Ah;
  }
  #pragma unroll
  for (int i = 0; i < 2; ++i) {
    int q = tid + 256*i;
    int t = q >> 3, s0 = (q & 7)*8;
    short8 v = *(const short8*)(xc + (size_t)(c0+t)*CD + DI + s0);
    int tc = t >> 3, ti = t & 7;
    #pragma unroll
    for (int e = 0; e < 8; ++e) {
      int s = s0 + e;
      Bt[s*64 + ((tc ^ (s & 7))*8 + ti)] = (unsigned short)v[e];
    }
  }
  __syncthreads();
  if (tid == 0) {
    float run = 0.f;
    for (int t = 63; t >= 0; --t) { sfx[t] = run; run += lg[t]; }
    totals = run;
  }
  __syncthreads();
  if (tid < 64) wgt[tid] = dts[tid]*expf(sfx[tid]);
  if (tid == 0) P[hh*NC + c] = expf(totals);
  __syncthreads();
  #pragma unroll
  for (int i = 0; i < 2; ++i) {
    int q = tid + 256*i;
    int t = q >> 3, p0 = (q & 7)*8;
    short8 v = *(const short8*)(xc + (size_t)(c0+t)*CD + h*HD + p0);
    float wvv = wgt[t];
    int tc = t >> 3, ti = t & 7;
    #pragma unroll
    for (int e = 0; e < 8; ++e) {
      int p = p0 + e;
      xT[p*64 + ((tc ^ (p & 7))*8 + ti)] = f2bf(bf2f((unsigned short)v[e]) * wvv);
    }
  }
  __syncthreads();
  int t16 = lane & 15, q4 = lane >> 4;
  f32x4 zero = {0.f,0.f,0.f,0.f};
  f32x4 acc[4];
  #pragma unroll
  for (int j = 0; j < 4; ++j) acc[j] = zero;
  #pragma unroll
  for (int ks = 0; ks < 2; ++ks) {
    int rowA = 16*w + t16;
    short8 a = *(const short8*)&xT[rowA*64 + (((ks*4 + q4) ^ (rowA & 7))*8)];
    #pragma unroll
    for (int j = 0; j < 4; ++j) {
      int rowB = 16*j + t16;
      short8 b = *(const short8*)&Bt[rowB*64 + (((ks*4 + q4) ^ (rowB & 7))*8)];
      acc[j] = __builtin_amdgcn_mfma_f32_16x16x32_bf16(a, b, acc[j], 0, 0, 0);
    }
  }
  unsigned short* Sp = S + ((size_t)(hh*NC + c))*4096;
  #pragma unroll
  for (int j = 0; j < 4; ++j)
    #pragma unroll
    for (int r = 0; r < 4; ++r)
      Sp[(size_t)(16*w + q4*4 + r)*64 + 16*j + t16] = f2bf(acc[j][r]);
}

// ---- phaseB: hh spans 16 (2 dirs x 8 heads) ----

__global__ __launch_bounds__(256) void phaseB1(const unsigned short* __restrict__ S, const float* __restrict__ P,
                                               float* __restrict__ Ssum, float* __restrict__ Psum) {
  int gid = blockIdx.x*256 + threadIdx.x;
  int e2 = gid & 2047;
  int sc = (gid >> 11) & 15;
  int hh = gid >> 15;
  const unsigned short* base = S + ((size_t)(hh*NC + sc*16))*4096 + e2*2;
  const float* Ph = P + hh*NC + sc*16;
  float hx = 0.f, hy = 0.f, pprod = 1.f;
  #pragma unroll
  for (int k = 0; k < 16; ++k) {
    unsigned int v = *(const unsigned int*)(base + (size_t)k*4096);
    float p = Ph[k];
    hx = p*hx + bf2f((unsigned short)(v & 0xffffu));
    hy = p*hy + bf2f((unsigned short)(v >> 16));
    pprod *= p;
  }
  float* sp = Ssum + ((size_t)(hh*16 + sc))*4096 + e2*2;
  sp[0] = hx; sp[1] = hy;
  if (e2 == 0) Psum[hh*16 + sc] = pprod;
}

__global__ __launch_bounds__(256) void phaseB3(unsigned short* __restrict__ S, const float* __restrict__ P,
                                               const float* __restrict__ Ssum, const float* __restrict__ Psum) {
  int gid = blockIdx.x*256 + threadIdx.x;
  int e2 = gid & 2047;
  int sc = (gid >> 11) & 15;
  int hh = gid >> 15;
  float hx = 0.f, hy = 0.f;
  for (int s2 = 0; s2 < sc; ++s2) {
    float pp = Psum[hh*16 + s2];
    const float* sp = Ssum + ((size_t)(hh*16 + s2))*4096 + e2*2;
    hx = pp*hx + sp[0];
    hy = pp*hy + sp[1];
  }
  unsigned short* base = S + ((size_t)(hh*NC + sc*16))*4096 + e2*2;
  const float* Ph = P + hh*NC + sc*16;
  #pragma unroll
  for (int k = 0; k < 16; ++k) {
    unsigned int* ptr = (unsigned int*)(base + (size_t)k*4096);
    unsigned int v = *ptr;
    float p = Ph[k];
    *ptr = (unsigned int)f2bf(hx) | ((unsigned int)f2bf(hy) << 16);
    hx = p*hx + bf2f((unsigned short)(v & 0xffffu));
    hy = p*hy + bf2f((unsigned short)(v >> 16));
  }
}

// phaseC: dirs merged; Y written into xbc buffer region (stride DI)
__global__ __launch_bounds__(256) void phaseC_mfma(const unsigned short* __restrict__ convo,
                                                   const float* __restrict__ dtb, const float* __restrict__ A_log,
                                                   const float* __restrict__ Dp,
                                                   const unsigned short* __restrict__ S,
                                                   unsigned short* __restrict__ ybase) {
  int c = blockIdx.x, h = blockIdx.y, dir = blockIdx.z, tid = threadIdx.x;
  int lane = tid & 63, w = tid >> 6;
  int hh = dir*NH + h;
  const unsigned short* xc = convo + (size_t)dir*L_TOK*CD;
  unsigned short* y = ybase + (size_t)dir*L_TOK*CD;
  __shared__ unsigned short Cl[64*64];
  __shared__ unsigned short Bl[64*64];
  __shared__ unsigned short h0l[64*64];
  __shared__ unsigned short xT[64*64];
  __shared__ unsigned short Gl[64*64];
  __shared__ float dts[64], lg[64], pl[64], pe[64];
  int c0 = c*CHUNK;
  float Ah = -expf(A_log[h]);
  float Dh = Dp[h];
  if (tid < 64) {
    float dtv = dtb[(size_t)(dir*L_TOK + c0 + tid)*NH + h];
    dts[tid] = dtv; lg[tid] = dtv*Ah;
  }
  const unsigned short* Sp = S + ((size_t)(hh*NC + c))*4096;
  #pragma unroll
  for (int i = 0; i < 2; ++i) {
    int q = tid + 256*i;
    int t = q >> 3, d0 = (q & 7)*8;
    int swoff = t*64 + (((q & 7) ^ (t & 7))*8);
    *(short8*)&Cl[swoff] = *(const short8*)(xc + (size_t)(c0+t)*CD + DI + DS + d0);
    *(short8*)&Bl[swoff] = *(const short8*)(xc + (size_t)(c0+t)*CD + DI + d0);
    *(short8*)&h0l[swoff] = *(const short8*)(Sp + (size_t)t*64 + d0);
    short8 xv = *(const short8*)(xc + (size_t)(c0+t)*CD + h*HD + d0);
    int tc = t >> 3, ti = t & 7;
    #pragma unroll
    for (int e = 0; e < 8; ++e) {
      int p = d0 + e;
      xT[p*64 + ((tc ^ (p & 7))*8 + ti)] = (unsigned short)xv[e];
    }
  }
  __syncthreads();
  if (tid == 0) {
    float run = 0.f;
    for (int t = 0; t < 64; ++t) { run += lg[t]; pl[t] = run; }
  }
  __syncthreads();
  if (tid < 64) pe[tid] = expf(pl[tid]);
  __syncthreads();
  int t16 = lane & 15, q4 = lane >> 4;
  int t0 = 16*w;
  f32x4 zero = {0.f,0.f,0.f,0.f};
  f32x4 accG[4], accY[4];
  #pragma unroll
  for (int j = 0; j < 4; ++j) { accG[j] = zero; accY[j] = zero; }
  #pragma unroll
  for (int ks = 0; ks < 2; ++ks) {
    int rowA = t0 + t16;
    short8 a = *(const short8*)&Cl[rowA*64 + (((ks*4 + q4) ^ (rowA & 7))*8)];
    #pragma unroll
    for (int j = 0; j < 4; ++j) {
      int rowB = 16*j + t16;
      int off = rowB*64 + (((ks*4 + q4) ^ (rowB & 7))*8);
      accG[j] = __builtin_amdgcn_mfma_f32_16x16x32_bf16(a, *(const short8*)&Bl[off], accG[j], 0, 0, 0);
      accY[j] = __builtin_amdgcn_mfma_f32_16x16x32_bf16(a, *(const short8*)&h0l[off], accY[j], 0, 0, 0);
    }
  }
  #pragma unroll
  for (int j = 0; j < 4; ++j) {
    #pragma unroll
    for (int r = 0; r < 4; ++r) {
      int t = t0 + q4*4 + r;
      int s = 16*j + t16;
      float v = 0.f;
      if (s <= t) {
        v = accG[j][r] * dts[s] * expf(pl[t] - pl[s]);
        if (s == t) v += Dh;
      }
      Gl[t*64 + (((s >> 3) ^ (t & 7))*8 + (s & 7))] = f2bf(v);
    }
  }
  #pragma unroll
  for (int j = 0; j < 4; ++j)
    #pragma unroll
    for (int r = 0; r < 4; ++r)
      accY[j][r] *= pe[t0 + q4*4 + r];
  #pragma unroll
  for (int ks = 0; ks < 2; ++ks) {
    int rowA = t0 + t16;
    short8 a = *(const short8*)&Gl[rowA*64 + (((ks*4 + q4) ^ (rowA & 7))*8)];
    #pragma unroll
    for (int j = 0; j < 4; ++j) {
      int rowB = 16*j + t16;
      short8 b = *(const short8*)&xT[rowB*64 + (((ks*4 + q4) ^ (rowB & 7))*8)];
      accY[j] = __builtin_amdgcn_mfma_f32_16x16x32_bf16(a, b, accY[j], 0, 0, 0);
    }
  }
  #pragma unroll
  for (int j = 0; j < 4; ++j)
    #pragma unroll
    for (int r = 0; r < 4; ++r) {
      int t = t0 + q4*4 + r;
      int p = 16*j + t16;
      y[(size_t)(c0+t)*DI + h*HD + p] = f2bf(accY[j][r]);
    }
}

__global__ void fill_debug(float* out, float v) {
  int i = blockIdx.x*256 + threadIdx.x;
  if (i < L_TOK*DM) out[i] = v;
}

// ---------------- host ----------------

extern "C" void kernel_launch(void* const* d_in, const int* in_sizes, int n_in,
                              void* d_out, int out_size, void* d_ws, size_t ws_size,
                              hipStream_t stream) {
  const float* query = (const float*)d_in[0];
  const float* qpos  = (const float*)d_in[1];
  const float* pre_w = (const float*)d_in[2];
  const float* pre_b = (const float*)d_in[3];
  const float* fin_w = (const float*)d_in[4];
  const float* fin_b = (const float*)d_in[5];
  float* out = (float*)d_out;

  char* ws = (char*)d_ws;
  size_t off = 0;
  auto alloc = [&](size_t bytes) -> void* {
    void* p = ws + off;
    off += (bytes + 255) & ~(size_t)255;
    return p;
  };
  unsigned long long* keys = (unsigned long long*)alloc((size_t)2*L_TOK*8);
  unsigned int* ord = (unsigned int*)alloc((size_t)2*L_TOK*4);
  unsigned int* rpart = (unsigned int*)alloc((size_t)32*2*L_TOK*4);
  float* pmm  = (float*)alloc(256);
  float* qn   = (float*)alloc((size_t)L_TOK*DM*4);
  unsigned short* qnbf = (unsigned short*)alloc((size_t)L_TOK*DM*2);
  unsigned short* gatebf = (unsigned short*)alloc((size_t)2*L_TOK*DI*2);
  unsigned short* xbcbf  = (unsigned short*)alloc((size_t)2*L_TOK*CD*2);  // also hosts y (stride DI) after conv
  unsigned short* convo  = (unsigned short*)alloc((size_t)2*L_TOK*CD*2);
  float* dtb  = (float*)alloc((size_t)2*L_TOK*NH*4);
  unsigned short* Sbuf = (unsigned short*)alloc((size_t)2*NH*NC*4096*2);
  float* Pbuf = (float*)alloc((size_t)2*NH*NC*4);
  float* Ssum = (float*)alloc((size_t)2*NH*16*4096*4);
  float* Psum = (float*)alloc((size_t)2*NH*16*4);
  unsigned short* WtA = (unsigned short*)alloc((size_t)1152*DM*2);
  unsigned short* WtO = (unsigned short*)alloc((size_t)DM*DI*2);
  if (off > ws_size) {
    fill_debug<<<(L_TOK*DM + 255)/256, 256, 0, stream>>>(out, (float)(ws_size >> 20));
    return;
  }

  minmax_kernel<<<1, 256, 0, stream>>>(qpos, pmm);
  hilbert_kernel<<<L_TOK/256, 256, 0, stream>>>(qpos, pmm, keys);
  rank_partial<<<dim3(16, 2, 32), 256, 0, stream>>>(keys, rpart);
  rank_scatter<<<(2*L_TOK)/256, 256, 0, stream>>>(keys, rpart, ord);
  hipMemcpyAsync(out, query, (size_t)L_TOK*DM*4, hipMemcpyDeviceToDevice, stream);

  for (int l = 0; l < 2; ++l) {
    int base = 6 + 8*l;
    const float* in_proj  = (const float*)d_in[base+0];
    const float* conv_w   = (const float*)d_in[base+1];
    const float* conv_b   = (const float*)d_in[base+2];
    const float* dt_bias  = (const float*)d_in[base+3];
    const float* A_log    = (const float*)d_in[base+4];
    const float* Dp       = (const float*)d_in[base+5];
    const float* norm_w   = (const float*)d_in[base+6];
    const float* out_proj = (const float*)d_in[base+7];

    ln_kernel<<<L_TOK/4, 256, 0, stream>>>(out, qn, qnbf, pre_w, pre_b);
    tcvt_both<<<(1152*DM + DM*DI)/256, 256, 0, stream>>>(in_proj, out_proj, WtA, WtO);
    gemm_in_mfma<<<dim3(9, L_TOK/128, 2), 256, 0, stream>>>(qnbf, WtA, ord, gatebf, xbcbf);
    dt_gemv<<<(2*L_TOK)/32, 256, 0, stream>>>(qn, in_proj, ord, dt_bias, dtb);
    conv_kernel<<<1280, 256, 0, stream>>>(xbcbf, conv_w, conv_b, convo);
    phaseA_mfma<<<dim3(NC, NH, 2), 256, 0, stream>>>(convo, dtb, A_log, Sbuf, Pbuf);
    phaseB1<<<(16*16*2048)/256, 256, 0, stream>>>(Sbuf, Pbuf, Ssum, Psum);
    phaseB3<<<(16*16*2048)/256, 256, 0, stream>>>(Sbuf, Pbuf, Ssum, Psum);
    phaseC_mfma<<<dim3(NC, NH, 2), 256, 0, stream>>>(convo, dtb, A_log, Dp, Sbuf, xbcbf);
    gating_kernel<<<(2*L_TOK)/4, 256, 0, stream>>>(xbcbf, gatebf, norm_w);
    for (int dir = 0; dir < 2; ++dir)
      gemm_out_mfma<<<dim3(2, L_TOK/128), 256, 0, stream>>>(xbcbf + (size_t)dir*L_TOK*CD, WtO,
                                                            ord + (size_t)dir*L_TOK, out);
    ln_kernel<<<L_TOK/4, 256, 0, stream>>>(out, out, (unsigned short*)nullptr, fin_w, fin_b);
  }
}

// Round 10
// 630.736 us; speedup vs baseline: 1.9813x; 1.0229x over previous
//
#include <hip/hip_runtime.h>
#include <stdint.h>

#define L_TOK 16384
#define DM 256
#define DI 512
#define DS 64
#define NH 8
#define HD 64
#define CD 640
#define DP 1160
#define CHUNK 64
#define NC 256
#define EPSF 1e-5f

typedef __attribute__((ext_vector_type(8))) short short8;
typedef __attribute__((ext_vector_type(4))) float f32x4;

#define GLL16(gp, lp) __builtin_amdgcn_global_load_lds((const __attribute__((address_space(1))) void*)(gp), (__attribute__((address_space(3))) void*)(lp), 16, 0, 0)

__device__ __forceinline__ float warp_sum(float v) {
  v += __shfl_xor(v, 1, 64);
  v += __shfl_xor(v, 2, 64);
  v += __shfl_xor(v, 4, 64);
  v += __shfl_xor(v, 8, 64);
  v += __shfl_xor(v, 16, 64);
  v += __shfl_xor(v, 32, 64);
  return v;
}

__device__ __forceinline__ float siluf(float x) { return x / (1.0f + expf(-x)); }

__device__ __forceinline__ unsigned short f2bf(float f) {
  unsigned int u = __float_as_uint(f);
  unsigned int r = (u + 0x7FFFu + ((u >> 16) & 1u)) >> 16;
  return (unsigned short)r;
}
__device__ __forceinline__ float bf2f(unsigned short u) {
  return __uint_as_float(((unsigned int)u) << 16);
}

// ---------------- serialization ----------------

__global__ __launch_bounds__(256) void minmax_kernel(const float* __restrict__ pos, float* __restrict__ pmm) {
  __shared__ float sm[6][256];
  int tid = threadIdx.x;
  float mn0=1e30f, mn1=1e30f, mn2=1e30f, mx0=-1e30f, mx1=-1e30f, mx2=-1e30f;
  for (int t = tid; t < L_TOK; t += 256) {
    float a = pos[t*3+0], b = pos[t*3+1], c = pos[t*3+2];
    mn0=fminf(mn0,a); mx0=fmaxf(mx0,a);
    mn1=fminf(mn1,b); mx1=fmaxf(mx1,b);
    mn2=fminf(mn2,c); mx2=fmaxf(mx2,c);
  }
  sm[0][tid]=mn0; sm[1][tid]=mn1; sm[2][tid]=mn2;
  sm[3][tid]=mx0; sm[4][tid]=mx1; sm[5][tid]=mx2;
  __syncthreads();
  for (int s = 128; s > 0; s >>= 1) {
    if (tid < s) {
      #pragma unroll
      for (int d = 0; d < 3; ++d) {
        sm[d][tid]   = fminf(sm[d][tid],   sm[d][tid+s]);
        sm[3+d][tid] = fmaxf(sm[3+d][tid], sm[3+d][tid+s]);
      }
    }
    __syncthreads();
  }
  if (tid < 6) pmm[tid] = sm[tid][0];
}

__device__ unsigned int hilbert3(unsigned int a, unsigned int b, unsigned int c) {
  unsigned int x0 = a, x1 = b, x2 = c;
  for (unsigned int Q = 512u; Q > 1u; Q >>= 1) {
    unsigned int P = Q - 1u;
    { if (x0 & Q) x0 ^= P; }
    {
      unsigned int t = (x0 ^ x1) & P;
      if (x1 & Q) { x0 ^= P; }
      else { x0 ^= t; x1 ^= t; }
    }
    {
      unsigned int t = (x0 ^ x2) & P;
      if (x2 & Q) { x0 ^= P; }
      else { x0 ^= t; x2 ^= t; }
    }
  }
  x1 ^= x0; x2 ^= x1;
  unsigned int tt = 0;
  for (unsigned int Q = 512u; Q > 1u; Q >>= 1)
    if (x2 & Q) tt ^= (Q - 1u);
  x0 ^= tt; x1 ^= tt; x2 ^= tt;
  unsigned int code = 0;
  #pragma unroll
  for (int bb = 9; bb >= 0; --bb) {
    code = (code << 1) | ((x0 >> bb) & 1u);
    code = (code << 1) | ((x1 >> bb) & 1u);
    code = (code << 1) | ((x2 >> bb) & 1u);
  }
  return code;
}

__global__ __launch_bounds__(256) void hilbert_kernel(const float* __restrict__ pos, const float* __restrict__ pmm,
                                                      unsigned long long* __restrict__ keys) {
  int t = blockIdx.x*256 + threadIdx.x;
  if (t >= L_TOK) return;
  unsigned int g[3];
  #pragma unroll
  for (int d = 0; d < 3; ++d) {
    float v = (pos[t*3+d] - pmm[d]) / (pmm[3+d] - pmm[d] + 1e-6f) * 1023.0f;
    v = fminf(fmaxf(v, 0.0f), 1023.0f);
    g[d] = (unsigned int)(int)v;
  }
  unsigned int ca = hilbert3(g[0], g[1], g[2]);
  unsigned int cb = hilbert3(g[1], g[0], g[2]);
  keys[t]         = ((unsigned long long)ca << 14) | (unsigned long long)t;
  keys[L_TOK + t] = ((unsigned long long)cb << 14) | (unsigned long long)t;
}

__global__ __launch_bounds__(256) void rank_partial(const unsigned long long* __restrict__ keys,
                                                    unsigned int* __restrict__ partial) {
  __shared__ unsigned long long tile[512];
  int arr = blockIdx.y, ks = blockIdx.z;
  const unsigned long long* k = keys + (size_t)arr * L_TOK;
  int qbase = blockIdx.x*1024 + threadIdx.x;
  unsigned long long q[4];
  #pragma unroll
  for (int i = 0; i < 4; ++i) q[i] = k[qbase + 256*i];
  const unsigned long long* src = k + ks*512;
  #pragma unroll
  for (int t = 0; t < 2; ++t) tile[threadIdx.x + 256*t] = src[threadIdx.x + 256*t];
  __syncthreads();
  unsigned int r[4] = {};
  const ulonglong2* t2 = (const ulonglong2*)tile;
  #pragma unroll 4
  for (int j = 0; j < 256; ++j) {
    ulonglong2 v = t2[j];
    #pragma unroll
    for (int i = 0; i < 4; ++i) {
      r[i] += (v.x < q[i]) ? 1u : 0u;
      r[i] += (v.y < q[i]) ? 1u : 0u;
    }
  }
  #pragma unroll
  for (int i = 0; i < 4; ++i)
    partial[(size_t)(ks*2 + arr)*L_TOK + qbase + 256*i] = r[i];
}

__global__ __launch_bounds__(256) void rank_scatter(const unsigned long long* __restrict__ keys,
                                                    const unsigned int* __restrict__ partial,
                                                    unsigned int* __restrict__ ord) {
  int i = blockIdx.x*256 + threadIdx.x;
  int arr = i >> 14;
  int qi = i & (L_TOK - 1);
  unsigned int r = 0;
  #pragma unroll
  for (int ks = 0; ks < 32; ++ks) r += partial[(size_t)(ks*2 + arr)*L_TOK + qi];
  ord[(size_t)arr*L_TOK + r] = (unsigned int)(keys[i] & 0x3FFFu);
}

// ---------------- layernorm / gating ----------------

__global__ __launch_bounds__(256) void ln_kernel(const float* __restrict__ in, float* __restrict__ out,
                                                 unsigned short* __restrict__ outbf,
                                                 const float* __restrict__ w, const float* __restrict__ b) {
  int row = blockIdx.x*4 + (threadIdx.x >> 6);
  int lane = threadIdx.x & 63;
  const float4 v = *(const float4*)(in + (size_t)row*DM + lane*4);
  float s = v.x + v.y + v.z + v.w;
  float mean = warp_sum(s) * (1.0f/DM);
  float4 xc = make_float4(v.x-mean, v.y-mean, v.z-mean, v.w-mean);
  float ss = xc.x*xc.x + xc.y*xc.y + xc.z*xc.z + xc.w*xc.w;
  ss = warp_sum(ss) * (1.0f/DM);
  float inv = rsqrtf(ss + EPSF);
  const float4 w4 = *(const float4*)(w + lane*4);
  const float4 b4 = *(const float4*)(b + lane*4);
  float4 o;
  o.x = xc.x*inv*w4.x + b4.x;
  o.y = xc.y*inv*w4.y + b4.y;
  o.z = xc.z*inv*w4.z + b4.z;
  o.w = xc.w*inv*w4.w + b4.w;
  *(float4*)(out + (size_t)row*DM + lane*4) = o;
  if (outbf) {
    ushort4 ob = make_ushort4(f2bf(o.x), f2bf(o.y), f2bf(o.z), f2bf(o.w));
    *(ushort4*)(outbf + (size_t)row*DM + lane*4) = ob;
  }
}

__global__ __launch_bounds__(256) void gating_kernel(unsigned short* __restrict__ ybase,
                                                     const unsigned short* __restrict__ gatebf,
                                                     const float* __restrict__ nw) {
  int row = blockIdx.x*4 + (threadIdx.x >> 6);
  int lane = threadIdx.x & 63;
  int dir = row >> 14, lrow = row & (L_TOK - 1);
  unsigned short* yr = ybase + (size_t)dir*L_TOK*CD + (size_t)lrow*DI;
  const unsigned short* gr = gatebf + (size_t)dir*L_TOK*DI + (size_t)lrow*DI;
  ushort4 yu0 = *(const ushort4*)(yr + lane*4);
  ushort4 yu1 = *(const ushort4*)(yr + 256 + lane*4);
  ushort4 gu0 = *(const ushort4*)(gr + lane*4);
  ushort4 gu1 = *(const ushort4*)(gr + 256 + lane*4);
  float4 y0 = make_float4(bf2f(yu0.x), bf2f(yu0.y), bf2f(yu0.z), bf2f(yu0.w));
  float4 y1 = make_float4(bf2f(yu1.x), bf2f(yu1.y), bf2f(yu1.z), bf2f(yu1.w));
  y0.x *= siluf(bf2f(gu0.x)); y0.y *= siluf(bf2f(gu0.y)); y0.z *= siluf(bf2f(gu0.z)); y0.w *= siluf(bf2f(gu0.w));
  y1.x *= siluf(bf2f(gu1.x)); y1.y *= siluf(bf2f(gu1.y)); y1.z *= siluf(bf2f(gu1.z)); y1.w *= siluf(bf2f(gu1.w));
  float ss = y0.x*y0.x + y0.y*y0.y + y0.z*y0.z + y0.w*y0.w
           + y1.x*y1.x + y1.y*y1.y + y1.z*y1.z + y1.w*y1.w;
  ss = warp_sum(ss) * (1.0f/DI);
  float inv = rsqrtf(ss + EPSF);
  const float4 w0 = *(const float4*)(nw + lane*4);
  const float4 w1 = *(const float4*)(nw + 256 + lane*4);
  y0.x *= inv*w0.x; y0.y *= inv*w0.y; y0.z *= inv*w0.z; y0.w *= inv*w0.w;
  y1.x *= inv*w1.x; y1.y *= inv*w1.y; y1.z *= inv*w1.z; y1.w *= inv*w1.w;
  *(ushort4*)(yr + lane*4)       = make_ushort4(f2bf(y0.x), f2bf(y0.y), f2bf(y0.z), f2bf(y0.w));
  *(ushort4*)(yr + 256 + lane*4) = make_ushort4(f2bf(y1.x), f2bf(y1.y), f2bf(y1.z), f2bf(y1.w));
}

// ---------------- weight transpose+convert ----------------

__global__ __launch_bounds__(256) void tcvt_both(const float* __restrict__ Wi, const float* __restrict__ Wo,
                                                 unsigned short* __restrict__ WtA, unsigned short* __restrict__ WtO) {
  int idx = blockIdx.x*256 + threadIdx.x;
  if (idx < 1152*DM) {
    int n = idx >> 8, k = idx & 255;
    WtA[idx] = f2bf(Wi[(size_t)k*DP + n]);
  } else {
    int j = idx - 1152*DM;
    int n = j >> 9, k = j & 511;
    WtO[j] = f2bf(Wo[(size_t)k*DM + n]);
  }
}

// ---------------- MFMA GEMMs ----------------

__global__ __launch_bounds__(256) void gemm_in_mfma(const unsigned short* __restrict__ Abf,
                                                    const unsigned short* __restrict__ Wt,
                                                    const unsigned int* __restrict__ ord,
                                                    unsigned short* __restrict__ gatebf,
                                                    unsigned short* __restrict__ xbcbf) {
  __shared__ unsigned short Alds[128*64];
  __shared__ unsigned short Blds[128*64];
  int tid = threadIdx.x, lane = tid & 63, w = tid >> 6;
  int rb = blockIdx.y*128, cb = blockIdx.x*128;
  int dir = blockIdx.z;
  const unsigned int* ordp = ord + (size_t)dir*L_TOK;
  int wm = (w & 1)*64, wn = (w >> 1)*64;
  const unsigned short* pA[4]; const unsigned short* pB[4];
  unsigned short* dA[4]; unsigned short* dB[4];
  #pragma unroll
  for (int s = 0; s < 4; ++s) {
    int inst = w*4 + s;
    int r = inst*8 + (lane >> 3);
    int cA = (lane & 7) ^ (r & 7);
    pA[s] = Abf + (size_t)ordp[rb + r]*DM + cA*8;
    pB[s] = Wt + (size_t)(cb + r)*DM + cA*8;
    dA[s] = &Alds[inst*512];
    dB[s] = &Blds[inst*512];
  }
  f32x4 zero = {0.f, 0.f, 0.f, 0.f};
  f32x4 acc[4][4];
  #pragma unroll
  for (int i = 0; i < 4; ++i)
    #pragma unroll
    for (int j = 0; j < 4; ++j) acc[i][j] = zero;
  int t = lane & 15, q = lane >> 4;
  for (int k0 = 0; k0 < DM; k0 += 64) {
    #pragma unroll
    for (int s = 0; s < 4; ++s) GLL16(pA[s] + k0, dA[s]);
    #pragma unroll
    for (int s = 0; s < 4; ++s) GLL16(pB[s] + k0, dB[s]);
    __syncthreads();
    #pragma unroll
    for (int ks = 0; ks < 2; ++ks) {
      short8 af[4], bfr[4];
      int cc = ks*4 + q;
      #pragma unroll
      for (int i = 0; i < 4; ++i) {
        int rr = wm + 16*i + t;
        af[i] = *(const short8*)&Alds[rr*64 + ((cc ^ (rr & 7))*8)];
      }
      #pragma unroll
      for (int j = 0; j < 4; ++j) {
        int rr = wn + 16*j + t;
        bfr[j] = *(const short8*)&Blds[rr*64 + ((cc ^ (rr & 7))*8)];
      }
      #pragma unroll
      for (int i = 0; i < 4; ++i)
        #pragma unroll
        for (int j = 0; j < 4; ++j)
          acc[i][j] = __builtin_amdgcn_mfma_f32_16x16x32_bf16(af[i], bfr[j], acc[i][j], 0, 0, 0);
    }
    __syncthreads();
  }
  unsigned short* dst; int ld;
  if (cb < DI) { dst = gatebf + (size_t)dir*L_TOK*DI + cb; ld = DI; }
  else         { dst = xbcbf + (size_t)dir*L_TOK*CD + (cb - DI); ld = CD; }
  #pragma unroll
  for (int i = 0; i < 4; ++i) {
    int rowb = rb + wm + 16*i + q*4;
    #pragma unroll
    for (int j = 0; j < 4; ++j) {
      int col = wn + 16*j + t;
      #pragma unroll
      for (int r = 0; r < 4; ++r)
        dst[(size_t)(rowb + r)*ld + col] = f2bf(acc[i][j][r]);
    }
  }
}

__global__ __launch_bounds__(256) void gemm_out_mfma(const unsigned short* __restrict__ Abf,
                                                     const unsigned short* __restrict__ Wt,
                                                     const unsigned int* __restrict__ ordp,
                                                     float* __restrict__ out) {
  __shared__ unsigned short Alds[128*64];
  __shared__ unsigned short Blds[128*64];
  __shared__ unsigned int ordl[128];
  int tid = threadIdx.x, lane = tid & 63, w = tid >> 6;
  int rb = blockIdx.y*128, cb = blockIdx.x*128;
  int wm = (w & 1)*64, wn = (w >> 1)*64;
  if (tid < 128) ordl[tid] = ordp[rb + tid];
  const unsigned short* pA[4]; const unsigned short* pB[4];
  unsigned short* dA[4]; unsigned short* dB[4];
  #pragma unroll
  for (int s = 0; s < 4; ++s) {
    int inst = w*4 + s;
    int r = inst*8 + (lane >> 3);
    int cA = (lane & 7) ^ (r & 7);
    pA[s] = Abf + (size_t)(rb + r)*DI + cA*8;
    pB[s] = Wt + (size_t)(cb + r)*DI + cA*8;
    dA[s] = &Alds[inst*512];
    dB[s] = &Blds[inst*512];
  }
  f32x4 zero = {0.f, 0.f, 0.f, 0.f};
  f32x4 acc[4][4];
  #pragma unroll
  for (int i = 0; i < 4; ++i)
    #pragma unroll
    for (int j = 0; j < 4; ++j) acc[i][j] = zero;
  int t = lane & 15, q = lane >> 4;
  for (int k0 = 0; k0 < DI; k0 += 64) {
    #pragma unroll
    for (int s = 0; s < 4; ++s) GLL16(pA[s] + k0, dA[s]);
    #pragma unroll
    for (int s = 0; s < 4; ++s) GLL16(pB[s] + k0, dB[s]);
    __syncthreads();
    #pragma unroll
    for (int ks = 0; ks < 2; ++ks) {
      short8 af[4], bfr[4];
      int cc = ks*4 + q;
      #pragma unroll
      for (int i = 0; i < 4; ++i) {
        int rr = wm + 16*i + t;
        af[i] = *(const short8*)&Alds[rr*64 + ((cc ^ (rr & 7))*8)];
      }
      #pragma unroll
      for (int j = 0; j < 4; ++j) {
        int rr = wn + 16*j + t;
        bfr[j] = *(const short8*)&Blds[rr*64 + ((cc ^ (rr & 7))*8)];
      }
      #pragma unroll
      for (int i = 0; i < 4; ++i)
        #pragma unroll
        for (int j = 0; j < 4; ++j)
          acc[i][j] = __builtin_amdgcn_mfma_f32_16x16x32_bf16(af[i], bfr[j], acc[i][j], 0, 0, 0);
    }
    __syncthreads();
  }
  #pragma unroll
  for (int i = 0; i < 4; ++i) {
    #pragma unroll
    for (int r = 0; r < 4; ++r) {
      unsigned int tok = ordl[wm + 16*i + q*4 + r];
      float* op = out + (size_t)tok*DM + cb;
      #pragma unroll
      for (int j = 0; j < 4; ++j) {
        int col = wn + 16*j + t;
        op[col] += 0.5f*acc[i][j][r];
      }
    }
  }
}

// ---------------- dt path: 8 rows/wave, LDS weights, fp32, fused softplus ----------------

__global__ __launch_bounds__(256) void dt_gemv(const float* __restrict__ qn, const float* __restrict__ W,
                                               const unsigned int* __restrict__ ord,
                                               const float* __restrict__ dt_bias, float* __restrict__ dtb) {
  __shared__ float Wl[2080];
  int tid = threadIdx.x;
  {
    const float* wp = W + (size_t)tid*DP + (DI + CD);
    float4 wa = *(const float4*)wp;
    float4 wb = *(const float4*)(wp + 4);
    int off = tid*8 + (tid >> 5)*4;
    *(float4*)&Wl[off]     = wa;
    *(float4*)&Wl[off + 4] = wb;
  }
  __syncthreads();
  int lane = tid & 63, w = tid >> 6;
  int r = blockIdx.x*32 + w*8 + (lane >> 3);
  int kg = lane & 7;
  int dir = r >> 14, lrow = r & (L_TOK - 1);
  unsigned int src = ord[(size_t)dir*L_TOK + lrow];
  const float* qp = qn + (size_t)src*DM + kg*32;
  float acc[8] = {};
  #pragma unroll
  for (int i = 0; i < 8; ++i) {
    float4 q4 = *(const float4*)(qp + i*4);
    float qv[4] = {q4.x, q4.y, q4.z, q4.w};
    #pragma unroll
    for (int e = 0; e < 4; ++e) {
      int k = kg*32 + i*4 + e;
      int off = k*8 + kg*4;
      float4 wa = *(const float4*)&Wl[off];
      float4 wb = *(const float4*)&Wl[off + 4];
      acc[0] = fmaf(qv[e], wa.x, acc[0]);
      acc[1] = fmaf(qv[e], wa.y, acc[1]);
      acc[2] = fmaf(qv[e], wa.z, acc[2]);
      acc[3] = fmaf(qv[e], wa.w, acc[3]);
      acc[4] = fmaf(qv[e], wb.x, acc[4]);
      acc[5] = fmaf(qv[e], wb.y, acc[5]);
      acc[6] = fmaf(qv[e], wb.z, acc[6]);
      acc[7] = fmaf(qv[e], wb.w, acc[7]);
    }
  }
  #pragma unroll
  for (int h = 0; h < 8; ++h) {
    acc[h] += __shfl_xor(acc[h], 8, 64);
    acc[h] += __shfl_xor(acc[h], 16, 64);
    acc[h] += __shfl_xor(acc[h], 32, 64);
  }
  float v = 0.f;
  #pragma unroll
  for (int h = 0; h < 8; ++h) if (kg == h) v = acc[h];
  v += dt_bias[kg];
  float sp = (v > 0.0f) ? (v + log1pf(expf(-v))) : log1pf(expf(v));
  dtb[(size_t)r*NH + kg] = sp;
}

// ---------------- conv: LDS-tiled, 128 tokens x 64 ch per block ----------------
// grid (10 ch-groups, 128 token-tiles, 2 dirs). LDS rows swizzled: chunk cgc of row r
// lives at r*64 + ((cgc^(r&7))*8). Thread (cg=tid&7, tp=tid>>3) computes tokens
// {tp, tp+32, tp+64, tp+96} x 8 channels -> Latin-square bank access, conflict-free.

__global__ __launch_bounds__(256) void conv_kernel(const unsigned short* __restrict__ xbc, const float* __restrict__ cw,
                                                   const float* __restrict__ cbias, unsigned short* __restrict__ outc) {
  __shared__ unsigned short tile[131*64];
  int tid = threadIdx.x;
  int ch0 = blockIdx.x*64;
  int t0  = blockIdx.y*128;
  int dir = blockIdx.z;
  const unsigned short* src = xbc + (size_t)dir*L_TOK*CD;
  unsigned short* dst = outc + (size_t)dir*L_TOK*CD;
  for (int c = tid; c < 131*8; c += 256) {
    int r = c >> 3, cgc = c & 7;
    int t = t0 - 3 + r;
    short8 v = {0,0,0,0,0,0,0,0};
    if (t >= 0) v = *(const short8*)(src + (size_t)t*CD + ch0 + cgc*8);
    *(short8*)&tile[r*64 + ((cgc ^ (r & 7))*8)] = v;
  }
  int cg = tid & 7, tp = tid >> 3;
  int ch = ch0 + cg*8;
  float wv[8][4];
  float bias[8];
  #pragma unroll
  for (int e = 0; e < 8; ++e) {
    float4 c4 = *(const float4*)(cw + (ch + e)*4);
    wv[e][0] = c4.x; wv[e][1] = c4.y; wv[e][2] = c4.z; wv[e][3] = c4.w;
  }
  {
    float4 b0 = *(const float4*)(cbias + ch);
    float4 b1 = *(const float4*)(cbias + ch + 4);
    bias[0]=b0.x; bias[1]=b0.y; bias[2]=b0.z; bias[3]=b0.w;
    bias[4]=b1.x; bias[5]=b1.y; bias[6]=b1.z; bias[7]=b1.w;
  }
  __syncthreads();
  #pragma unroll
  for (int tk = 0; tk < 4; ++tk) {
    int rel = tp + 32*tk;
    float acc[8];
    #pragma unroll
    for (int e = 0; e < 8; ++e) acc[e] = bias[e];
    #pragma unroll
    for (int k = 0; k < 4; ++k) {
      int r = rel + k;
      short8 v = *(const short8*)&tile[r*64 + ((cg ^ (r & 7))*8)];
      #pragma unroll
      for (int e = 0; e < 8; ++e)
        acc[e] = fmaf(wv[e][k], bf2f((unsigned short)v[e]), acc[e]);
    }
    short8 o;
    #pragma unroll
    for (int e = 0; e < 8; ++e) o[e] = (short)f2bf(siluf(acc[e]));
    *(short8*)(dst + (size_t)(t0 + rel)*CD + ch) = o;
  }
}

// ---------------- chunked scan (MFMA, bf16 S); dirs merged via blockIdx.z ----------------

__global__ __launch_bounds__(256) void phaseA_mfma(const unsigned short* __restrict__ convo,
                                                   const float* __restrict__ dtb, const float* __restrict__ A_log,
                                                   unsigned short* __restrict__ S, float* __restrict__ P) {
  int c = blockIdx.x, h = blockIdx.y, dir = blockIdx.z, tid = threadIdx.x;
  int lane = tid & 63, w = tid >> 6;
  int hh = dir*NH + h;
  const unsigned short* xc = convo + (size_t)dir*L_TOK*CD;
  __shared__ unsigned short xT[64*64];
  __shared__ unsigned short Bt[64*64];
  __shared__ float dts[64], lg[64], sfx[64], wgt[64];
  __shared__ float totals;
  int c0 = c*CHUNK;
  float Ah = -expf(A_log[h]);
  if (tid < 64) {
    float dtv = dtb[(size_t)(dir*L_TOK + c0 + tid)*NH + h];
    dts[tid] = dtv; lg[tid] = dtv*Ah;
  }
  #pragma unroll
  for (int i = 0; i < 2; ++i) {
    int q = tid + 256*i;
    int t = q >> 3, s0 = (q & 7)*8;
    short8 v = *(const short8*)(xc + (size_t)(c0+t)*CD + DI + s0);
    int tc = t >> 3, ti = t & 7;
    #pragma unroll
    for (int e = 0; e < 8; ++e) {
      int s = s0 + e;
      Bt[s*64 + ((tc ^ (s & 7))*8 + ti)] = (unsigned short)v[e];
    }
  }
  __syncthreads();
  if (tid == 0) {
    float run = 0.f;
    for (int t = 63; t >= 0; --t) { sfx[t] = run; run += lg[t]; }
    totals = run;
  }
  __syncthreads();
  if (tid < 64) wgt[tid] = dts[tid]*expf(sfx[tid]);
  if (tid == 0) P[hh*NC + c] = expf(totals);
  __syncthreads();
  #pragma unroll
  for (int i = 0; i < 2; ++i) {
    int q = tid + 256*i;
    int t = q >> 3, p0 = (q & 7)*8;
    short8 v = *(const short8*)(xc + (size_t)(c0+t)*CD + h*HD + p0);
    float wvv = wgt[t];
    int tc = t >> 3, ti = t & 7;
    #pragma unroll
    for (int e = 0; e < 8; ++e) {
      int p = p0 + e;
      xT[p*64 + ((tc ^ (p & 7))*8 + ti)] = f2bf(bf2f((unsigned short)v[e]) * wvv);
    }
  }
  __syncthreads();
  int t16 = lane & 15, q4 = lane >> 4;
  f32x4 zero = {0.f,0.f,0.f,0.f};
  f32x4 acc[4];
  #pragma unroll
  for (int j = 0; j < 4; ++j) acc[j] = zero;
  #pragma unroll
  for (int ks = 0; ks < 2; ++ks) {
    int rowA = 16*w + t16;
    short8 a = *(const short8*)&xT[rowA*64 + (((ks*4 + q4) ^ (rowA & 7))*8)];
    #pragma unroll
    for (int j = 0; j < 4; ++j) {
      int rowB = 16*j + t16;
      short8 b = *(const short8*)&Bt[rowB*64 + (((ks*4 + q4) ^ (rowB & 7))*8)];
      acc[j] = __builtin_amdgcn_mfma_f32_16x16x32_bf16(a, b, acc[j], 0, 0, 0);
    }
  }
  unsigned short* Sp = S + ((size_t)(hh*NC + c))*4096;
  #pragma unroll
  for (int j = 0; j < 4; ++j)
    #pragma unroll
    for (int r = 0; r < 4; ++r)
      Sp[(size_t)(16*w + q4*4 + r)*64 + 16*j + t16] = f2bf(acc[j][r]);
}

// ---- phaseB: hh spans 16 (2 dirs x 8 heads) ----

__global__ __launch_bounds__(256) void phaseB1(const unsigned short* __restrict__ S, const float* __restrict__ P,
                                               float* __restrict__ Ssum, float* __restrict__ Psum) {
  int gid = blockIdx.x*256 + threadIdx.x;
  int e2 = gid & 2047;
  int sc = (gid >> 11) & 15;
  int hh = gid >> 15;
  const unsigned short* base = S + ((size_t)(hh*NC + sc*16))*4096 + e2*2;
  const float* Ph = P + hh*NC + sc*16;
  float hx = 0.f, hy = 0.f, pprod = 1.f;
  #pragma unroll
  for (int k = 0; k < 16; ++k) {
    unsigned int v = *(const unsigned int*)(base + (size_t)k*4096);
    float p = Ph[k];
    hx = p*hx + bf2f((unsigned short)(v & 0xffffu));
    hy = p*hy + bf2f((unsigned short)(v >> 16));
    pprod *= p;
  }
  float* sp = Ssum + ((size_t)(hh*16 + sc))*4096 + e2*2;
  sp[0] = hx; sp[1] = hy;
  if (e2 == 0) Psum[hh*16 + sc] = pprod;
}

__global__ __launch_bounds__(256) void phaseB3(unsigned short* __restrict__ S, const float* __restrict__ P,
                                               const float* __restrict__ Ssum, const float* __restrict__ Psum) {
  int gid = blockIdx.x*256 + threadIdx.x;
  int e2 = gid & 2047;
  int sc = (gid >> 11) & 15;
  int hh = gid >> 15;
  float hx = 0.f, hy = 0.f;
  for (int s2 = 0; s2 < sc; ++s2) {
    float pp = Psum[hh*16 + s2];
    const float* sp = Ssum + ((size_t)(hh*16 + s2))*4096 + e2*2;
    hx = pp*hx + sp[0];
    hy = pp*hy + sp[1];
  }
  unsigned short* base = S + ((size_t)(hh*NC + sc*16))*4096 + e2*2;
  const float* Ph = P + hh*NC + sc*16;
  #pragma unroll
  for (int k = 0; k < 16; ++k) {
    unsigned int* ptr = (unsigned int*)(base + (size_t)k*4096);
    unsigned int v = *ptr;
    float p = Ph[k];
    *ptr = (unsigned int)f2bf(hx) | ((unsigned int)f2bf(hy) << 16);
    hx = p*hx + bf2f((unsigned short)(v & 0xffffu));
    hy = p*hy + bf2f((unsigned short)(v >> 16));
  }
}

// phaseC: dirs merged; Y written into xbc buffer region (stride DI)
__global__ __launch_bounds__(256) void phaseC_mfma(const unsigned short* __restrict__ convo,
                                                   const float* __restrict__ dtb, const float* __restrict__ A_log,
                                                   const float* __restrict__ Dp,
                                                   const unsigned short* __restrict__ S,
                                                   unsigned short* __restrict__ ybase) {
  int c = blockIdx.x, h = blockIdx.y, dir = blockIdx.z, tid = threadIdx.x;
  int lane = tid & 63, w = tid >> 6;
  int hh = dir*NH + h;
  const unsigned short* xc = convo + (size_t)dir*L_TOK*CD;
  unsigned short* y = ybase + (size_t)dir*L_TOK*CD;
  __shared__ unsigned short Cl[64*64];
  __shared__ unsigned short Bl[64*64];
  __shared__ unsigned short h0l[64*64];
  __shared__ unsigned short xT[64*64];
  __shared__ unsigned short Gl[64*64];
  __shared__ float dts[64], lg[64], pl[64], pe[64];
  int c0 = c*CHUNK;
  float Ah = -expf(A_log[h]);
  float Dh = Dp[h];
  if (tid < 64) {
    float dtv = dtb[(size_t)(dir*L_TOK + c0 + tid)*NH + h];
    dts[tid] = dtv; lg[tid] = dtv*Ah;
  }
  const unsigned short* Sp = S + ((size_t)(hh*NC + c))*4096;
  #pragma unroll
  for (int i = 0; i < 2; ++i) {
    int q = tid + 256*i;
    int t = q >> 3, d0 = (q & 7)*8;
    int swoff = t*64 + (((q & 7) ^ (t & 7))*8);
    *(short8*)&Cl[swoff] = *(const short8*)(xc + (size_t)(c0+t)*CD + DI + DS + d0);
    *(short8*)&Bl[swoff] = *(const short8*)(xc + (size_t)(c0+t)*CD + DI + d0);
    *(short8*)&h0l[swoff] = *(const short8*)(Sp + (size_t)t*64 + d0);
    short8 xv = *(const short8*)(xc + (size_t)(c0+t)*CD + h*HD + d0);
    int tc = t >> 3, ti = t & 7;
    #pragma unroll
    for (int e = 0; e < 8; ++e) {
      int p = d0 + e;
      xT[p*64 + ((tc ^ (p & 7))*8 + ti)] = (unsigned short)xv[e];
    }
  }
  __syncthreads();
  if (tid == 0) {
    float run = 0.f;
    for (int t = 0; t < 64; ++t) { run += lg[t]; pl[t] = run; }
  }
  __syncthreads();
  if (tid < 64) pe[tid] = expf(pl[tid]);
  __syncthreads();
  int t16 = lane & 15, q4 = lane >> 4;
  int t0 = 16*w;
  f32x4 zero = {0.f,0.f,0.f,0.f};
  f32x4 accG[4], accY[4];
  #pragma unroll
  for (int j = 0; j < 4; ++j) { accG[j] = zero; accY[j] = zero; }
  #pragma unroll
  for (int ks = 0; ks < 2; ++ks) {
    int rowA = t0 + t16;
    short8 a = *(const short8*)&Cl[rowA*64 + (((ks*4 + q4) ^ (rowA & 7))*8)];
    #pragma unroll
    for (int j = 0; j < 4; ++j) {
      int rowB = 16*j + t16;
      int off = rowB*64 + (((ks*4 + q4) ^ (rowB & 7))*8);
      accG[j] = __builtin_amdgcn_mfma_f32_16x16x32_bf16(a, *(const short8*)&Bl[off], accG[j], 0, 0, 0);
      accY[j] = __builtin_amdgcn_mfma_f32_16x16x32_bf16(a, *(const short8*)&h0l[off], accY[j], 0, 0, 0);
    }
  }
  #pragma unroll
  for (int j = 0; j < 4; ++j) {
    #pragma unroll
    for (int r = 0; r < 4; ++r) {
      int t = t0 + q4*4 + r;
      int s = 16*j + t16;
      float v = 0.f;
      if (s <= t) {
        v = accG[j][r] * dts[s] * expf(pl[t] - pl[s]);
        if (s == t) v += Dh;
      }
      Gl[t*64 + (((s >> 3) ^ (t & 7))*8 + (s & 7))] = f2bf(v);
    }
  }
  #pragma unroll
  for (int j = 0; j < 4; ++j)
    #pragma unroll
    for (int r = 0; r < 4; ++r)
      accY[j][r] *= pe[t0 + q4*4 + r];
  #pragma unroll
  for (int ks = 0; ks < 2; ++ks) {
    int rowA = t0 + t16;
    short8 a = *(const short8*)&Gl[rowA*64 + (((ks*4 + q4) ^ (rowA & 7))*8)];
    #pragma unroll
    for (int j = 0; j < 4; ++j) {
      int rowB = 16*j + t16;
      short8 b = *(const short8*)&xT[rowB*64 + (((ks*4 + q4) ^ (rowB & 7))*8)];
      accY[j] = __builtin_amdgcn_mfma_f32_16x16x32_bf16(a, b, accY[j], 0, 0, 0);
    }
  }
  #pragma unroll
  for (int j = 0; j < 4; ++j)
    #pragma unroll
    for (int r = 0; r < 4; ++r) {
      int t = t0 + q4*4 + r;
      int p = 16*j + t16;
      y[(size_t)(c0+t)*DI + h*HD + p] = f2bf(accY[j][r]);
    }
}

__global__ void fill_debug(float* out, float v) {
  int i = blockIdx.x*256 + threadIdx.x;
  if (i < L_TOK*DM) out[i] = v;
}

// ---------------- host ----------------

extern "C" void kernel_launch(void* const* d_in, const int* in_sizes, int n_in,
                              void* d_out, int out_size, void* d_ws, size_t ws_size,
                              hipStream_t stream) {
  const float* query = (const float*)d_in[0];
  const float* qpos  = (const float*)d_in[1];
  const float* pre_w = (const float*)d_in[2];
  const float* pre_b = (const float*)d_in[3];
  const float* fin_w = (const float*)d_in[4];
  const float* fin_b = (const float*)d_in[5];
  float* out = (float*)d_out;

  char* ws = (char*)d_ws;
  size_t off = 0;
  auto alloc = [&](size_t bytes) -> void* {
    void* p = ws + off;
    off += (bytes + 255) & ~(size_t)255;
    return p;
  };
  unsigned long long* keys = (unsigned long long*)alloc((size_t)2*L_TOK*8);
  unsigned int* ord = (unsigned int*)alloc((size_t)2*L_TOK*4);
  unsigned int* rpart = (unsigned int*)alloc((size_t)32*2*L_TOK*4);
  float* pmm  = (float*)alloc(256);
  float* qn   = (float*)alloc((size_t)L_TOK*DM*4);
  unsigned short* qnbf = (unsigned short*)alloc((size_t)L_TOK*DM*2);
  unsigned short* gatebf = (unsigned short*)alloc((size_t)2*L_TOK*DI*2);
  unsigned short* xbcbf  = (unsigned short*)alloc((size_t)2*L_TOK*CD*2);  // also hosts y (stride DI) after conv
  unsigned short* convo  = (unsigned short*)alloc((size_t)2*L_TOK*CD*2);
  float* dtb  = (float*)alloc((size_t)2*L_TOK*NH*4);
  unsigned short* Sbuf = (unsigned short*)alloc((size_t)2*NH*NC*4096*2);
  float* Pbuf = (float*)alloc((size_t)2*NH*NC*4);
  float* Ssum = (float*)alloc((size_t)2*NH*16*4096*4);
  float* Psum = (float*)alloc((size_t)2*NH*16*4);
  unsigned short* WtA = (unsigned short*)alloc((size_t)1152*DM*2);
  unsigned short* WtO = (unsigned short*)alloc((size_t)DM*DI*2);
  if (off > ws_size) {
    fill_debug<<<(L_TOK*DM + 255)/256, 256, 0, stream>>>(out, (float)(ws_size >> 20));
    return;
  }

  minmax_kernel<<<1, 256, 0, stream>>>(qpos, pmm);
  hilbert_kernel<<<L_TOK/256, 256, 0, stream>>>(qpos, pmm, keys);
  rank_partial<<<dim3(16, 2, 32), 256, 0, stream>>>(keys, rpart);
  rank_scatter<<<(2*L_TOK)/256, 256, 0, stream>>>(keys, rpart, ord);
  hipMemcpyAsync(out, query, (size_t)L_TOK*DM*4, hipMemcpyDeviceToDevice, stream);

  for (int l = 0; l < 2; ++l) {
    int base = 6 + 8*l;
    const float* in_proj  = (const float*)d_in[base+0];
    const float* conv_w   = (const float*)d_in[base+1];
    const float* conv_b   = (const float*)d_in[base+2];
    const float* dt_bias  = (const float*)d_in[base+3];
    const float* A_log    = (const float*)d_in[base+4];
    const float* Dp       = (const float*)d_in[base+5];
    const float* norm_w   = (const float*)d_in[base+6];
    const float* out_proj = (const float*)d_in[base+7];

    ln_kernel<<<L_TOK/4, 256, 0, stream>>>(out, qn, qnbf, pre_w, pre_b);
    tcvt_both<<<(1152*DM + DM*DI)/256, 256, 0, stream>>>(in_proj, out_proj, WtA, WtO);
    gemm_in_mfma<<<dim3(9, L_TOK/128, 2), 256, 0, stream>>>(qnbf, WtA, ord, gatebf, xbcbf);
    dt_gemv<<<(2*L_TOK)/32, 256, 0, stream>>>(qn, in_proj, ord, dt_bias, dtb);
    conv_kernel<<<dim3(10, 128, 2), 256, 0, stream>>>(xbcbf, conv_w, conv_b, convo);
    phaseA_mfma<<<dim3(NC, NH, 2), 256, 0, stream>>>(convo, dtb, A_log, Sbuf, Pbuf);
    phaseB1<<<(16*16*2048)/256, 256, 0, stream>>>(Sbuf, Pbuf, Ssum, Psum);
    phaseB3<<<(16*16*2048)/256, 256, 0, stream>>>(Sbuf, Pbuf, Ssum, Psum);
    phaseC_mfma<<<dim3(NC, NH, 2), 256, 0, stream>>>(convo, dtb, A_log, Dp, Sbuf, xbcbf);
    gating_kernel<<<(2*L_TOK)/4, 256, 0, stream>>>(xbcbf, gatebf, norm_w);
    for (int dir = 0; dir < 2; ++dir)
      gemm_out_mfma<<<dim3(2, L_TOK/128), 256, 0, stream>>>(xbcbf + (size_t)dir*L_TOK*CD, WtO,
                                                            ord + (size_t)dir*L_TOK, out);
    ln_kernel<<<L_TOK/4, 256, 0, stream>>>(out, out, (unsigned short*)nullptr, fin_w, fin_b);
  }
}

// Round 11
// 610.776 us; speedup vs baseline: 2.0460x; 1.0327x over previous
//
#include <hip/hip_runtime.h>
#include <stdint.h>

#define L_TOK 16384
#define DM 256
#define DI 512
#define DS 64
#define NH 8
#define HD 64
#define CD 640
#define DP 1160
#define CHUNK 64
#define NC 256
#define EPSF 1e-5f

typedef __attribute__((ext_vector_type(8))) short short8;
typedef __attribute__((ext_vector_type(4))) float f32x4;

#define GLL16(gp, lp) __builtin_amdgcn_global_load_lds((const __attribute__((address_space(1))) void*)(gp), (__attribute__((address_space(3))) void*)(lp), 16, 0, 0)

__device__ __forceinline__ float warp_sum(float v) {
  v += __shfl_xor(v, 1, 64);
  v += __shfl_xor(v, 2, 64);
  v += __shfl_xor(v, 4, 64);
  v += __shfl_xor(v, 8, 64);
  v += __shfl_xor(v, 16, 64);
  v += __shfl_xor(v, 32, 64);
  return v;
}

__device__ __forceinline__ float siluf(float x) { return x / (1.0f + expf(-x)); }

__device__ __forceinline__ unsigned short f2bf(float f) {
  unsigned int u = __float_as_uint(f);
  unsigned int r = (u + 0x7FFFu + ((u >> 16) & 1u)) >> 16;
  return (unsigned short)r;
}
__device__ __forceinline__ float bf2f(unsigned short u) {
  return __uint_as_float(((unsigned int)u) << 16);
}

// ---------------- serialization ----------------

__global__ __launch_bounds__(256) void minmax_kernel(const float* __restrict__ pos, float* __restrict__ pmm) {
  __shared__ float sm[6][256];
  int tid = threadIdx.x;
  float mn0=1e30f, mn1=1e30f, mn2=1e30f, mx0=-1e30f, mx1=-1e30f, mx2=-1e30f;
  for (int t = tid; t < L_TOK; t += 256) {
    float a = pos[t*3+0], b = pos[t*3+1], c = pos[t*3+2];
    mn0=fminf(mn0,a); mx0=fmaxf(mx0,a);
    mn1=fminf(mn1,b); mx1=fmaxf(mx1,b);
    mn2=fminf(mn2,c); mx2=fmaxf(mx2,c);
  }
  sm[0][tid]=mn0; sm[1][tid]=mn1; sm[2][tid]=mn2;
  sm[3][tid]=mx0; sm[4][tid]=mx1; sm[5][tid]=mx2;
  __syncthreads();
  for (int s = 128; s > 0; s >>= 1) {
    if (tid < s) {
      #pragma unroll
      for (int d = 0; d < 3; ++d) {
        sm[d][tid]   = fminf(sm[d][tid],   sm[d][tid+s]);
        sm[3+d][tid] = fmaxf(sm[3+d][tid], sm[3+d][tid+s]);
      }
    }
    __syncthreads();
  }
  if (tid < 6) pmm[tid] = sm[tid][0];
}

__device__ unsigned int hilbert3(unsigned int a, unsigned int b, unsigned int c) {
  unsigned int x0 = a, x1 = b, x2 = c;
  for (unsigned int Q = 512u; Q > 1u; Q >>= 1) {
    unsigned int P = Q - 1u;
    { if (x0 & Q) x0 ^= P; }
    {
      unsigned int t = (x0 ^ x1) & P;
      if (x1 & Q) { x0 ^= P; }
      else { x0 ^= t; x1 ^= t; }
    }
    {
      unsigned int t = (x0 ^ x2) & P;
      if (x2 & Q) { x0 ^= P; }
      else { x0 ^= t; x2 ^= t; }
    }
  }
  x1 ^= x0; x2 ^= x1;
  unsigned int tt = 0;
  for (unsigned int Q = 512u; Q > 1u; Q >>= 1)
    if (x2 & Q) tt ^= (Q - 1u);
  x0 ^= tt; x1 ^= tt; x2 ^= tt;
  unsigned int code = 0;
  #pragma unroll
  for (int bb = 9; bb >= 0; --bb) {
    code = (code << 1) | ((x0 >> bb) & 1u);
    code = (code << 1) | ((x1 >> bb) & 1u);
    code = (code << 1) | ((x2 >> bb) & 1u);
  }
  return code;
}

__global__ __launch_bounds__(256) void hilbert_kernel(const float* __restrict__ pos, const float* __restrict__ pmm,
                                                      unsigned long long* __restrict__ keys) {
  int t = blockIdx.x*256 + threadIdx.x;
  if (t >= L_TOK) return;
  unsigned int g[3];
  #pragma unroll
  for (int d = 0; d < 3; ++d) {
    float v = (pos[t*3+d] - pmm[d]) / (pmm[3+d] - pmm[d] + 1e-6f) * 1023.0f;
    v = fminf(fmaxf(v, 0.0f), 1023.0f);
    g[d] = (unsigned int)(int)v;
  }
  unsigned int ca = hilbert3(g[0], g[1], g[2]);
  unsigned int cb = hilbert3(g[1], g[0], g[2]);
  keys[t]         = ((unsigned long long)ca << 14) | (unsigned long long)t;
  keys[L_TOK + t] = ((unsigned long long)cb << 14) | (unsigned long long)t;
}

__global__ __launch_bounds__(256) void rank_partial(const unsigned long long* __restrict__ keys,
                                                    unsigned int* __restrict__ partial) {
  __shared__ unsigned long long tile[512];
  int arr = blockIdx.y, ks = blockIdx.z;
  const unsigned long long* k = keys + (size_t)arr * L_TOK;
  int qbase = blockIdx.x*1024 + threadIdx.x;
  unsigned long long q[4];
  #pragma unroll
  for (int i = 0; i < 4; ++i) q[i] = k[qbase + 256*i];
  const unsigned long long* src = k + ks*512;
  #pragma unroll
  for (int t = 0; t < 2; ++t) tile[threadIdx.x + 256*t] = src[threadIdx.x + 256*t];
  __syncthreads();
  unsigned int r[4] = {};
  const ulonglong2* t2 = (const ulonglong2*)tile;
  #pragma unroll 4
  for (int j = 0; j < 256; ++j) {
    ulonglong2 v = t2[j];
    #pragma unroll
    for (int i = 0; i < 4; ++i) {
      r[i] += (v.x < q[i]) ? 1u : 0u;
      r[i] += (v.y < q[i]) ? 1u : 0u;
    }
  }
  #pragma unroll
  for (int i = 0; i < 4; ++i)
    partial[(size_t)(ks*2 + arr)*L_TOK + qbase + 256*i] = r[i];
}

__global__ __launch_bounds__(256) void rank_scatter(const unsigned long long* __restrict__ keys,
                                                    const unsigned int* __restrict__ partial,
                                                    unsigned int* __restrict__ ord) {
  int i = blockIdx.x*256 + threadIdx.x;
  int arr = i >> 14;
  int qi = i & (L_TOK - 1);
  unsigned int r = 0;
  #pragma unroll
  for (int ks = 0; ks < 32; ++ks) r += partial[(size_t)(ks*2 + arr)*L_TOK + qi];
  ord[(size_t)arr*L_TOK + r] = (unsigned int)(keys[i] & 0x3FFFu);
}

// ---------------- layernorm / gating ----------------

__global__ __launch_bounds__(256) void ln_kernel(const float* __restrict__ in, float* __restrict__ out,
                                                 unsigned short* __restrict__ outbf,
                                                 const float* __restrict__ w, const float* __restrict__ b) {
  int row = blockIdx.x*4 + (threadIdx.x >> 6);
  int lane = threadIdx.x & 63;
  const float4 v = *(const float4*)(in + (size_t)row*DM + lane*4);
  float s = v.x + v.y + v.z + v.w;
  float mean = warp_sum(s) * (1.0f/DM);
  float4 xc = make_float4(v.x-mean, v.y-mean, v.z-mean, v.w-mean);
  float ss = xc.x*xc.x + xc.y*xc.y + xc.z*xc.z + xc.w*xc.w;
  ss = warp_sum(ss) * (1.0f/DM);
  float inv = rsqrtf(ss + EPSF);
  const float4 w4 = *(const float4*)(w + lane*4);
  const float4 b4 = *(const float4*)(b + lane*4);
  float4 o;
  o.x = xc.x*inv*w4.x + b4.x;
  o.y = xc.y*inv*w4.y + b4.y;
  o.z = xc.z*inv*w4.z + b4.z;
  o.w = xc.w*inv*w4.w + b4.w;
  *(float4*)(out + (size_t)row*DM + lane*4) = o;
  if (outbf) {
    ushort4 ob = make_ushort4(f2bf(o.x), f2bf(o.y), f2bf(o.z), f2bf(o.w));
    *(ushort4*)(outbf + (size_t)row*DM + lane*4) = ob;
  }
}

__global__ __launch_bounds__(256) void gating_kernel(unsigned short* __restrict__ ybase,
                                                     const unsigned short* __restrict__ gatebf,
                                                     const float* __restrict__ nw) {
  int row = blockIdx.x*4 + (threadIdx.x >> 6);
  int lane = threadIdx.x & 63;
  int dir = row >> 14, lrow = row & (L_TOK - 1);
  unsigned short* yr = ybase + (size_t)dir*L_TOK*CD + (size_t)lrow*DI;
  const unsigned short* gr = gatebf + (size_t)dir*L_TOK*DI + (size_t)lrow*DI;
  ushort4 yu0 = *(const ushort4*)(yr + lane*4);
  ushort4 yu1 = *(const ushort4*)(yr + 256 + lane*4);
  ushort4 gu0 = *(const ushort4*)(gr + lane*4);
  ushort4 gu1 = *(const ushort4*)(gr + 256 + lane*4);
  float4 y0 = make_float4(bf2f(yu0.x), bf2f(yu0.y), bf2f(yu0.z), bf2f(yu0.w));
  float4 y1 = make_float4(bf2f(yu1.x), bf2f(yu1.y), bf2f(yu1.z), bf2f(yu1.w));
  y0.x *= siluf(bf2f(gu0.x)); y0.y *= siluf(bf2f(gu0.y)); y0.z *= siluf(bf2f(gu0.z)); y0.w *= siluf(bf2f(gu0.w));
  y1.x *= siluf(bf2f(gu1.x)); y1.y *= siluf(bf2f(gu1.y)); y1.z *= siluf(bf2f(gu1.z)); y1.w *= siluf(bf2f(gu1.w));
  float ss = y0.x*y0.x + y0.y*y0.y + y0.z*y0.z + y0.w*y0.w
           + y1.x*y1.x + y1.y*y1.y + y1.z*y1.z + y1.w*y1.w;
  ss = warp_sum(ss) * (1.0f/DI);
  float inv = rsqrtf(ss + EPSF);
  const float4 w0 = *(const float4*)(nw + lane*4);
  const float4 w1 = *(const float4*)(nw + 256 + lane*4);
  y0.x *= inv*w0.x; y0.y *= inv*w0.y; y0.z *= inv*w0.z; y0.w *= inv*w0.w;
  y1.x *= inv*w1.x; y1.y *= inv*w1.y; y1.z *= inv*w1.z; y1.w *= inv*w1.w;
  *(ushort4*)(yr + lane*4)       = make_ushort4(f2bf(y0.x), f2bf(y0.y), f2bf(y0.z), f2bf(y0.w));
  *(ushort4*)(yr + 256 + lane*4) = make_ushort4(f2bf(y1.x), f2bf(y1.y), f2bf(y1.z), f2bf(y1.w));
}

// ---------------- weight transpose+convert ----------------

__global__ __launch_bounds__(256) void tcvt_both(const float* __restrict__ Wi, const float* __restrict__ Wo,
                                                 unsigned short* __restrict__ WtA, unsigned short* __restrict__ WtO) {
  int idx = blockIdx.x*256 + threadIdx.x;
  if (idx < 1152*DM) {
    int n = idx >> 8, k = idx & 255;
    WtA[idx] = f2bf(Wi[(size_t)k*DP + n]);
  } else {
    int j = idx - 1152*DM;
    int n = j >> 9, k = j & 511;
    WtO[j] = f2bf(Wo[(size_t)k*DM + n]);
  }
}

// ---------------- MFMA GEMMs ----------------

// XCD-aware swizzle: bid -> (rb,cb) so each XCD (bid&7 under round-robin) owns a
// contiguous band of 16 row-tiles and sweeps all 9 col-tiles per row-tile -> A rows
// are fetched into that XCD's L2 once instead of 9x.
__global__ __launch_bounds__(256) void gemm_in_mfma(const unsigned short* __restrict__ Abf,
                                                    const unsigned short* __restrict__ Wt,
                                                    const unsigned int* __restrict__ ord,
                                                    unsigned short* __restrict__ gatebf,
                                                    unsigned short* __restrict__ xbcbf) {
  __shared__ unsigned short Alds[128*64];
  __shared__ unsigned short Blds[128*64];
  int tid = threadIdx.x, lane = tid & 63, w = tid >> 6;
  int bid = blockIdx.x;
  int xcd = bid & 7, g = bid >> 3;
  int rb = (xcd*16 + g/9)*128;
  int cb = (g % 9)*128;
  int dir = blockIdx.z;
  const unsigned int* ordp = ord + (size_t)dir*L_TOK;
  int wm = (w & 1)*64, wn = (w >> 1)*64;
  const unsigned short* pA[4]; const unsigned short* pB[4];
  unsigned short* dA[4]; unsigned short* dB[4];
  #pragma unroll
  for (int s = 0; s < 4; ++s) {
    int inst = w*4 + s;
    int r = inst*8 + (lane >> 3);
    int cA = (lane & 7) ^ (r & 7);
    pA[s] = Abf + (size_t)ordp[rb + r]*DM + cA*8;
    pB[s] = Wt + (size_t)(cb + r)*DM + cA*8;
    dA[s] = &Alds[inst*512];
    dB[s] = &Blds[inst*512];
  }
  f32x4 zero = {0.f, 0.f, 0.f, 0.f};
  f32x4 acc[4][4];
  #pragma unroll
  for (int i = 0; i < 4; ++i)
    #pragma unroll
    for (int j = 0; j < 4; ++j) acc[i][j] = zero;
  int t = lane & 15, q = lane >> 4;
  for (int k0 = 0; k0 < DM; k0 += 64) {
    #pragma unroll
    for (int s = 0; s < 4; ++s) GLL16(pA[s] + k0, dA[s]);
    #pragma unroll
    for (int s = 0; s < 4; ++s) GLL16(pB[s] + k0, dB[s]);
    __syncthreads();
    #pragma unroll
    for (int ks = 0; ks < 2; ++ks) {
      short8 af[4], bfr[4];
      int cc = ks*4 + q;
      #pragma unroll
      for (int i = 0; i < 4; ++i) {
        int rr = wm + 16*i + t;
        af[i] = *(const short8*)&Alds[rr*64 + ((cc ^ (rr & 7))*8)];
      }
      #pragma unroll
      for (int j = 0; j < 4; ++j) {
        int rr = wn + 16*j + t;
        bfr[j] = *(const short8*)&Blds[rr*64 + ((cc ^ (rr & 7))*8)];
      }
      #pragma unroll
      for (int i = 0; i < 4; ++i)
        #pragma unroll
        for (int j = 0; j < 4; ++j)
          acc[i][j] = __builtin_amdgcn_mfma_f32_16x16x32_bf16(af[i], bfr[j], acc[i][j], 0, 0, 0);
    }
    __syncthreads();
  }
  unsigned short* dst; int ld;
  if (cb < DI) { dst = gatebf + (size_t)dir*L_TOK*DI + cb; ld = DI; }
  else         { dst = xbcbf + (size_t)dir*L_TOK*CD + (cb - DI); ld = CD; }
  #pragma unroll
  for (int i = 0; i < 4; ++i) {
    int rowb = rb + wm + 16*i + q*4;
    #pragma unroll
    for (int j = 0; j < 4; ++j) {
      int col = wn + 16*j + t;
      #pragma unroll
      for (int r = 0; r < 4; ++r)
        dst[(size_t)(rowb + r)*ld + col] = f2bf(acc[i][j][r]);
    }
  }
}

// per-dir launch (sequential) to keep out-accumulate race-free; same XCD swizzle (2 col-tiles)
__global__ __launch_bounds__(256) void gemm_out_mfma(const unsigned short* __restrict__ Abf,
                                                     const unsigned short* __restrict__ Wt,
                                                     const unsigned int* __restrict__ ordp,
                                                     float* __restrict__ out) {
  __shared__ unsigned short Alds[128*64];
  __shared__ unsigned short Blds[128*64];
  __shared__ unsigned int ordl[128];
  int tid = threadIdx.x, lane = tid & 63, w = tid >> 6;
  int bid = blockIdx.x;
  int xcd = bid & 7, g = bid >> 3;
  int rb = (xcd*16 + (g >> 1))*128;
  int cb = (g & 1)*128;
  int wm = (w & 1)*64, wn = (w >> 1)*64;
  if (tid < 128) ordl[tid] = ordp[rb + tid];
  const unsigned short* pA[4]; const unsigned short* pB[4];
  unsigned short* dA[4]; unsigned short* dB[4];
  #pragma unroll
  for (int s = 0; s < 4; ++s) {
    int inst = w*4 + s;
    int r = inst*8 + (lane >> 3);
    int cA = (lane & 7) ^ (r & 7);
    pA[s] = Abf + (size_t)(rb + r)*DI + cA*8;
    pB[s] = Wt + (size_t)(cb + r)*DI + cA*8;
    dA[s] = &Alds[inst*512];
    dB[s] = &Blds[inst*512];
  }
  f32x4 zero = {0.f, 0.f, 0.f, 0.f};
  f32x4 acc[4][4];
  #pragma unroll
  for (int i = 0; i < 4; ++i)
    #pragma unroll
    for (int j = 0; j < 4; ++j) acc[i][j] = zero;
  int t = lane & 15, q = lane >> 4;
  for (int k0 = 0; k0 < DI; k0 += 64) {
    #pragma unroll
    for (int s = 0; s < 4; ++s) GLL16(pA[s] + k0, dA[s]);
    #pragma unroll
    for (int s = 0; s < 4; ++s) GLL16(pB[s] + k0, dB[s]);
    __syncthreads();
    #pragma unroll
    for (int ks = 0; ks < 2; ++ks) {
      short8 af[4], bfr[4];
      int cc = ks*4 + q;
      #pragma unroll
      for (int i = 0; i < 4; ++i) {
        int rr = wm + 16*i + t;
        af[i] = *(const short8*)&Alds[rr*64 + ((cc ^ (rr & 7))*8)];
      }
      #pragma unroll
      for (int j = 0; j < 4; ++j) {
        int rr = wn + 16*j + t;
        bfr[j] = *(const short8*)&Blds[rr*64 + ((cc ^ (rr & 7))*8)];
      }
      #pragma unroll
      for (int i = 0; i < 4; ++i)
        #pragma unroll
        for (int j = 0; j < 4; ++j)
          acc[i][j] = __builtin_amdgcn_mfma_f32_16x16x32_bf16(af[i], bfr[j], acc[i][j], 0, 0, 0);
    }
    __syncthreads();
  }
  #pragma unroll
  for (int i = 0; i < 4; ++i) {
    #pragma unroll
    for (int r = 0; r < 4; ++r) {
      unsigned int tok = ordl[wm + 16*i + q*4 + r];
      float* op = out + (size_t)tok*DM + cb;
      #pragma unroll
      for (int j = 0; j < 4; ++j) {
        int col = wn + 16*j + t;
        op[col] += 0.5f*acc[i][j][r];
      }
    }
  }
}

// ---------------- dt path: 8 rows/wave, LDS weights, fp32, fused softplus ----------------

__global__ __launch_bounds__(256) void dt_gemv(const float* __restrict__ qn, const float* __restrict__ W,
                                               const unsigned int* __restrict__ ord,
                                               const float* __restrict__ dt_bias, float* __restrict__ dtb) {
  __shared__ float Wl[2080];
  int tid = threadIdx.x;
  {
    const float* wp = W + (size_t)tid*DP + (DI + CD);
    float4 wa = *(const float4*)wp;
    float4 wb = *(const float4*)(wp + 4);
    int off = tid*8 + (tid >> 5)*4;
    *(float4*)&Wl[off]     = wa;
    *(float4*)&Wl[off + 4] = wb;
  }
  __syncthreads();
  int lane = tid & 63, w = tid >> 6;
  int r = blockIdx.x*32 + w*8 + (lane >> 3);
  int kg = lane & 7;
  int dir = r >> 14, lrow = r & (L_TOK - 1);
  unsigned int src = ord[(size_t)dir*L_TOK + lrow];
  const float* qp = qn + (size_t)src*DM + kg*32;
  float acc[8] = {};
  #pragma unroll
  for (int i = 0; i < 8; ++i) {
    float4 q4 = *(const float4*)(qp + i*4);
    float qv[4] = {q4.x, q4.y, q4.z, q4.w};
    #pragma unroll
    for (int e = 0; e < 4; ++e) {
      int k = kg*32 + i*4 + e;
      int off = k*8 + kg*4;
      float4 wa = *(const float4*)&Wl[off];
      float4 wb = *(const float4*)&Wl[off + 4];
      acc[0] = fmaf(qv[e], wa.x, acc[0]);
      acc[1] = fmaf(qv[e], wa.y, acc[1]);
      acc[2] = fmaf(qv[e], wa.z, acc[2]);
      acc[3] = fmaf(qv[e], wa.w, acc[3]);
      acc[4] = fmaf(qv[e], wb.x, acc[4]);
      acc[5] = fmaf(qv[e], wb.y, acc[5]);
      acc[6] = fmaf(qv[e], wb.z, acc[6]);
      acc[7] = fmaf(qv[e], wb.w, acc[7]);
    }
  }
  #pragma unroll
  for (int h = 0; h < 8; ++h) {
    acc[h] += __shfl_xor(acc[h], 8, 64);
    acc[h] += __shfl_xor(acc[h], 16, 64);
    acc[h] += __shfl_xor(acc[h], 32, 64);
  }
  float v = 0.f;
  #pragma unroll
  for (int h = 0; h < 8; ++h) if (kg == h) v = acc[h];
  v += dt_bias[kg];
  float sp = (v > 0.0f) ? (v + log1pf(expf(-v))) : log1pf(expf(v));
  dtb[(size_t)r*NH + kg] = sp;
}

// ---------------- conv: LDS-tiled, 128 tokens x 64 ch per block ----------------

__global__ __launch_bounds__(256) void conv_kernel(const unsigned short* __restrict__ xbc, const float* __restrict__ cw,
                                                   const float* __restrict__ cbias, unsigned short* __restrict__ outc) {
  __shared__ unsigned short tile[131*64];
  int tid = threadIdx.x;
  int ch0 = blockIdx.x*64;
  int t0  = blockIdx.y*128;
  int dir = blockIdx.z;
  const unsigned short* src = xbc + (size_t)dir*L_TOK*CD;
  unsigned short* dst = outc + (size_t)dir*L_TOK*CD;
  for (int c = tid; c < 131*8; c += 256) {
    int r = c >> 3, cgc = c & 7;
    int t = t0 - 3 + r;
    short8 v = {0,0,0,0,0,0,0,0};
    if (t >= 0) v = *(const short8*)(src + (size_t)t*CD + ch0 + cgc*8);
    *(short8*)&tile[r*64 + ((cgc ^ (r & 7))*8)] = v;
  }
  int cg = tid & 7, tp = tid >> 3;
  int ch = ch0 + cg*8;
  float wv[8][4];
  float bias[8];
  #pragma unroll
  for (int e = 0; e < 8; ++e) {
    float4 c4 = *(const float4*)(cw + (ch + e)*4);
    wv[e][0] = c4.x; wv[e][1] = c4.y; wv[e][2] = c4.z; wv[e][3] = c4.w;
  }
  {
    float4 b0 = *(const float4*)(cbias + ch);
    float4 b1 = *(const float4*)(cbias + ch + 4);
    bias[0]=b0.x; bias[1]=b0.y; bias[2]=b0.z; bias[3]=b0.w;
    bias[4]=b1.x; bias[5]=b1.y; bias[6]=b1.z; bias[7]=b1.w;
  }
  __syncthreads();
  #pragma unroll
  for (int tk = 0; tk < 4; ++tk) {
    int rel = tp + 32*tk;
    float acc[8];
    #pragma unroll
    for (int e = 0; e < 8; ++e) acc[e] = bias[e];
    #pragma unroll
    for (int k = 0; k < 4; ++k) {
      int r = rel + k;
      short8 v = *(const short8*)&tile[r*64 + ((cg ^ (r & 7))*8)];
      #pragma unroll
      for (int e = 0; e < 8; ++e)
        acc[e] = fmaf(wv[e][k], bf2f((unsigned short)v[e]), acc[e]);
    }
    short8 o;
    #pragma unroll
    for (int e = 0; e < 8; ++e) o[e] = (short)f2bf(siluf(acc[e]));
    *(short8*)(dst + (size_t)(t0 + rel)*CD + ch) = o;
  }
}

// ---------------- chunked scan (MFMA, bf16 S); dirs merged via blockIdx.z ----------------

__global__ __launch_bounds__(256) void phaseA_mfma(const unsigned short* __restrict__ convo,
                                                   const float* __restrict__ dtb, const float* __restrict__ A_log,
                                                   unsigned short* __restrict__ S, float* __restrict__ P) {
  int c = blockIdx.x, h = blockIdx.y, dir = blockIdx.z, tid = threadIdx.x;
  int lane = tid & 63, w = tid >> 6;
  int hh = dir*NH + h;
  const unsigned short* xc = convo + (size_t)dir*L_TOK*CD;
  __shared__ unsigned short xT[64*64];
  __shared__ unsigned short Bt[64*64];
  __shared__ float dts[64], lg[64], sfx[64], wgt[64];
  __shared__ float totals;
  int c0 = c*CHUNK;
  float Ah = -expf(A_log[h]);
  if (tid < 64) {
    float dtv = dtb[(size_t)(dir*L_TOK + c0 + tid)*NH + h];
    dts[tid] = dtv; lg[tid] = dtv*Ah;
  }
  #pragma unroll
  for (int i = 0; i < 2; ++i) {
    int q = tid + 256*i;
    int t = q >> 3, s0 = (q & 7)*8;
    short8 v = *(const short8*)(xc + (size_t)(c0+t)*CD + DI + s0);
    int tc = t >> 3, ti = t & 7;
    #pragma unroll
    for (int e = 0; e < 8; ++e) {
      int s = s0 + e;
      Bt[s*64 + ((tc ^ (s & 7))*8 + ti)] = (unsigned short)v[e];
    }
  }
  __syncthreads();
  if (tid == 0) {
    float run = 0.f;
    for (int t = 63; t >= 0; --t) { sfx[t] = run; run += lg[t]; }
    totals = run;
  }
  __syncthreads();
  if (tid < 64) wgt[tid] = dts[tid]*expf(sfx[tid]);
  if (tid == 0) P[hh*NC + c] = expf(totals);
  __syncthreads();
  #pragma unroll
  for (int i = 0; i < 2; ++i) {
    int q = tid + 256*i;
    int t = q >> 3, p0 = (q & 7)*8;
    short8 v = *(const short8*)(xc + (size_t)(c0+t)*CD + h*HD + p0);
    float wvv = wgt[t];
    int tc = t >> 3, ti = t & 7;
    #pragma unroll
    for (int e = 0; e < 8; ++e) {
      int p = p0 + e;
      xT[p*64 + ((tc ^ (p & 7))*8 + ti)] = f2bf(bf2f((unsigned short)v[e]) * wvv);
    }
  }
  __syncthreads();
  int t16 = lane & 15, q4 = lane >> 4;
  f32x4 zero = {0.f,0.f,0.f,0.f};
  f32x4 acc[4];
  #pragma unroll
  for (int j = 0; j < 4; ++j) acc[j] = zero;
  #pragma unroll
  for (int ks = 0; ks < 2; ++ks) {
    int rowA = 16*w + t16;
    short8 a = *(const short8*)&xT[rowA*64 + (((ks*4 + q4) ^ (rowA & 7))*8)];
    #pragma unroll
    for (int j = 0; j < 4; ++j) {
      int rowB = 16*j + t16;
      short8 b = *(const short8*)&Bt[rowB*64 + (((ks*4 + q4) ^ (rowB & 7))*8)];
      acc[j] = __builtin_amdgcn_mfma_f32_16x16x32_bf16(a, b, acc[j], 0, 0, 0);
    }
  }
  unsigned short* Sp = S + ((size_t)(hh*NC + c))*4096;
  #pragma unroll
  for (int j = 0; j < 4; ++j)
    #pragma unroll
    for (int r = 0; r < 4; ++r)
      Sp[(size_t)(16*w + q4*4 + r)*64 + 16*j + t16] = f2bf(acc[j][r]);
}

// ---- phaseB: hh spans 16 (2 dirs x 8 heads) ----

__global__ __launch_bounds__(256) void phaseB1(const unsigned short* __restrict__ S, const float* __restrict__ P,
                                               float* __restrict__ Ssum, float* __restrict__ Psum) {
  int gid = blockIdx.x*256 + threadIdx.x;
  int e2 = gid & 2047;
  int sc = (gid >> 11) & 15;
  int hh = gid >> 15;
  const unsigned short* base = S + ((size_t)(hh*NC + sc*16))*4096 + e2*2;
  const float* Ph = P + hh*NC + sc*16;
  float hx = 0.f, hy = 0.f, pprod = 1.f;
  #pragma unroll
  for (int k = 0; k < 16; ++k) {
    unsigned int v = *(const unsigned int*)(base + (size_t)k*4096);
    float p = Ph[k];
    hx = p*hx + bf2f((unsigned short)(v & 0xffffu));
    hy = p*hy + bf2f((unsigned short)(v >> 16));
    pprod *= p;
  }
  float* sp = Ssum + ((size_t)(hh*16 + sc))*4096 + e2*2;
  sp[0] = hx; sp[1] = hy;
  if (e2 == 0) Psum[hh*16 + sc] = pprod;
}

__global__ __launch_bounds__(256) void phaseB3(unsigned short* __restrict__ S, const float* __restrict__ P,
                                               const float* __restrict__ Ssum, const float* __restrict__ Psum) {
  int gid = blockIdx.x*256 + threadIdx.x;
  int e2 = gid & 2047;
  int sc = (gid >> 11) & 15;
  int hh = gid >> 15;
  float hx = 0.f, hy = 0.f;
  for (int s2 = 0; s2 < sc; ++s2) {
    float pp = Psum[hh*16 + s2];
    const float* sp = Ssum + ((size_t)(hh*16 + s2))*4096 + e2*2;
    hx = pp*hx + sp[0];
    hy = pp*hy + sp[1];
  }
  unsigned short* base = S + ((size_t)(hh*NC + sc*16))*4096 + e2*2;
  const float* Ph = P + hh*NC + sc*16;
  #pragma unroll
  for (int k = 0; k < 16; ++k) {
    unsigned int* ptr = (unsigned int*)(base + (size_t)k*4096);
    unsigned int v = *ptr;
    float p = Ph[k];
    *ptr = (unsigned int)f2bf(hx) | ((unsigned int)f2bf(hy) << 16);
    hx = p*hx + bf2f((unsigned short)(v & 0xffffu));
    hy = p*hy + bf2f((unsigned short)(v >> 16));
  }
}

// phaseC: dirs merged; Y written into xbc buffer region (stride DI)
__global__ __launch_bounds__(256) void phaseC_mfma(const unsigned short* __restrict__ convo,
                                                   const float* __restrict__ dtb, const float* __restrict__ A_log,
                                                   const float* __restrict__ Dp,
                                                   const unsigned short* __restrict__ S,
                                                   unsigned short* __restrict__ ybase) {
  int c = blockIdx.x, h = blockIdx.y, dir = blockIdx.z, tid = threadIdx.x;
  int lane = tid & 63, w = tid >> 6;
  int hh = dir*NH + h;
  const unsigned short* xc = convo + (size_t)dir*L_TOK*CD;
  unsigned short* y = ybase + (size_t)dir*L_TOK*CD;
  __shared__ unsigned short Cl[64*64];
  __shared__ unsigned short Bl[64*64];
  __shared__ unsigned short h0l[64*64];
  __shared__ unsigned short xT[64*64];
  __shared__ unsigned short Gl[64*64];
  __shared__ float dts[64], lg[64], pl[64], pe[64];
  int c0 = c*CHUNK;
  float Ah = -expf(A_log[h]);
  float Dh = Dp[h];
  if (tid < 64) {
    float dtv = dtb[(size_t)(dir*L_TOK + c0 + tid)*NH + h];
    dts[tid] = dtv; lg[tid] = dtv*Ah;
  }
  const unsigned short* Sp = S + ((size_t)(hh*NC + c))*4096;
  #pragma unroll
  for (int i = 0; i < 2; ++i) {
    int q = tid + 256*i;
    int t = q >> 3, d0 = (q & 7)*8;
    int swoff = t*64 + (((q & 7) ^ (t & 7))*8);
    *(short8*)&Cl[swoff] = *(const short8*)(xc + (size_t)(c0+t)*CD + DI + DS + d0);
    *(short8*)&Bl[swoff] = *(const short8*)(xc + (size_t)(c0+t)*CD + DI + d0);
    *(short8*)&h0l[swoff] = *(const short8*)(Sp + (size_t)t*64 + d0);
    short8 xv = *(const short8*)(xc + (size_t)(c0+t)*CD + h*HD + d0);
    int tc = t >> 3, ti = t & 7;
    #pragma unroll
    for (int e = 0; e < 8; ++e) {
      int p = d0 + e;
      xT[p*64 + ((tc ^ (p & 7))*8 + ti)] = (unsigned short)xv[e];
    }
  }
  __syncthreads();
  if (tid == 0) {
    float run = 0.f;
    for (int t = 0; t < 64; ++t) { run += lg[t]; pl[t] = run; }
  }
  __syncthreads();
  if (tid < 64) pe[tid] = expf(pl[tid]);
  __syncthreads();
  int t16 = lane & 15, q4 = lane >> 4;
  int t0 = 16*w;
  f32x4 zero = {0.f,0.f,0.f,0.f};
  f32x4 accG[4], accY[4];
  #pragma unroll
  for (int j = 0; j < 4; ++j) { accG[j] = zero; accY[j] = zero; }
  #pragma unroll
  for (int ks = 0; ks < 2; ++ks) {
    int rowA = t0 + t16;
    short8 a = *(const short8*)&Cl[rowA*64 + (((ks*4 + q4) ^ (rowA & 7))*8)];
    #pragma unroll
    for (int j = 0; j < 4; ++j) {
      int rowB = 16*j + t16;
      int off = rowB*64 + (((ks*4 + q4) ^ (rowB & 7))*8);
      accG[j] = __builtin_amdgcn_mfma_f32_16x16x32_bf16(a, *(const short8*)&Bl[off], accG[j], 0, 0, 0);
      accY[j] = __builtin_amdgcn_mfma_f32_16x16x32_bf16(a, *(const short8*)&h0l[off], accY[j], 0, 0, 0);
    }
  }
  #pragma unroll
  for (int j = 0; j < 4; ++j) {
    #pragma unroll
    for (int r = 0; r < 4; ++r) {
      int t = t0 + q4*4 + r;
      int s = 16*j + t16;
      float v = 0.f;
      if (s <= t) {
        v = accG[j][r] * dts[s] * expf(pl[t] - pl[s]);
        if (s == t) v += Dh;
      }
      Gl[t*64 + (((s >> 3) ^ (t & 7))*8 + (s & 7))] = f2bf(v);
    }
  }
  #pragma unroll
  for (int j = 0; j < 4; ++j)
    #pragma unroll
    for (int r = 0; r < 4; ++r)
      accY[j][r] *= pe[t0 + q4*4 + r];
  #pragma unroll
  for (int ks = 0; ks < 2; ++ks) {
    int rowA = t0 + t16;
    short8 a = *(const short8*)&Gl[rowA*64 + (((ks*4 + q4) ^ (rowA & 7))*8)];
    #pragma unroll
    for (int j = 0; j < 4; ++j) {
      int rowB = 16*j + t16;
      short8 b = *(const short8*)&xT[rowB*64 + (((ks*4 + q4) ^ (rowB & 7))*8)];
      accY[j] = __builtin_amdgcn_mfma_f32_16x16x32_bf16(a, b, accY[j], 0, 0, 0);
    }
  }
  #pragma unroll
  for (int j = 0; j < 4; ++j)
    #pragma unroll
    for (int r = 0; r < 4; ++r) {
      int t = t0 + q4*4 + r;
      int p = 16*j + t16;
      y[(size_t)(c0+t)*DI + h*HD + p] = f2bf(accY[j][r]);
    }
}

__global__ void fill_debug(float* out, float v) {
  int i = blockIdx.x*256 + threadIdx.x;
  if (i < L_TOK*DM) out[i] = v;
}

// ---------------- host ----------------

extern "C" void kernel_launch(void* const* d_in, const int* in_sizes, int n_in,
                              void* d_out, int out_size, void* d_ws, size_t ws_size,
                              hipStream_t stream) {
  const float* query = (const float*)d_in[0];
  const float* qpos  = (const float*)d_in[1];
  const float* pre_w = (const float*)d_in[2];
  const float* pre_b = (const float*)d_in[3];
  const float* fin_w = (const float*)d_in[4];
  const float* fin_b = (const float*)d_in[5];
  float* out = (float*)d_out;

  char* ws = (char*)d_ws;
  size_t off = 0;
  auto alloc = [&](size_t bytes) -> void* {
    void* p = ws + off;
    off += (bytes + 255) & ~(size_t)255;
    return p;
  };
  unsigned long long* keys = (unsigned long long*)alloc((size_t)2*L_TOK*8);
  unsigned int* ord = (unsigned int*)alloc((size_t)2*L_TOK*4);
  unsigned int* rpart = (unsigned int*)alloc((size_t)32*2*L_TOK*4);
  float* pmm  = (float*)alloc(256);
  float* qn   = (float*)alloc((size_t)L_TOK*DM*4);
  unsigned short* qnbf = (unsigned short*)alloc((size_t)L_TOK*DM*2);
  unsigned short* gatebf = (unsigned short*)alloc((size_t)2*L_TOK*DI*2);
  unsigned short* xbcbf  = (unsigned short*)alloc((size_t)2*L_TOK*CD*2);  // also hosts y (stride DI) after conv
  unsigned short* convo  = (unsigned short*)alloc((size_t)2*L_TOK*CD*2);
  float* dtb  = (float*)alloc((size_t)2*L_TOK*NH*4);
  unsigned short* Sbuf = (unsigned short*)alloc((size_t)2*NH*NC*4096*2);
  float* Pbuf = (float*)alloc((size_t)2*NH*NC*4);
  float* Ssum = (float*)alloc((size_t)2*NH*16*4096*4);
  float* Psum = (float*)alloc((size_t)2*NH*16*4);
  unsigned short* WtA = (unsigned short*)alloc((size_t)1152*DM*2);
  unsigned short* WtO = (unsigned short*)alloc((size_t)DM*DI*2);
  if (off > ws_size) {
    fill_debug<<<(L_TOK*DM + 255)/256, 256, 0, stream>>>(out, (float)(ws_size >> 20));
    return;
  }

  minmax_kernel<<<1, 256, 0, stream>>>(qpos, pmm);
  hilbert_kernel<<<L_TOK/256, 256, 0, stream>>>(qpos, pmm, keys);
  rank_partial<<<dim3(16, 2, 32), 256, 0, stream>>>(keys, rpart);
  rank_scatter<<<(2*L_TOK)/256, 256, 0, stream>>>(keys, rpart, ord);
  hipMemcpyAsync(out, query, (size_t)L_TOK*DM*4, hipMemcpyDeviceToDevice, stream);

  for (int l = 0; l < 2; ++l) {
    int base = 6 + 8*l;
    const float* in_proj  = (const float*)d_in[base+0];
    const float* conv_w   = (const float*)d_in[base+1];
    const float* conv_b   = (const float*)d_in[base+2];
    const float* dt_bias  = (const float*)d_in[base+3];
    const float* A_log    = (const float*)d_in[base+4];
    const float* Dp       = (const float*)d_in[base+5];
    const float* norm_w   = (const float*)d_in[base+6];
    const float* out_proj = (const float*)d_in[base+7];

    ln_kernel<<<L_TOK/4, 256, 0, stream>>>(out, qn, qnbf, pre_w, pre_b);
    tcvt_both<<<(1152*DM + DM*DI)/256, 256, 0, stream>>>(in_proj, out_proj, WtA, WtO);
    gemm_in_mfma<<<dim3(1152, 1, 2), 256, 0, stream>>>(qnbf, WtA, ord, gatebf, xbcbf);
    dt_gemv<<<(2*L_TOK)/32, 256, 0, stream>>>(qn, in_proj, ord, dt_bias, dtb);
    conv_kernel<<<dim3(10, 128, 2), 256, 0, stream>>>(xbcbf, conv_w, conv_b, convo);
    phaseA_mfma<<<dim3(NC, NH, 2), 256, 0, stream>>>(convo, dtb, A_log, Sbuf, Pbuf);
    phaseB1<<<(16*16*2048)/256, 256, 0, stream>>>(Sbuf, Pbuf, Ssum, Psum);
    phaseB3<<<(16*16*2048)/256, 256, 0, stream>>>(Sbuf, Pbuf, Ssum, Psum);
    phaseC_mfma<<<dim3(NC, NH, 2), 256, 0, stream>>>(convo, dtb, A_log, Dp, Sbuf, xbcbf);
    gating_kernel<<<(2*L_TOK)/4, 256, 0, stream>>>(xbcbf, gatebf, norm_w);
    for (int dir = 0; dir < 2; ++dir)
      gemm_out_mfma<<<256, 256, 0, stream>>>(xbcbf + (size_t)dir*L_TOK*CD, WtO,
                                             ord + (size_t)dir*L_TOK, out);
    ln_kernel<<<L_TOK/4, 256, 0, stream>>>(out, out, (unsigned short*)nullptr, fin_w, fin_b);
  }
}